// Round 4
// baseline (924.606 us; speedup 1.0000x reference)
//
#include <hip/hip_runtime.h>
#include <hip/hip_bf16.h>
#include <math.h>

#define NN_F_IN   512
#define NN_HID    256
#define NN_HEADS  8
#define NN_FH     32
#define NN_NCLASS 40
#define TAU_F     0.5f
#define LAMDA_F   0.5f

typedef __attribute__((ext_vector_type(8))) short bf16x8;
typedef __attribute__((ext_vector_type(4))) float f32x4;

static __device__ __forceinline__ float lrelu02(float x) { return x >= 0.f ? x : 0.2f * x; }
static __device__ __forceinline__ float elu1(float x)    { return x > 0.f ? x : expm1f(x); }
static __device__ __forceinline__ float b2f(unsigned short u) {
    unsigned int x = ((unsigned int)u) << 16;
    return __uint_as_float(x);
}
static __device__ __forceinline__ unsigned short f2b(float f) {
    __hip_bfloat16 hb = __float2bfloat16(f);
    return *reinterpret_cast<unsigned short*>(&hb);
}

// ---------------------------------------------------------------------------
// fp32 -> bf16 bulk cast (x input), 4 elems/thread
// ---------------------------------------------------------------------------
__global__ void cast_f2b_kernel(const float* __restrict__ src,
                                unsigned short* __restrict__ dst, int n4) {
    int i = blockIdx.x * 256 + threadIdx.x;
    if (i >= n4) return;
    float4 v = *(const float4*)(src + (size_t)i * 4);
    ushort4 o;
    o.x = f2b(v.x); o.y = f2b(v.y); o.z = f2b(v.z); o.w = f2b(v.w);
    *(ushort4*)(dst + (size_t)i * 4) = o;
}

// ---------------------------------------------------------------------------
// W [K][Nc] fp32  ->  Wt [Np][K] bf16 (transposed, zero-padded rows >= Nc)
// ---------------------------------------------------------------------------
__global__ void castW_kernel(const float* __restrict__ W, unsigned short* __restrict__ Wt,
                             int K, int Nc, int Np) {
    int idx = blockIdx.x * 256 + threadIdx.x;
    if (idx >= Np * K) return;
    int np = idx / K, k = idx - np * K;
    float v = (np < Nc) ? W[(size_t)k * Nc + np] : 0.f;
    Wt[idx] = f2b(v);
}

// ---------------------------------------------------------------------------
// MFMA GEMM: H[m][col] = sum_k A[m][k] * B[col][k], A/B bf16, H bf16.
// Block 4 waves 2x2 -> 128x128 tile; wave 64x64 = 4x4 frags of 16x16x32.
// A rows clamped to M-1 (stores masked). B rows pre-padded to tile multiple.
// ---------------------------------------------------------------------------
__global__ __launch_bounds__(256) void fc_mfma(const unsigned short* __restrict__ A,
                                               const unsigned short* __restrict__ B,
                                               unsigned short* __restrict__ H,
                                               int M, int K, int ncols, int ldH) {
    int t = threadIdx.x, lane = t & 63, wid = t >> 6;
    int wrow = wid >> 1, wcol = wid & 1;
    int l15 = lane & 15, lg = lane >> 4;
    int mbase = blockIdx.y * 128 + wrow * 64;
    int nbase = blockIdx.x * 128 + wcol * 64;

    const unsigned short* Ap[4];
    const unsigned short* Bp[4];
#pragma unroll
    for (int m = 0; m < 4; ++m) {
        int rr = mbase + m * 16 + l15;
        if (rr > M - 1) rr = M - 1;
        Ap[m] = A + (size_t)rr * K + lg * 8;
        Bp[m] = B + (size_t)(nbase + m * 16 + l15) * K + lg * 8;
    }
    f32x4 acc[4][4];
#pragma unroll
    for (int m = 0; m < 4; ++m)
#pragma unroll
        for (int nn = 0; nn < 4; ++nn)
#pragma unroll
            for (int r = 0; r < 4; ++r) acc[m][nn][r] = 0.f;

    bf16x8 aP[4], bP[4], aQ[4], bQ[4];
#pragma unroll
    for (int m = 0; m < 4; ++m) {
        aP[m] = *(const bf16x8*)(Ap[m]);
        bP[m] = *(const bf16x8*)(Bp[m]);
    }
    int nhalf = K >> 6;
    int kk = 32;
    for (int it = 0; it < nhalf; ++it) {
#pragma unroll
        for (int m = 0; m < 4; ++m) {
            aQ[m] = *(const bf16x8*)(Ap[m] + kk);
            bQ[m] = *(const bf16x8*)(Bp[m] + kk);
        }
#pragma unroll
        for (int m = 0; m < 4; ++m)
#pragma unroll
            for (int nn = 0; nn < 4; ++nn)
                acc[m][nn] = __builtin_amdgcn_mfma_f32_16x16x32_bf16(aP[m], bP[nn], acc[m][nn], 0, 0, 0);
        if (it + 1 < nhalf) {
#pragma unroll
            for (int m = 0; m < 4; ++m) {
                aP[m] = *(const bf16x8*)(Ap[m] + kk + 32);
                bP[m] = *(const bf16x8*)(Bp[m] + kk + 32);
            }
        }
#pragma unroll
        for (int m = 0; m < 4; ++m)
#pragma unroll
            for (int nn = 0; nn < 4; ++nn)
                acc[m][nn] = __builtin_amdgcn_mfma_f32_16x16x32_bf16(aQ[m], bQ[nn], acc[m][nn], 0, 0, 0);
        kk += 64;
    }
    // store: row = mbase + m*16 + lg*4 + r ; col = nbase + nn*16 + l15
#pragma unroll
    for (int m = 0; m < 4; ++m) {
#pragma unroll
        for (int nn = 0; nn < 4; ++nn) {
            int col = nbase + nn * 16 + l15;
            if (col >= ncols) continue;
#pragma unroll
            for (int r = 0; r < 4; ++r) {
                int row = mbase + m * 16 + lg * 4 + r;
                if (row < M) H[(size_t)row * ldH + col] = f2b(acc[m][nn][r]);
            }
        }
    }
}

// ---------------------------------------------------------------------------
// es/ed dot products (Hm bf16)
// ---------------------------------------------------------------------------
__global__ void attn_kernel(const unsigned short* __restrict__ Hm, const float* __restrict__ As,
                            const float* __restrict__ Ad, float* __restrict__ es,
                            float* __restrict__ ed, int n, int df) {
    int idx = blockIdx.x * blockDim.x + threadIdx.x;
    if (idx >= n * NN_HEADS) return;
    int nn = idx / NN_HEADS, hh = idx - nn * NN_HEADS;
    const unsigned short* hp = Hm + (size_t)nn * NN_HEADS * df + hh * df;
    const float* ap = As + hh * df;
    const float* bp = Ad + hh * df;
    float s1 = 0.f, s2 = 0.f;
    for (int d = 0; d < df; d += 4) {
        ushort4 hv = *(const ushort4*)(hp + d);
        float4 av = *(const float4*)(ap + d);
        float4 bv = *(const float4*)(bp + d);
        float h0 = b2f(hv.x), h1 = b2f(hv.y), h2 = b2f(hv.z), h3 = b2f(hv.w);
        s1 += h0 * av.x + h1 * av.y + h2 * av.z + h3 * av.w;
        s2 += h0 * bv.x + h1 * bv.y + h2 * bv.z + h3 * bv.w;
    }
    es[idx] = s1;
    ed[idx] = s2;
}

// ---------------------------------------------------------------------------
// CSR build
// ---------------------------------------------------------------------------
__global__ void count_kernel(const int* __restrict__ dst, int* __restrict__ counts, int E) {
    int e = blockIdx.x * blockDim.x + threadIdx.x;
    if (e < E) atomicAdd(&counts[dst[e]], 1);
}

__global__ void scan_kernel(const int* __restrict__ counts, int* __restrict__ row_start,
                            int* __restrict__ cursor, int n) {
    __shared__ int s[1024];
    int t  = threadIdx.x;
    int ch = (n + 1023) / 1024;
    int lo = t * ch;
    int sum = 0;
    for (int j = 0; j < ch; ++j) {
        int i = lo + j;
        if (i < n) sum += counts[i];
    }
    s[t] = sum;
    __syncthreads();
    for (int off = 1; off < 1024; off <<= 1) {
        int v = 0;
        if (t >= off) v = s[t - off];
        __syncthreads();
        s[t] += v;
        __syncthreads();
    }
    int run = (t == 0) ? 0 : s[t - 1];
    for (int j = 0; j < ch; ++j) {
        int i = lo + j;
        if (i < n) {
            row_start[i] = run;
            cursor[i] = run;
            run += counts[i];
        }
    }
    if (t == 1023) row_start[n] = s[1023];
}

__global__ void scatter_kernel(const int* __restrict__ src, const int* __restrict__ dst,
                               int* __restrict__ cursor, int* __restrict__ csr_src, int E) {
    int e = blockIdx.x * blockDim.x + threadIdx.x;
    if (e < E) {
        int d   = dst[e];
        int pos = atomicAdd(&cursor[d], 1);
        csr_src[pos] = src[e];
    }
}

// ---------------------------------------------------------------------------
// Hidden-layer gather, SINGLE PASS: z accumulated inline, divide at end.
// 1 wave per node, 4 nodes per block. bf16 in/out, fp32 accumulation.
// ---------------------------------------------------------------------------
__global__ __launch_bounds__(256) void gather_hidden(
    const unsigned short* __restrict__ Hm, const float* __restrict__ es,
    const float* __restrict__ ed, const int* __restrict__ csr_src,
    const int* __restrict__ row_start, const unsigned short* __restrict__ last,
    unsigned short* __restrict__ out, int n, float beta) {
    int lane = threadIdx.x & 63;
    int nn   = blockIdx.x * 4 + (threadIdx.x >> 6);
    if (nn >= n) return;
    int s0 = row_start[nn], s1 = row_start[nn + 1];
    int h2 = lane >> 3;
    float edh = ed[nn * NN_HEADS + h2];

    float zacc = 0.f;
    float a0 = 0.f, a1 = 0.f, a2 = 0.f, a3 = 0.f;
    for (int e = s0; e < s1; e += 4) {
        int c = s1 - e;
        int sv0 = csr_src[e];
        int sv1 = csr_src[c > 1 ? e + 1 : e];
        int sv2 = csr_src[c > 2 ? e + 2 : e];
        int sv3 = csr_src[c > 3 ? e + 3 : e];
        float q0 = es[sv0 * NN_HEADS + h2];
        float q1 = es[sv1 * NN_HEADS + h2];
        float q2 = es[sv2 * NN_HEADS + h2];
        float q3 = es[sv3 * NN_HEADS + h2];
        ushort4 r0 = *(const ushort4*)&Hm[(size_t)sv0 * NN_HID + lane * 4];
        ushort4 r1 = *(const ushort4*)&Hm[(size_t)sv1 * NN_HID + lane * 4];
        ushort4 r2 = *(const ushort4*)&Hm[(size_t)sv2 * NN_HID + lane * 4];
        ushort4 r3 = *(const ushort4*)&Hm[(size_t)sv3 * NN_HID + lane * 4];
        float w0 = expf(lrelu02(q0 + edh));
        zacc += w0;
        a0 += w0 * b2f(r0.x); a1 += w0 * b2f(r0.y); a2 += w0 * b2f(r0.z); a3 += w0 * b2f(r0.w);
        if (c > 1) {
            float w1 = expf(lrelu02(q1 + edh));
            zacc += w1;
            a0 += w1 * b2f(r1.x); a1 += w1 * b2f(r1.y); a2 += w1 * b2f(r1.z); a3 += w1 * b2f(r1.w);
        }
        if (c > 2) {
            float w2 = expf(lrelu02(q2 + edh));
            zacc += w2;
            a0 += w2 * b2f(r2.x); a1 += w2 * b2f(r2.y); a2 += w2 * b2f(r2.z); a3 += w2 * b2f(r2.w);
        }
        if (c > 3) {
            float w3 = expf(lrelu02(q3 + edh));
            zacc += w3;
            a0 += w3 * b2f(r3.x); a1 += w3 * b2f(r3.y); a2 += w3 * b2f(r3.z); a3 += w3 * b2f(r3.w);
        }
    }
    float zinv = 1.f / zacc;
    float v0 = elu1(a0 * zinv), v1 = elu1(a1 * zinv), v2 = elu1(a2 * zinv), v3 = elu1(a3 * zinv);
    if (beta >= 0.f) {
        ushort4 lv = *(const ushort4*)&last[(size_t)nn * NN_HID + lane * 4];
        v0 = beta * b2f(lv.x) + (1.f - beta) * v0;
        v1 = beta * b2f(lv.y) + (1.f - beta) * v1;
        v2 = beta * b2f(lv.z) + (1.f - beta) * v2;
        v3 = beta * b2f(lv.w) + (1.f - beta) * v3;
    }
    ushort4 o;
    o.x = f2b(v0); o.y = f2b(v1); o.z = f2b(v2); o.w = f2b(v3);
    *(ushort4*)&out[(size_t)nn * NN_HID + lane * 4] = o;
}

// ---------------------------------------------------------------------------
// Final layer gather, SINGLE PASS + head-mean + log_softmax -> d_out
// ---------------------------------------------------------------------------
__global__ void gather_final(const unsigned short* __restrict__ Hm, const float* __restrict__ es,
                             const float* __restrict__ ed, const int* __restrict__ csr_src,
                             const int* __restrict__ row_start, float* __restrict__ dout, int n) {
    int nn = blockIdx.x;
    __shared__ float accs[NN_HEADS * NN_NCLASS];
    int t = threadIdx.x;  // 0..319
    int s0 = row_start[nn], s1 = row_start[nn + 1];
    int hh = t / NN_NCLASS;
    float edh = ed[nn * NN_HEADS + hh];
    float acc = 0.f, zacc = 0.f;
    const int LD = NN_HEADS * NN_NCLASS;
    for (int e = s0; e < s1; e += 4) {
        int c = s1 - e;
        int sv0 = csr_src[e];
        int sv1 = csr_src[c > 1 ? e + 1 : e];
        int sv2 = csr_src[c > 2 ? e + 2 : e];
        int sv3 = csr_src[c > 3 ? e + 3 : e];
        float q0 = es[sv0 * NN_HEADS + hh];
        float q1 = es[sv1 * NN_HEADS + hh];
        float q2 = es[sv2 * NN_HEADS + hh];
        float q3 = es[sv3 * NN_HEADS + hh];
        float v0 = b2f(Hm[(size_t)sv0 * LD + t]);
        float v1 = b2f(Hm[(size_t)sv1 * LD + t]);
        float v2 = b2f(Hm[(size_t)sv2 * LD + t]);
        float v3 = b2f(Hm[(size_t)sv3 * LD + t]);
        float w0 = expf(lrelu02(q0 + edh));
        zacc += w0; acc += w0 * v0;
        if (c > 1) { float w1 = expf(lrelu02(q1 + edh)); zacc += w1; acc += w1 * v1; }
        if (c > 2) { float w2 = expf(lrelu02(q2 + edh)); zacc += w2; acc += w2 * v2; }
        if (c > 3) { float w3 = expf(lrelu02(q3 + edh)); zacc += w3; acc += w3 * v3; }
    }
    accs[t] = acc / zacc;
    __syncthreads();
    if (t < 64) {
        float v = -INFINITY;
        if (t < NN_NCLASS) {
            float sacc = 0.f;
#pragma unroll
            for (int h2 = 0; h2 < NN_HEADS; ++h2) sacc += accs[h2 * NN_NCLASS + t];
            v = sacc * (1.f / NN_HEADS);
        }
        float mx = v;
#pragma unroll
        for (int o = 1; o < 64; o <<= 1) mx = fmaxf(mx, __shfl_xor(mx, o, 64));
        float ex = (t < NN_NCLASS) ? expf(v - mx) : 0.f;
        float se = ex;
#pragma unroll
        for (int o = 1; o < 64; o <<= 1) se += __shfl_xor(se, o, 64);
        if (t < NN_NCLASS) dout[(size_t)nn * NN_NCLASS + t] = (v - mx) - logf(se);
    }
}

// ---------------------------------------------------------------------------
// Row-normalize (bf16 in) + bf16 zn + analytic diagonal
// ---------------------------------------------------------------------------
__global__ void rownorm_kernel(const unsigned short* __restrict__ z, short* __restrict__ znb,
                               float* __restrict__ dvec, int n) {
    int nn = blockIdx.x;
    int t  = threadIdx.x;  // 256
    float v  = b2f(z[(size_t)nn * NN_HID + t]);
    float sq = v * v;
#pragma unroll
    for (int o = 1; o < 64; o <<= 1) sq += __shfl_xor(sq, o, 64);
    __shared__ float ws[4];
    if ((t & 63) == 0) ws[t >> 6] = sq;
    __syncthreads();
    float s = ws[0] + ws[1] + ws[2] + ws[3];
    float m = fmaxf(sqrtf(s), 1e-12f);
    znb[(size_t)nn * NN_HID + t] = (short)f2b(v / m);
    if (t == 0) dvec[nn] = expf((s / (m * m)) * (1.f / TAU_F));
}

// ---------------------------------------------------------------------------
// Symmetric gram rowsums, NO atomics. Upper-triangle tiles in strips of 8
// j-tiles per block; A-frags (full K) held in registers across the strip.
// Partials stored to disjoint slots of P2d[2T][Npad]:
//   row-partials (target panel bi) -> slot 2*bj + wcol  (slots >= 2*bi)
//   col-partials (target panel bj) -> slot 2*bi + wrow  (slots <  2*bj)
// Final fold happens in loss_kernel.
// ---------------------------------------------------------------------------
__global__ __launch_bounds__(256) void gram_mfma(const short* __restrict__ znb,
                                                 float* __restrict__ P2d, int n,
                                                 int T, int nwg, int Npad) {
    // bijective XCD swizzle
    int b = blockIdx.x;
    int q = nwg >> 3, r8 = nwg & 7, xc = b & 7, oo = b >> 3;
    int sid = (xc < r8 ? xc * (q + 1) : r8 * (q + 1) + (xc - r8) * q) + oo;
    // strip decode: strips of 8 j-tiles per row-panel
    int bi = 0, rem = sid;
    for (;;) {
        int ns = (T - bi + 7) >> 3;
        if (rem < ns) break;
        rem -= ns;
        ++bi;
    }
    int bj0 = bi + (rem << 3);
    int bjend = bj0 + 8;
    if (bjend > T) bjend = T;

    int t    = threadIdx.x;
    int lane = t & 63;
    int wid  = t >> 6;
    int wrow = wid >> 1, wcol = wid & 1;
    int l15  = lane & 15, lg = lane >> 4;
    int i0w  = bi * 128 + wrow * 64;

    // A fragments for the whole K=256, resident across the strip
    const short* Apt = znb + (size_t)(i0w + l15) * NN_HID + lg * 8;
    bf16x8 Af[32];
#pragma unroll
    for (int s = 0; s < 8; ++s)
#pragma unroll
        for (int m = 0; m < 4; ++m)
            Af[s * 4 + m] = *(const bf16x8*)(Apt + (size_t)m * 16 * NN_HID + s * 32);

    for (int bj = bj0; bj < bjend; ++bj) {
        const short* Bpt = znb + (size_t)(bj * 128 + wcol * 64 + l15) * NN_HID + lg * 8;
        f32x4 acc[4][4];
#pragma unroll
        for (int m = 0; m < 4; ++m)
#pragma unroll
            for (int nn = 0; nn < 4; ++nn)
#pragma unroll
                for (int r = 0; r < 4; ++r) acc[m][nn][r] = 0.f;

        bf16x8 bB[2][4];
#pragma unroll
        for (int nn = 0; nn < 4; ++nn)
            bB[0][nn] = *(const bf16x8*)(Bpt + (size_t)nn * 16 * NN_HID);
#pragma unroll
        for (int s = 0; s < 8; ++s) {
            if (s < 7) {
#pragma unroll
                for (int nn = 0; nn < 4; ++nn)
                    bB[(s + 1) & 1][nn] = *(const bf16x8*)(Bpt + (size_t)nn * 16 * NN_HID + (s + 1) * 32);
            }
#pragma unroll
            for (int m = 0; m < 4; ++m)
#pragma unroll
                for (int nn = 0; nn < 4; ++nn)
                    acc[m][nn] = __builtin_amdgcn_mfma_f32_16x16x32_bf16(Af[s * 4 + m], bB[s & 1][nn], acc[m][nn], 0, 0, 0);
        }

        // in-place transform acc -> exp(acc/tau), masked
        int j0 = bj * 128 + wcol * 64;
        bool diag = (bj == bi);
#pragma unroll
        for (int m = 0; m < 4; ++m)
#pragma unroll
            for (int nn = 0; nn < 4; ++nn) {
                int gj = j0 + nn * 16 + l15;
                bool jok = gj < n;
#pragma unroll
                for (int r = 0; r < 4; ++r) {
                    int gi = i0w + m * 16 + lg * 4 + r;
                    acc[m][nn][r] = (jok && gi < n) ? expf(acc[m][nn][r] * (1.f / TAU_F)) : 0.f;
                }
            }
        // row partials: reduce over l15 lanes -> slot 2*bj + wcol
        float* rowslot = P2d + (size_t)(2 * bj + wcol) * Npad;
#pragma unroll
        for (int m = 0; m < 4; ++m) {
#pragma unroll
            for (int r = 0; r < 4; ++r) {
                float v = acc[m][0][r] + acc[m][1][r] + acc[m][2][r] + acc[m][3][r];
                v += __shfl_xor(v, 1, 64);
                v += __shfl_xor(v, 2, 64);
                v += __shfl_xor(v, 4, 64);
                v += __shfl_xor(v, 8, 64);
                if (l15 == 0) {
                    int gi = i0w + m * 16 + lg * 4 + r;
                    if (gi < n) rowslot[gi] = v;
                }
            }
        }
        // col partials (symmetry): reduce over lg -> slot 2*bi + wrow
        if (!diag) {
            float* colslot = P2d + (size_t)(2 * bi + wrow) * Npad;
#pragma unroll
            for (int nn = 0; nn < 4; ++nn) {
                float v = 0.f;
#pragma unroll
                for (int m = 0; m < 4; ++m)
#pragma unroll
                    for (int r = 0; r < 4; ++r) v += acc[m][nn][r];
                v += __shfl_xor(v, 16, 64);
                v += __shfl_xor(v, 32, 64);
                if (lg == 0) {
                    int gj = j0 + nn * 16 + l15;
                    if (gj < n) colslot[gj] = v;
                }
            }
        }
    }
}

// ---------------------------------------------------------------------------
// Fold partial slots + compute loss
// ---------------------------------------------------------------------------
__global__ void loss_kernel(const float* __restrict__ P2d, const float* __restrict__ dvec,
                            float* __restrict__ out_loss, int n, int slots, int Npad) {
    __shared__ float s[1024];
    int t = threadIdx.x;
    float sum = 0.f;
    for (int i = t; i < n; i += 1024) {
        float r = 0.f;
        for (int sl = 0; sl < slots; ++sl) r += P2d[(size_t)sl * Npad + i];
        float d   = dvec[i];
        float off = r - d;
        sum += -logf(d / (off + off));
    }
    s[t] = sum;
    __syncthreads();
    for (int o = 512; o > 0; o >>= 1) {
        if (t < o) s[t] += s[t + o];
        __syncthreads();
    }
    if (t == 0) *out_loss = s[0] / n;
}

// ---------------------------------------------------------------------------
extern "C" void kernel_launch(void* const* d_in, const int* in_sizes, int n_in,
                              void* d_out, int out_size, void* d_ws, size_t ws_size,
                              hipStream_t stream) {
    const float* x   = (const float*)d_in[0];
    const int*   src = (const int*)d_in[1];
    const int*   dst = (const int*)d_in[2];
    const float* W0  = (const float*)d_in[3];
    const float* a0s = (const float*)d_in[4];
    const float* a0d = (const float*)d_in[5];
    const float* W1  = (const float*)d_in[6];
    const float* a1s = (const float*)d_in[7];
    const float* a1d = (const float*)d_in[8];
    const float* W2  = (const float*)d_in[9];
    const float* a2s = (const float*)d_in[10];
    const float* a2d = (const float*)d_in[11];
    const float* Wout= (const float*)d_in[12];
    const float* aos = (const float*)d_in[13];
    const float* aod = (const float*)d_in[14];

    int N = in_sizes[0] / NN_F_IN;
    int E = in_sizes[1];
    int Npad = ((N + 127) / 128) * 128;
    int T = Npad / 128;
    // strips of 8 j-tiles per row panel
    int nwg = 0;
    for (int bi = 0; bi < T; ++bi) nwg += (T - bi + 7) >> 3;
    float* out = (float*)d_out;

    char*  ws  = (char*)d_ws;
    size_t off = 0;
    auto alloc = [&](size_t bytes) -> void* {
        void* p = ws + off;
        off += bytes;
        off = (off + 255) & ~(size_t)255;
        return p;
    };
    size_t hbBytes = (size_t)N * 320 * 2;
    size_t znBytes = (size_t)Npad * NN_HID * 2;
    unsigned short* Hb = (unsigned short*)alloc(hbBytes > znBytes ? hbBytes : znBytes);
    short* znb = (short*)Hb;  // alias: znb live only between rownorm and gram; Hb rewritten after
    unsigned short* Bl = (unsigned short*)alloc((size_t)N * NN_HID * 2);
    unsigned short* Bc = (unsigned short*)alloc((size_t)N * NN_HID * 2);
    size_t xbBytes = (size_t)N * NN_F_IN * 2;
    size_t p2Bytes = (size_t)2 * T * Npad * 4;
    void* XbP2d = alloc(xbBytes > p2Bytes ? xbBytes : p2Bytes);
    unsigned short* Xb  = (unsigned short*)XbP2d;  // live: castX..fc L0
    float*          P2d = (float*)XbP2d;           // live: memset..loss
    unsigned short* Wt0 = (unsigned short*)alloc((size_t)256 * 512 * 2);
    unsigned short* Wt1 = (unsigned short*)alloc((size_t)256 * 256 * 2);
    unsigned short* Wt2 = (unsigned short*)alloc((size_t)256 * 256 * 2);
    unsigned short* Wto = (unsigned short*)alloc((size_t)384 * 256 * 2);
    float* es     = (float*)alloc((size_t)N * NN_HEADS * 4);
    float* ed     = (float*)alloc((size_t)N * NN_HEADS * 4);
    float* dvec   = (float*)alloc((size_t)N * 4);
    int*   counts = (int*)alloc((size_t)N * 4);
    int*   rs     = (int*)alloc((size_t)(N + 1) * 4);
    int*   cursor = (int*)alloc((size_t)N * 4);
    int*   csr    = (int*)alloc((size_t)E * 4);

    // ---- CSR build
    hipMemsetAsync(counts, 0, (size_t)N * 4, stream);
    count_kernel<<<(E + 255) / 256, 256, 0, stream>>>(dst, counts, E);
    scan_kernel<<<1, 1024, 0, stream>>>(counts, rs, cursor, N);
    scatter_kernel<<<(E + 255) / 256, 256, 0, stream>>>(src, dst, cursor, csr, E);

    // ---- casts
    cast_f2b_kernel<<<(N * NN_F_IN / 4 + 255) / 256, 256, 0, stream>>>(x, Xb, N * NN_F_IN / 4);
    castW_kernel<<<(256 * 512 + 255) / 256, 256, 0, stream>>>(W0, Wt0, 512, 256, 256);
    castW_kernel<<<(256 * 256 + 255) / 256, 256, 0, stream>>>(W1, Wt1, 256, 256, 256);
    castW_kernel<<<(256 * 256 + 255) / 256, 256, 0, stream>>>(W2, Wt2, 256, 256, 256);
    castW_kernel<<<(384 * 256 + 255) / 256, 256, 0, stream>>>(Wout, Wto, 256, 320, 384);

    int atGrid = (N * NN_HEADS + 255) / 256;
    int ghGrid = (N + 3) / 4;
    int mTiles = (N + 127) / 128;

    // ---- layer 0: Xb -> Hb -> Bl
    fc_mfma<<<dim3(2, mTiles), 256, 0, stream>>>(Xb, Wt0, Hb, N, 512, 256, 256);
    attn_kernel<<<atGrid, 256, 0, stream>>>(Hb, a0s, a0d, es, ed, N, NN_FH);
    gather_hidden<<<ghGrid, 256, 0, stream>>>(Hb, es, ed, csr, rs, nullptr, Bl, N, -1.f);

    // ---- layer 1: Bl -> Hb -> Bc (beta = 0.5/3)
    fc_mfma<<<dim3(2, mTiles), 256, 0, stream>>>(Bl, Wt1, Hb, N, 256, 256, 256);
    attn_kernel<<<atGrid, 256, 0, stream>>>(Hb, a1s, a1d, es, ed, N, NN_FH);
    gather_hidden<<<ghGrid, 256, 0, stream>>>(Hb, es, ed, csr, rs, Bl, Bc, N, LAMDA_F / 3.f);

    // ---- layer 2: Bc -> Hb -> Bl (beta = 0.5/4)
    fc_mfma<<<dim3(2, mTiles), 256, 0, stream>>>(Bc, Wt2, Hb, N, 256, 256, 256);
    attn_kernel<<<atGrid, 256, 0, stream>>>(Hb, a2s, a2d, es, ed, N, NN_FH);
    gather_hidden<<<ghGrid, 256, 0, stream>>>(Hb, es, ed, csr, rs, Bc, Bl, N, LAMDA_F / 4.f);

    // ---- bind_loss(Bl): znb (aliases Hb), partial slots in P2d
    rownorm_kernel<<<N, 256, 0, stream>>>(Bl, znb, dvec, N);
    hipMemsetAsync(znb + (size_t)N * NN_HID, 0, (size_t)(Npad - N) * NN_HID * 2, stream);
    hipMemsetAsync(P2d, 0, (size_t)2 * T * Npad * 4, stream);
    gram_mfma<<<nwg, 256, 0, stream>>>(znb, P2d, N, T, nwg, Npad);
    loss_kernel<<<1, 1024, 0, stream>>>(P2d, dvec, out + (size_t)N * NN_NCLASS, N, 2 * T, Npad);

    // ---- output layer: Bl -> Hb(320) -> d_out  (Hb overwrites znb after gram)
    fc_mfma<<<dim3(3, mTiles), 256, 0, stream>>>(Bl, Wto, Hb, N, 256, 320, 320);
    attn_kernel<<<atGrid, 256, 0, stream>>>(Hb, aos, aod, es, ed, N, NN_NCLASS);
    gather_final<<<N, NN_HEADS * NN_NCLASS, 0, stream>>>(Hb, es, ed, csr, rs, out, N);
}

// Round 5
// 528.960 us; speedup vs baseline: 1.7480x; 1.7480x over previous
//
#include <hip/hip_runtime.h>
#include <hip/hip_bf16.h>
#include <math.h>

#define NN_F_IN   512
#define NN_HID    256
#define NN_HEADS  8
#define NN_FH     32
#define NN_NCLASS 40
#define TAU_F     0.5f
#define LAMDA_F   0.5f

typedef __attribute__((ext_vector_type(8))) short bf16x8;
typedef __attribute__((ext_vector_type(4))) float f32x4;

static __device__ __forceinline__ float lrelu02(float x) { return x >= 0.f ? x : 0.2f * x; }
static __device__ __forceinline__ float elu1(float x)    { return x > 0.f ? x : expm1f(x); }
static __device__ __forceinline__ float b2f(unsigned short u) {
    unsigned int x = ((unsigned int)u) << 16;
    return __uint_as_float(x);
}
static __device__ __forceinline__ unsigned short f2b(float f) {
    __hip_bfloat16 hb = __float2bfloat16(f);
    return *reinterpret_cast<unsigned short*>(&hb);
}

// ---------------------------------------------------------------------------
// fp32 -> bf16 bulk cast (x input), 4 elems/thread
// ---------------------------------------------------------------------------
__global__ void cast_f2b_kernel(const float* __restrict__ src,
                                unsigned short* __restrict__ dst, int n4) {
    int i = blockIdx.x * 256 + threadIdx.x;
    if (i >= n4) return;
    float4 v = *(const float4*)(src + (size_t)i * 4);
    ushort4 o;
    o.x = f2b(v.x); o.y = f2b(v.y); o.z = f2b(v.z); o.w = f2b(v.w);
    *(ushort4*)(dst + (size_t)i * 4) = o;
}

// ---------------------------------------------------------------------------
// W [K][Nc] fp32  ->  Wt [Np][K] bf16 (transposed, zero-padded rows >= Nc)
// ---------------------------------------------------------------------------
__global__ void castW_kernel(const float* __restrict__ W, unsigned short* __restrict__ Wt,
                             int K, int Nc, int Np) {
    int idx = blockIdx.x * 256 + threadIdx.x;
    if (idx >= Np * K) return;
    int np = idx / K, k = idx - np * K;
    float v = (np < Nc) ? W[(size_t)k * Nc + np] : 0.f;
    Wt[idx] = f2b(v);
}

// ---------------------------------------------------------------------------
// MFMA GEMM: H[m][col] = sum_k A[m][k] * B[col][k], A/B bf16, H bf16.
// ---------------------------------------------------------------------------
__global__ __launch_bounds__(256) void fc_mfma(const unsigned short* __restrict__ A,
                                               const unsigned short* __restrict__ B,
                                               unsigned short* __restrict__ H,
                                               int M, int K, int ncols, int ldH) {
    int t = threadIdx.x, lane = t & 63, wid = t >> 6;
    int wrow = wid >> 1, wcol = wid & 1;
    int l15 = lane & 15, lg = lane >> 4;
    int mbase = blockIdx.y * 128 + wrow * 64;
    int nbase = blockIdx.x * 128 + wcol * 64;

    const unsigned short* Ap[4];
    const unsigned short* Bp[4];
#pragma unroll
    for (int m = 0; m < 4; ++m) {
        int rr = mbase + m * 16 + l15;
        if (rr > M - 1) rr = M - 1;
        Ap[m] = A + (size_t)rr * K + lg * 8;
        Bp[m] = B + (size_t)(nbase + m * 16 + l15) * K + lg * 8;
    }
    f32x4 acc[4][4];
#pragma unroll
    for (int m = 0; m < 4; ++m)
#pragma unroll
        for (int nn = 0; nn < 4; ++nn)
#pragma unroll
            for (int r = 0; r < 4; ++r) acc[m][nn][r] = 0.f;

    bf16x8 aP[4], bP[4], aQ[4], bQ[4];
#pragma unroll
    for (int m = 0; m < 4; ++m) {
        aP[m] = *(const bf16x8*)(Ap[m]);
        bP[m] = *(const bf16x8*)(Bp[m]);
    }
    int nhalf = K >> 6;
    int kk = 32;
    for (int it = 0; it < nhalf; ++it) {
#pragma unroll
        for (int m = 0; m < 4; ++m) {
            aQ[m] = *(const bf16x8*)(Ap[m] + kk);
            bQ[m] = *(const bf16x8*)(Bp[m] + kk);
        }
#pragma unroll
        for (int m = 0; m < 4; ++m)
#pragma unroll
            for (int nn = 0; nn < 4; ++nn)
                acc[m][nn] = __builtin_amdgcn_mfma_f32_16x16x32_bf16(aP[m], bP[nn], acc[m][nn], 0, 0, 0);
        if (it + 1 < nhalf) {
#pragma unroll
            for (int m = 0; m < 4; ++m) {
                aP[m] = *(const bf16x8*)(Ap[m] + kk + 32);
                bP[m] = *(const bf16x8*)(Bp[m] + kk + 32);
            }
        }
#pragma unroll
        for (int m = 0; m < 4; ++m)
#pragma unroll
            for (int nn = 0; nn < 4; ++nn)
                acc[m][nn] = __builtin_amdgcn_mfma_f32_16x16x32_bf16(aQ[m], bQ[nn], acc[m][nn], 0, 0, 0);
        kk += 64;
    }
#pragma unroll
    for (int m = 0; m < 4; ++m) {
#pragma unroll
        for (int nn = 0; nn < 4; ++nn) {
            int col = nbase + nn * 16 + l15;
            if (col >= ncols) continue;
#pragma unroll
            for (int r = 0; r < 4; ++r) {
                int row = mbase + m * 16 + lg * 4 + r;
                if (row < M) H[(size_t)row * ldH + col] = f2b(acc[m][nn][r]);
            }
        }
    }
}

// ---------------------------------------------------------------------------
// es/ed dot products (Hm bf16)
// ---------------------------------------------------------------------------
__global__ void attn_kernel(const unsigned short* __restrict__ Hm, const float* __restrict__ As,
                            const float* __restrict__ Ad, float* __restrict__ es,
                            float* __restrict__ ed, int n, int df) {
    int idx = blockIdx.x * blockDim.x + threadIdx.x;
    if (idx >= n * NN_HEADS) return;
    int nn = idx / NN_HEADS, hh = idx - nn * NN_HEADS;
    const unsigned short* hp = Hm + (size_t)nn * NN_HEADS * df + hh * df;
    const float* ap = As + hh * df;
    const float* bp = Ad + hh * df;
    float s1 = 0.f, s2 = 0.f;
    for (int d = 0; d < df; d += 4) {
        ushort4 hv = *(const ushort4*)(hp + d);
        float4 av = *(const float4*)(ap + d);
        float4 bv = *(const float4*)(bp + d);
        float h0 = b2f(hv.x), h1 = b2f(hv.y), h2 = b2f(hv.z), h3 = b2f(hv.w);
        s1 += h0 * av.x + h1 * av.y + h2 * av.z + h3 * av.w;
        s2 += h0 * bv.x + h1 * bv.y + h2 * bv.z + h3 * bv.w;
    }
    es[idx] = s1;
    ed[idx] = s2;
}

// ---------------------------------------------------------------------------
// CSR build
// ---------------------------------------------------------------------------
__global__ void count_kernel(const int* __restrict__ dst, int* __restrict__ counts, int E) {
    int e = blockIdx.x * blockDim.x + threadIdx.x;
    if (e < E) atomicAdd(&counts[dst[e]], 1);
}

__global__ void scan_kernel(const int* __restrict__ counts, int* __restrict__ row_start,
                            int* __restrict__ cursor, int n) {
    __shared__ int s[1024];
    int t  = threadIdx.x;
    int ch = (n + 1023) / 1024;
    int lo = t * ch;
    int sum = 0;
    for (int j = 0; j < ch; ++j) {
        int i = lo + j;
        if (i < n) sum += counts[i];
    }
    s[t] = sum;
    __syncthreads();
    for (int off = 1; off < 1024; off <<= 1) {
        int v = 0;
        if (t >= off) v = s[t - off];
        __syncthreads();
        s[t] += v;
        __syncthreads();
    }
    int run = (t == 0) ? 0 : s[t - 1];
    for (int j = 0; j < ch; ++j) {
        int i = lo + j;
        if (i < n) {
            row_start[i] = run;
            cursor[i] = run;
            run += counts[i];
        }
    }
    if (t == 1023) row_start[n] = s[1023];
}

__global__ void scatter_kernel(const int* __restrict__ src, const int* __restrict__ dst,
                               int* __restrict__ cursor, int* __restrict__ csr_src, int E) {
    int e = blockIdx.x * blockDim.x + threadIdx.x;
    if (e < E) {
        int d   = dst[e];
        int pos = atomicAdd(&cursor[d], 1);
        csr_src[pos] = src[e];
    }
}

// ---------------------------------------------------------------------------
// Hidden-layer gather, SINGLE PASS
// ---------------------------------------------------------------------------
__global__ __launch_bounds__(256) void gather_hidden(
    const unsigned short* __restrict__ Hm, const float* __restrict__ es,
    const float* __restrict__ ed, const int* __restrict__ csr_src,
    const int* __restrict__ row_start, const unsigned short* __restrict__ last,
    unsigned short* __restrict__ out, int n, float beta) {
    int lane = threadIdx.x & 63;
    int nn   = blockIdx.x * 4 + (threadIdx.x >> 6);
    if (nn >= n) return;
    int s0 = row_start[nn], s1 = row_start[nn + 1];
    int h2 = lane >> 3;
    float edh = ed[nn * NN_HEADS + h2];

    float zacc = 0.f;
    float a0 = 0.f, a1 = 0.f, a2 = 0.f, a3 = 0.f;
    for (int e = s0; e < s1; e += 4) {
        int c = s1 - e;
        int sv0 = csr_src[e];
        int sv1 = csr_src[c > 1 ? e + 1 : e];
        int sv2 = csr_src[c > 2 ? e + 2 : e];
        int sv3 = csr_src[c > 3 ? e + 3 : e];
        float q0 = es[sv0 * NN_HEADS + h2];
        float q1 = es[sv1 * NN_HEADS + h2];
        float q2 = es[sv2 * NN_HEADS + h2];
        float q3 = es[sv3 * NN_HEADS + h2];
        ushort4 r0 = *(const ushort4*)&Hm[(size_t)sv0 * NN_HID + lane * 4];
        ushort4 r1 = *(const ushort4*)&Hm[(size_t)sv1 * NN_HID + lane * 4];
        ushort4 r2 = *(const ushort4*)&Hm[(size_t)sv2 * NN_HID + lane * 4];
        ushort4 r3 = *(const ushort4*)&Hm[(size_t)sv3 * NN_HID + lane * 4];
        float w0 = expf(lrelu02(q0 + edh));
        zacc += w0;
        a0 += w0 * b2f(r0.x); a1 += w0 * b2f(r0.y); a2 += w0 * b2f(r0.z); a3 += w0 * b2f(r0.w);
        if (c > 1) {
            float w1 = expf(lrelu02(q1 + edh));
            zacc += w1;
            a0 += w1 * b2f(r1.x); a1 += w1 * b2f(r1.y); a2 += w1 * b2f(r1.z); a3 += w1 * b2f(r1.w);
        }
        if (c > 2) {
            float w2 = expf(lrelu02(q2 + edh));
            zacc += w2;
            a0 += w2 * b2f(r2.x); a1 += w2 * b2f(r2.y); a2 += w2 * b2f(r2.z); a3 += w2 * b2f(r2.w);
        }
        if (c > 3) {
            float w3 = expf(lrelu02(q3 + edh));
            zacc += w3;
            a0 += w3 * b2f(r3.x); a1 += w3 * b2f(r3.y); a2 += w3 * b2f(r3.z); a3 += w3 * b2f(r3.w);
        }
    }
    float zinv = 1.f / zacc;
    float v0 = elu1(a0 * zinv), v1 = elu1(a1 * zinv), v2 = elu1(a2 * zinv), v3 = elu1(a3 * zinv);
    if (beta >= 0.f) {
        ushort4 lv = *(const ushort4*)&last[(size_t)nn * NN_HID + lane * 4];
        v0 = beta * b2f(lv.x) + (1.f - beta) * v0;
        v1 = beta * b2f(lv.y) + (1.f - beta) * v1;
        v2 = beta * b2f(lv.z) + (1.f - beta) * v2;
        v3 = beta * b2f(lv.w) + (1.f - beta) * v3;
    }
    ushort4 o;
    o.x = f2b(v0); o.y = f2b(v1); o.z = f2b(v2); o.w = f2b(v3);
    *(ushort4*)&out[(size_t)nn * NN_HID + lane * 4] = o;
}

// ---------------------------------------------------------------------------
// Final layer gather, SINGLE PASS + head-mean + log_softmax -> d_out
// ---------------------------------------------------------------------------
__global__ void gather_final(const unsigned short* __restrict__ Hm, const float* __restrict__ es,
                             const float* __restrict__ ed, const int* __restrict__ csr_src,
                             const int* __restrict__ row_start, float* __restrict__ dout, int n) {
    int nn = blockIdx.x;
    __shared__ float accs[NN_HEADS * NN_NCLASS];
    int t = threadIdx.x;  // 0..319
    int s0 = row_start[nn], s1 = row_start[nn + 1];
    int hh = t / NN_NCLASS;
    float edh = ed[nn * NN_HEADS + hh];
    float acc = 0.f, zacc = 0.f;
    const int LD = NN_HEADS * NN_NCLASS;
    for (int e = s0; e < s1; e += 4) {
        int c = s1 - e;
        int sv0 = csr_src[e];
        int sv1 = csr_src[c > 1 ? e + 1 : e];
        int sv2 = csr_src[c > 2 ? e + 2 : e];
        int sv3 = csr_src[c > 3 ? e + 3 : e];
        float q0 = es[sv0 * NN_HEADS + hh];
        float q1 = es[sv1 * NN_HEADS + hh];
        float q2 = es[sv2 * NN_HEADS + hh];
        float q3 = es[sv3 * NN_HEADS + hh];
        float v0 = b2f(Hm[(size_t)sv0 * LD + t]);
        float v1 = b2f(Hm[(size_t)sv1 * LD + t]);
        float v2 = b2f(Hm[(size_t)sv2 * LD + t]);
        float v3 = b2f(Hm[(size_t)sv3 * LD + t]);
        float w0 = expf(lrelu02(q0 + edh));
        zacc += w0; acc += w0 * v0;
        if (c > 1) { float w1 = expf(lrelu02(q1 + edh)); zacc += w1; acc += w1 * v1; }
        if (c > 2) { float w2 = expf(lrelu02(q2 + edh)); zacc += w2; acc += w2 * v2; }
        if (c > 3) { float w3 = expf(lrelu02(q3 + edh)); zacc += w3; acc += w3 * v3; }
    }
    accs[t] = acc / zacc;
    __syncthreads();
    if (t < 64) {
        float v = -INFINITY;
        if (t < NN_NCLASS) {
            float sacc = 0.f;
#pragma unroll
            for (int h2 = 0; h2 < NN_HEADS; ++h2) sacc += accs[h2 * NN_NCLASS + t];
            v = sacc * (1.f / NN_HEADS);
        }
        float mx = v;
#pragma unroll
        for (int o = 1; o < 64; o <<= 1) mx = fmaxf(mx, __shfl_xor(mx, o, 64));
        float ex = (t < NN_NCLASS) ? expf(v - mx) : 0.f;
        float se = ex;
#pragma unroll
        for (int o = 1; o < 64; o <<= 1) se += __shfl_xor(se, o, 64);
        if (t < NN_NCLASS) dout[(size_t)nn * NN_NCLASS + t] = (v - mx) - logf(se);
    }
}

// ---------------------------------------------------------------------------
// Row-normalize (bf16 in) + bf16 zn + analytic diagonal
// ---------------------------------------------------------------------------
__global__ void rownorm_kernel(const unsigned short* __restrict__ z, short* __restrict__ znb,
                               float* __restrict__ dvec, int n) {
    int nn = blockIdx.x;
    int t  = threadIdx.x;  // 256
    float v  = b2f(z[(size_t)nn * NN_HID + t]);
    float sq = v * v;
#pragma unroll
    for (int o = 1; o < 64; o <<= 1) sq += __shfl_xor(sq, o, 64);
    __shared__ float ws[4];
    if ((t & 63) == 0) ws[t >> 6] = sq;
    __syncthreads();
    float s = ws[0] + ws[1] + ws[2] + ws[3];
    float m = fmaxf(sqrtf(s), 1e-12f);
    znb[(size_t)nn * NN_HID + t] = (short)f2b(v / m);
    if (t == 0) dvec[nn] = expf((s / (m * m)) * (1.f / TAU_F));
}

// ---------------------------------------------------------------------------
// Symmetric gram rowsums, NO atomics (see round-4 slot scheme).
// ---------------------------------------------------------------------------
__global__ __launch_bounds__(256) void gram_mfma(const short* __restrict__ znb,
                                                 float* __restrict__ P2d, int n,
                                                 int T, int nwg, int Npad) {
    int b = blockIdx.x;
    int q = nwg >> 3, r8 = nwg & 7, xc = b & 7, oo = b >> 3;
    int sid = (xc < r8 ? xc * (q + 1) : r8 * (q + 1) + (xc - r8) * q) + oo;
    int bi = 0, rem = sid;
    for (;;) {
        int ns = (T - bi + 7) >> 3;
        if (rem < ns) break;
        rem -= ns;
        ++bi;
    }
    int bj0 = bi + (rem << 3);
    int bjend = bj0 + 8;
    if (bjend > T) bjend = T;

    int t    = threadIdx.x;
    int lane = t & 63;
    int wid  = t >> 6;
    int wrow = wid >> 1, wcol = wid & 1;
    int l15  = lane & 15, lg = lane >> 4;
    int i0w  = bi * 128 + wrow * 64;

    const short* Apt = znb + (size_t)(i0w + l15) * NN_HID + lg * 8;
    bf16x8 Af[32];
#pragma unroll
    for (int s = 0; s < 8; ++s)
#pragma unroll
        for (int m = 0; m < 4; ++m)
            Af[s * 4 + m] = *(const bf16x8*)(Apt + (size_t)m * 16 * NN_HID + s * 32);

    for (int bj = bj0; bj < bjend; ++bj) {
        const short* Bpt = znb + (size_t)(bj * 128 + wcol * 64 + l15) * NN_HID + lg * 8;
        f32x4 acc[4][4];
#pragma unroll
        for (int m = 0; m < 4; ++m)
#pragma unroll
            for (int nn = 0; nn < 4; ++nn)
#pragma unroll
                for (int r = 0; r < 4; ++r) acc[m][nn][r] = 0.f;

        bf16x8 bB[2][4];
#pragma unroll
        for (int nn = 0; nn < 4; ++nn)
            bB[0][nn] = *(const bf16x8*)(Bpt + (size_t)nn * 16 * NN_HID);
#pragma unroll
        for (int s = 0; s < 8; ++s) {
            if (s < 7) {
#pragma unroll
                for (int nn = 0; nn < 4; ++nn)
                    bB[(s + 1) & 1][nn] = *(const bf16x8*)(Bpt + (size_t)nn * 16 * NN_HID + (s + 1) * 32);
            }
#pragma unroll
            for (int m = 0; m < 4; ++m)
#pragma unroll
                for (int nn = 0; nn < 4; ++nn)
                    acc[m][nn] = __builtin_amdgcn_mfma_f32_16x16x32_bf16(Af[s * 4 + m], bB[s & 1][nn], acc[m][nn], 0, 0, 0);
        }

        int j0 = bj * 128 + wcol * 64;
        bool diag = (bj == bi);
#pragma unroll
        for (int m = 0; m < 4; ++m)
#pragma unroll
            for (int nn = 0; nn < 4; ++nn) {
                int gj = j0 + nn * 16 + l15;
                bool jok = gj < n;
#pragma unroll
                for (int r = 0; r < 4; ++r) {
                    int gi = i0w + m * 16 + lg * 4 + r;
                    acc[m][nn][r] = (jok && gi < n) ? expf(acc[m][nn][r] * (1.f / TAU_F)) : 0.f;
                }
            }
        float* rowslot = P2d + (size_t)(2 * bj + wcol) * Npad;
#pragma unroll
        for (int m = 0; m < 4; ++m) {
#pragma unroll
            for (int r = 0; r < 4; ++r) {
                float v = acc[m][0][r] + acc[m][1][r] + acc[m][2][r] + acc[m][3][r];
                v += __shfl_xor(v, 1, 64);
                v += __shfl_xor(v, 2, 64);
                v += __shfl_xor(v, 4, 64);
                v += __shfl_xor(v, 8, 64);
                if (l15 == 0) {
                    int gi = i0w + m * 16 + lg * 4 + r;
                    if (gi < n) rowslot[gi] = v;
                }
            }
        }
        if (!diag) {
            float* colslot = P2d + (size_t)(2 * bi + wrow) * Npad;
#pragma unroll
            for (int nn = 0; nn < 4; ++nn) {
                float v = 0.f;
#pragma unroll
                for (int m = 0; m < 4; ++m)
#pragma unroll
                    for (int r = 0; r < 4; ++r) v += acc[m][nn][r];
                v += __shfl_xor(v, 16, 64);
                v += __shfl_xor(v, 32, 64);
                if (lg == 0) {
                    int gj = j0 + nn * 16 + l15;
                    if (gj < n) colslot[gj] = v;
                }
            }
        }
    }
}

// ---------------------------------------------------------------------------
// Parallel fold of partial slots: R[i] = sum_sl P2d[sl][i]
// ---------------------------------------------------------------------------
__global__ void fold_kernel(const float* __restrict__ P2d, float* __restrict__ R,
                            int n, int slots, int Npad) {
    int i = blockIdx.x * 256 + threadIdx.x;
    if (i >= n) return;
    const float* p = P2d + i;
    float s0 = 0.f, s1 = 0.f, s2 = 0.f, s3 = 0.f;
    int sl = 0;
    for (; sl + 4 <= slots; sl += 4) {
        s0 += p[(size_t)(sl + 0) * Npad];
        s1 += p[(size_t)(sl + 1) * Npad];
        s2 += p[(size_t)(sl + 2) * Npad];
        s3 += p[(size_t)(sl + 3) * Npad];
    }
    for (; sl < slots; ++sl) s0 += p[(size_t)sl * Npad];
    R[i] = (s0 + s1) + (s2 + s3);
}

__global__ void loss_kernel(const float* __restrict__ R, const float* __restrict__ dvec,
                            float* __restrict__ out_loss, int n) {
    __shared__ float s[1024];
    int t = threadIdx.x;
    float sum = 0.f;
    for (int i = t; i < n; i += 1024) {
        float d   = dvec[i];
        float off = R[i] - d;
        sum += -logf(d / (off + off));
    }
    s[t] = sum;
    __syncthreads();
    for (int o = 512; o > 0; o >>= 1) {
        if (t < o) s[t] += s[t + o];
        __syncthreads();
    }
    if (t == 0) *out_loss = s[0] / n;
}

// ---------------------------------------------------------------------------
extern "C" void kernel_launch(void* const* d_in, const int* in_sizes, int n_in,
                              void* d_out, int out_size, void* d_ws, size_t ws_size,
                              hipStream_t stream) {
    const float* x   = (const float*)d_in[0];
    const int*   src = (const int*)d_in[1];
    const int*   dst = (const int*)d_in[2];
    const float* W0  = (const float*)d_in[3];
    const float* a0s = (const float*)d_in[4];
    const float* a0d = (const float*)d_in[5];
    const float* W1  = (const float*)d_in[6];
    const float* a1s = (const float*)d_in[7];
    const float* a1d = (const float*)d_in[8];
    const float* W2  = (const float*)d_in[9];
    const float* a2s = (const float*)d_in[10];
    const float* a2d = (const float*)d_in[11];
    const float* Wout= (const float*)d_in[12];
    const float* aos = (const float*)d_in[13];
    const float* aod = (const float*)d_in[14];

    int N = in_sizes[0] / NN_F_IN;
    int E = in_sizes[1];
    int Npad = ((N + 127) / 128) * 128;
    int T = Npad / 128;
    int nwg = 0;
    for (int bi = 0; bi < T; ++bi) nwg += (T - bi + 7) >> 3;
    float* out = (float*)d_out;

    char*  ws  = (char*)d_ws;
    size_t off = 0;
    auto alloc = [&](size_t bytes) -> void* {
        void* p = ws + off;
        off += bytes;
        off = (off + 255) & ~(size_t)255;
        return p;
    };
    size_t hbBytes = (size_t)N * 320 * 2;
    size_t znBytes = (size_t)Npad * NN_HID * 2;
    unsigned short* Hb = (unsigned short*)alloc(hbBytes > znBytes ? hbBytes : znBytes);
    short* znb = (short*)Hb;  // alias: znb live only between rownorm and gram
    unsigned short* Bl = (unsigned short*)alloc((size_t)N * NN_HID * 2);
    unsigned short* Bc = (unsigned short*)alloc((size_t)N * NN_HID * 2);
    size_t xbBytes = (size_t)N * NN_F_IN * 2;
    size_t p2Bytes = (size_t)2 * T * Npad * 4;
    void* XbP2d = alloc(xbBytes > p2Bytes ? xbBytes : p2Bytes);
    unsigned short* Xb  = (unsigned short*)XbP2d;  // live: castX..fc L0
    float*          P2d = (float*)XbP2d;           // live: memset..fold
    unsigned short* Wt0 = (unsigned short*)alloc((size_t)256 * 512 * 2);
    unsigned short* Wt1 = (unsigned short*)alloc((size_t)256 * 256 * 2);
    unsigned short* Wt2 = (unsigned short*)alloc((size_t)256 * 256 * 2);
    unsigned short* Wto = (unsigned short*)alloc((size_t)384 * 256 * 2);
    float* es     = (float*)alloc((size_t)N * NN_HEADS * 4);
    float* ed     = (float*)alloc((size_t)N * NN_HEADS * 4);
    float* Rrow   = (float*)alloc((size_t)N * 4);
    float* dvec   = (float*)alloc((size_t)N * 4);
    int*   counts = (int*)alloc((size_t)N * 4);
    int*   rs     = (int*)alloc((size_t)(N + 1) * 4);
    int*   cursor = (int*)alloc((size_t)N * 4);
    int*   csr    = (int*)alloc((size_t)E * 4);

    // ---- CSR build
    hipMemsetAsync(counts, 0, (size_t)N * 4, stream);
    count_kernel<<<(E + 255) / 256, 256, 0, stream>>>(dst, counts, E);
    scan_kernel<<<1, 1024, 0, stream>>>(counts, rs, cursor, N);
    scatter_kernel<<<(E + 255) / 256, 256, 0, stream>>>(src, dst, cursor, csr, E);

    // ---- casts
    cast_f2b_kernel<<<(N * NN_F_IN / 4 + 255) / 256, 256, 0, stream>>>(x, Xb, N * NN_F_IN / 4);
    castW_kernel<<<(256 * 512 + 255) / 256, 256, 0, stream>>>(W0, Wt0, 512, 256, 256);
    castW_kernel<<<(256 * 256 + 255) / 256, 256, 0, stream>>>(W1, Wt1, 256, 256, 256);
    castW_kernel<<<(256 * 256 + 255) / 256, 256, 0, stream>>>(W2, Wt2, 256, 256, 256);
    castW_kernel<<<(384 * 256 + 255) / 256, 256, 0, stream>>>(Wout, Wto, 256, 320, 384);

    int atGrid = (N * NN_HEADS + 255) / 256;
    int ghGrid = (N + 3) / 4;
    int mTiles = (N + 127) / 128;

    // ---- layer 0: Xb -> Hb -> Bl
    fc_mfma<<<dim3(2, mTiles), 256, 0, stream>>>(Xb, Wt0, Hb, N, 512, 256, 256);
    attn_kernel<<<atGrid, 256, 0, stream>>>(Hb, a0s, a0d, es, ed, N, NN_FH);
    gather_hidden<<<ghGrid, 256, 0, stream>>>(Hb, es, ed, csr, rs, nullptr, Bl, N, -1.f);

    // ---- layer 1: Bl -> Hb -> Bc (beta = 0.5/3)
    fc_mfma<<<dim3(2, mTiles), 256, 0, stream>>>(Bl, Wt1, Hb, N, 256, 256, 256);
    attn_kernel<<<atGrid, 256, 0, stream>>>(Hb, a1s, a1d, es, ed, N, NN_FH);
    gather_hidden<<<ghGrid, 256, 0, stream>>>(Hb, es, ed, csr, rs, Bl, Bc, N, LAMDA_F / 3.f);

    // ---- layer 2: Bc -> Hb -> Bl (beta = 0.5/4)
    fc_mfma<<<dim3(2, mTiles), 256, 0, stream>>>(Bc, Wt2, Hb, N, 256, 256, 256);
    attn_kernel<<<atGrid, 256, 0, stream>>>(Hb, a2s, a2d, es, ed, N, NN_FH);
    gather_hidden<<<ghGrid, 256, 0, stream>>>(Hb, es, ed, csr, rs, Bc, Bl, N, LAMDA_F / 4.f);

    // ---- bind_loss(Bl): znb (aliases Hb), partial slots in P2d
    rownorm_kernel<<<N, 256, 0, stream>>>(Bl, znb, dvec, N);
    hipMemsetAsync(znb + (size_t)N * NN_HID, 0, (size_t)(Npad - N) * NN_HID * 2, stream);
    hipMemsetAsync(P2d, 0, (size_t)2 * T * Npad * 4, stream);
    gram_mfma<<<nwg, 256, 0, stream>>>(znb, P2d, N, T, nwg, Npad);
    fold_kernel<<<(N + 255) / 256, 256, 0, stream>>>(P2d, Rrow, N, 2 * T, Npad);
    loss_kernel<<<1, 1024, 0, stream>>>(Rrow, dvec, out + (size_t)N * NN_NCLASS, N);

    // ---- output layer: Bl -> Hb(320) -> d_out
    fc_mfma<<<dim3(3, mTiles), 256, 0, stream>>>(Bl, Wto, Hb, N, 256, 320, 320);
    attn_kernel<<<atGrid, 256, 0, stream>>>(Hb, aos, aod, es, ed, N, NN_NCLASS);
    gather_final<<<N, NN_HEADS * NN_NCLASS, 0, stream>>>(Hb, es, ed, csr, rs, out, N);
}

// Round 6
// 528.089 us; speedup vs baseline: 1.7509x; 1.0016x over previous
//
#include <hip/hip_runtime.h>
#include <hip/hip_bf16.h>
#include <math.h>

#define NN_F_IN   512
#define NN_HID    256
#define NN_HEADS  8
#define NN_FH     32
#define NN_NCLASS 40
#define TAU_F     0.5f
#define LAMDA_F   0.5f

typedef __attribute__((ext_vector_type(8))) short bf16x8;
typedef __attribute__((ext_vector_type(4))) float f32x4;

static __device__ __forceinline__ float lrelu02(float x) { return x >= 0.f ? x : 0.2f * x; }
static __device__ __forceinline__ float elu1(float x)    { return x > 0.f ? x : expm1f(x); }
static __device__ __forceinline__ float b2f(unsigned short u) {
    unsigned int x = ((unsigned int)u) << 16;
    return __uint_as_float(x);
}
static __device__ __forceinline__ unsigned short f2b(float f) {
    __hip_bfloat16 hb = __float2bfloat16(f);
    return *reinterpret_cast<unsigned short*>(&hb);
}

// ---------------------------------------------------------------------------
// fp32 -> bf16 bulk cast (x input), 4 elems/thread
// ---------------------------------------------------------------------------
__global__ void cast_f2b_kernel(const float* __restrict__ src,
                                unsigned short* __restrict__ dst, int n4) {
    int i = blockIdx.x * 256 + threadIdx.x;
    if (i >= n4) return;
    float4 v = *(const float4*)(src + (size_t)i * 4);
    ushort4 o;
    o.x = f2b(v.x); o.y = f2b(v.y); o.z = f2b(v.z); o.w = f2b(v.w);
    *(ushort4*)(dst + (size_t)i * 4) = o;
}

// ---------------------------------------------------------------------------
// W [K][Nc] fp32  ->  Wt [Np][K] bf16 (transposed, zero-padded rows >= Nc)
// ---------------------------------------------------------------------------
__global__ void castW_kernel(const float* __restrict__ W, unsigned short* __restrict__ Wt,
                             int K, int Nc, int Np) {
    int idx = blockIdx.x * 256 + threadIdx.x;
    if (idx >= Np * K) return;
    int np = idx / K, k = idx - np * K;
    float v = (np < Nc) ? W[(size_t)k * Nc + np] : 0.f;
    Wt[idx] = f2b(v);
}

// ---------------------------------------------------------------------------
// MFMA GEMM: H[m][col] = sum_k A[m][k] * B[col][k], A/B bf16, H bf16.
// Block = 4 waves 2x2 -> 64x64 tile; wave = 32x32 = 2x2 frags of 16x16x32.
// Small tiles -> 628+ blocks -> occupancy (158-block version was 0.6 w/SIMD).
// ---------------------------------------------------------------------------
__global__ __launch_bounds__(256) void fc_mfma(const unsigned short* __restrict__ A,
                                               const unsigned short* __restrict__ B,
                                               unsigned short* __restrict__ H,
                                               int M, int K, int ncols, int ldH) {
    int t = threadIdx.x, lane = t & 63, wid = t >> 6;
    int wrow = wid >> 1, wcol = wid & 1;
    int l15 = lane & 15, lg = lane >> 4;
    int mbase = blockIdx.y * 64 + wrow * 32;
    int nbase = blockIdx.x * 64 + wcol * 32;

    const unsigned short* Ap[2];
    const unsigned short* Bp[2];
#pragma unroll
    for (int m = 0; m < 2; ++m) {
        int rr = mbase + m * 16 + l15;
        if (rr > M - 1) rr = M - 1;
        Ap[m] = A + (size_t)rr * K + lg * 8;
        Bp[m] = B + (size_t)(nbase + m * 16 + l15) * K + lg * 8;
    }
    f32x4 acc[2][2];
#pragma unroll
    for (int m = 0; m < 2; ++m)
#pragma unroll
        for (int nn = 0; nn < 2; ++nn)
#pragma unroll
            for (int r = 0; r < 4; ++r) acc[m][nn][r] = 0.f;

    bf16x8 aP[2], bP[2], aQ[2], bQ[2];
#pragma unroll
    for (int m = 0; m < 2; ++m) {
        aP[m] = *(const bf16x8*)(Ap[m]);
        bP[m] = *(const bf16x8*)(Bp[m]);
    }
    int nhalf = K >> 6;
    int kk = 32;
    for (int it = 0; it < nhalf; ++it) {
#pragma unroll
        for (int m = 0; m < 2; ++m) {
            aQ[m] = *(const bf16x8*)(Ap[m] + kk);
            bQ[m] = *(const bf16x8*)(Bp[m] + kk);
        }
#pragma unroll
        for (int m = 0; m < 2; ++m)
#pragma unroll
            for (int nn = 0; nn < 2; ++nn)
                acc[m][nn] = __builtin_amdgcn_mfma_f32_16x16x32_bf16(aP[m], bP[nn], acc[m][nn], 0, 0, 0);
        if (it + 1 < nhalf) {
#pragma unroll
            for (int m = 0; m < 2; ++m) {
                aP[m] = *(const bf16x8*)(Ap[m] + kk + 32);
                bP[m] = *(const bf16x8*)(Bp[m] + kk + 32);
            }
        }
#pragma unroll
        for (int m = 0; m < 2; ++m)
#pragma unroll
            for (int nn = 0; nn < 2; ++nn)
                acc[m][nn] = __builtin_amdgcn_mfma_f32_16x16x32_bf16(aQ[m], bQ[nn], acc[m][nn], 0, 0, 0);
        kk += 64;
    }
#pragma unroll
    for (int m = 0; m < 2; ++m) {
#pragma unroll
        for (int nn = 0; nn < 2; ++nn) {
            int col = nbase + nn * 16 + l15;
            if (col >= ncols) continue;
#pragma unroll
            for (int r = 0; r < 4; ++r) {
                int row = mbase + m * 16 + lg * 4 + r;
                if (row < M) H[(size_t)row * ldH + col] = f2b(acc[m][nn][r]);
            }
        }
    }
}

// ---------------------------------------------------------------------------
// es/ed dot products (Hm bf16)
// ---------------------------------------------------------------------------
__global__ void attn_kernel(const unsigned short* __restrict__ Hm, const float* __restrict__ As,
                            const float* __restrict__ Ad, float* __restrict__ es,
                            float* __restrict__ ed, int n, int df) {
    int idx = blockIdx.x * blockDim.x + threadIdx.x;
    if (idx >= n * NN_HEADS) return;
    int nn = idx / NN_HEADS, hh = idx - nn * NN_HEADS;
    const unsigned short* hp = Hm + (size_t)nn * NN_HEADS * df + hh * df;
    const float* ap = As + hh * df;
    const float* bp = Ad + hh * df;
    float s1 = 0.f, s2 = 0.f;
    for (int d = 0; d < df; d += 4) {
        ushort4 hv = *(const ushort4*)(hp + d);
        float4 av = *(const float4*)(ap + d);
        float4 bv = *(const float4*)(bp + d);
        float h0 = b2f(hv.x), h1 = b2f(hv.y), h2 = b2f(hv.z), h3 = b2f(hv.w);
        s1 += h0 * av.x + h1 * av.y + h2 * av.z + h3 * av.w;
        s2 += h0 * bv.x + h1 * bv.y + h2 * bv.z + h3 * bv.w;
    }
    es[idx] = s1;
    ed[idx] = s2;
}

// ---------------------------------------------------------------------------
// CSR build
// ---------------------------------------------------------------------------
__global__ void count_kernel(const int* __restrict__ dst, int* __restrict__ counts, int E) {
    int e = blockIdx.x * blockDim.x + threadIdx.x;
    if (e < E) atomicAdd(&counts[dst[e]], 1);
}

__global__ void scan_kernel(const int* __restrict__ counts, int* __restrict__ row_start,
                            int* __restrict__ cursor, int n) {
    __shared__ int s[1024];
    int t  = threadIdx.x;
    int ch = (n + 1023) / 1024;
    int lo = t * ch;
    int sum = 0;
    for (int j = 0; j < ch; ++j) {
        int i = lo + j;
        if (i < n) sum += counts[i];
    }
    s[t] = sum;
    __syncthreads();
    for (int off = 1; off < 1024; off <<= 1) {
        int v = 0;
        if (t >= off) v = s[t - off];
        __syncthreads();
        s[t] += v;
        __syncthreads();
    }
    int run = (t == 0) ? 0 : s[t - 1];
    for (int j = 0; j < ch; ++j) {
        int i = lo + j;
        if (i < n) {
            row_start[i] = run;
            cursor[i] = run;
            run += counts[i];
        }
    }
    if (t == 1023) row_start[n] = s[1023];
}

__global__ void scatter_kernel(const int* __restrict__ src, const int* __restrict__ dst,
                               int* __restrict__ cursor, int* __restrict__ csr_src, int E) {
    int e = blockIdx.x * blockDim.x + threadIdx.x;
    if (e < E) {
        int d   = dst[e];
        int pos = atomicAdd(&cursor[d], 1);
        csr_src[pos] = src[e];
    }
}

// ---------------------------------------------------------------------------
// Hidden-layer gather, SINGLE PASS
// ---------------------------------------------------------------------------
__global__ __launch_bounds__(256) void gather_hidden(
    const unsigned short* __restrict__ Hm, const float* __restrict__ es,
    const float* __restrict__ ed, const int* __restrict__ csr_src,
    const int* __restrict__ row_start, const unsigned short* __restrict__ last,
    unsigned short* __restrict__ out, int n, float beta) {
    int lane = threadIdx.x & 63;
    int nn   = blockIdx.x * 4 + (threadIdx.x >> 6);
    if (nn >= n) return;
    int s0 = row_start[nn], s1 = row_start[nn + 1];
    int h2 = lane >> 3;
    float edh = ed[nn * NN_HEADS + h2];

    float zacc = 0.f;
    float a0 = 0.f, a1 = 0.f, a2 = 0.f, a3 = 0.f;
    for (int e = s0; e < s1; e += 4) {
        int c = s1 - e;
        int sv0 = csr_src[e];
        int sv1 = csr_src[c > 1 ? e + 1 : e];
        int sv2 = csr_src[c > 2 ? e + 2 : e];
        int sv3 = csr_src[c > 3 ? e + 3 : e];
        float q0 = es[sv0 * NN_HEADS + h2];
        float q1 = es[sv1 * NN_HEADS + h2];
        float q2 = es[sv2 * NN_HEADS + h2];
        float q3 = es[sv3 * NN_HEADS + h2];
        ushort4 r0 = *(const ushort4*)&Hm[(size_t)sv0 * NN_HID + lane * 4];
        ushort4 r1 = *(const ushort4*)&Hm[(size_t)sv1 * NN_HID + lane * 4];
        ushort4 r2 = *(const ushort4*)&Hm[(size_t)sv2 * NN_HID + lane * 4];
        ushort4 r3 = *(const ushort4*)&Hm[(size_t)sv3 * NN_HID + lane * 4];
        float w0 = expf(lrelu02(q0 + edh));
        zacc += w0;
        a0 += w0 * b2f(r0.x); a1 += w0 * b2f(r0.y); a2 += w0 * b2f(r0.z); a3 += w0 * b2f(r0.w);
        if (c > 1) {
            float w1 = expf(lrelu02(q1 + edh));
            zacc += w1;
            a0 += w1 * b2f(r1.x); a1 += w1 * b2f(r1.y); a2 += w1 * b2f(r1.z); a3 += w1 * b2f(r1.w);
        }
        if (c > 2) {
            float w2 = expf(lrelu02(q2 + edh));
            zacc += w2;
            a0 += w2 * b2f(r2.x); a1 += w2 * b2f(r2.y); a2 += w2 * b2f(r2.z); a3 += w2 * b2f(r2.w);
        }
        if (c > 3) {
            float w3 = expf(lrelu02(q3 + edh));
            zacc += w3;
            a0 += w3 * b2f(r3.x); a1 += w3 * b2f(r3.y); a2 += w3 * b2f(r3.z); a3 += w3 * b2f(r3.w);
        }
    }
    float zinv = 1.f / zacc;
    float v0 = elu1(a0 * zinv), v1 = elu1(a1 * zinv), v2 = elu1(a2 * zinv), v3 = elu1(a3 * zinv);
    if (beta >= 0.f) {
        ushort4 lv = *(const ushort4*)&last[(size_t)nn * NN_HID + lane * 4];
        v0 = beta * b2f(lv.x) + (1.f - beta) * v0;
        v1 = beta * b2f(lv.y) + (1.f - beta) * v1;
        v2 = beta * b2f(lv.z) + (1.f - beta) * v2;
        v3 = beta * b2f(lv.w) + (1.f - beta) * v3;
    }
    ushort4 o;
    o.x = f2b(v0); o.y = f2b(v1); o.z = f2b(v2); o.w = f2b(v3);
    *(ushort4*)&out[(size_t)nn * NN_HID + lane * 4] = o;
}

// ---------------------------------------------------------------------------
// Final layer gather, SINGLE PASS + head-mean + log_softmax -> d_out
// ---------------------------------------------------------------------------
__global__ void gather_final(const unsigned short* __restrict__ Hm, const float* __restrict__ es,
                             const float* __restrict__ ed, const int* __restrict__ csr_src,
                             const int* __restrict__ row_start, float* __restrict__ dout, int n) {
    int nn = blockIdx.x;
    __shared__ float accs[NN_HEADS * NN_NCLASS];
    int t = threadIdx.x;  // 0..319
    int s0 = row_start[nn], s1 = row_start[nn + 1];
    int hh = t / NN_NCLASS;
    float edh = ed[nn * NN_HEADS + hh];
    float acc = 0.f, zacc = 0.f;
    const int LD = NN_HEADS * NN_NCLASS;
    for (int e = s0; e < s1; e += 4) {
        int c = s1 - e;
        int sv0 = csr_src[e];
        int sv1 = csr_src[c > 1 ? e + 1 : e];
        int sv2 = csr_src[c > 2 ? e + 2 : e];
        int sv3 = csr_src[c > 3 ? e + 3 : e];
        float q0 = es[sv0 * NN_HEADS + hh];
        float q1 = es[sv1 * NN_HEADS + hh];
        float q2 = es[sv2 * NN_HEADS + hh];
        float q3 = es[sv3 * NN_HEADS + hh];
        float v0 = b2f(Hm[(size_t)sv0 * LD + t]);
        float v1 = b2f(Hm[(size_t)sv1 * LD + t]);
        float v2 = b2f(Hm[(size_t)sv2 * LD + t]);
        float v3 = b2f(Hm[(size_t)sv3 * LD + t]);
        float w0 = expf(lrelu02(q0 + edh));
        zacc += w0; acc += w0 * v0;
        if (c > 1) { float w1 = expf(lrelu02(q1 + edh)); zacc += w1; acc += w1 * v1; }
        if (c > 2) { float w2 = expf(lrelu02(q2 + edh)); zacc += w2; acc += w2 * v2; }
        if (c > 3) { float w3 = expf(lrelu02(q3 + edh)); zacc += w3; acc += w3 * v3; }
    }
    accs[t] = acc / zacc;
    __syncthreads();
    if (t < 64) {
        float v = -INFINITY;
        if (t < NN_NCLASS) {
            float sacc = 0.f;
#pragma unroll
            for (int h2 = 0; h2 < NN_HEADS; ++h2) sacc += accs[h2 * NN_NCLASS + t];
            v = sacc * (1.f / NN_HEADS);
        }
        float mx = v;
#pragma unroll
        for (int o = 1; o < 64; o <<= 1) mx = fmaxf(mx, __shfl_xor(mx, o, 64));
        float ex = (t < NN_NCLASS) ? expf(v - mx) : 0.f;
        float se = ex;
#pragma unroll
        for (int o = 1; o < 64; o <<= 1) se += __shfl_xor(se, o, 64);
        if (t < NN_NCLASS) dout[(size_t)nn * NN_NCLASS + t] = (v - mx) - logf(se);
    }
}

// ---------------------------------------------------------------------------
// Row-normalize (bf16 in) + bf16 zn + analytic diagonal
// ---------------------------------------------------------------------------
__global__ void rownorm_kernel(const unsigned short* __restrict__ z, short* __restrict__ znb,
                               float* __restrict__ dvec, int n) {
    int nn = blockIdx.x;
    int t  = threadIdx.x;  // 256
    float v  = b2f(z[(size_t)nn * NN_HID + t]);
    float sq = v * v;
#pragma unroll
    for (int o = 1; o < 64; o <<= 1) sq += __shfl_xor(sq, o, 64);
    __shared__ float ws[4];
    if ((t & 63) == 0) ws[t >> 6] = sq;
    __syncthreads();
    float s = ws[0] + ws[1] + ws[2] + ws[3];
    float m = fmaxf(sqrtf(s), 1e-12f);
    znb[(size_t)nn * NN_HID + t] = (short)f2b(v / m);
    if (t == 0) dvec[nn] = expf((s / (m * m)) * (1.f / TAU_F));
}

// ---------------------------------------------------------------------------
// Symmetric gram rowsums, NO atomics, ONE BLOCK PER 128x128 TRIANGLE TILE
// (3160 blocks -> occupancy; strip persistence removed: it cost 128 VGPR and
// cut the grid to 430 blocks -> 8% occupancy in round 5).
// Partials stored to disjoint slots of P2d[2T][Npad]:
//   row-partials (panel bi) -> slot 2*bj + wcol   (>= 2*bi)
//   col-partials (panel bj) -> slot 2*bi + wrow   (<  2*bj)
// ---------------------------------------------------------------------------
__global__ __launch_bounds__(256) void gram_mfma(const short* __restrict__ znb,
                                                 float* __restrict__ P2d, int n,
                                                 int T, int nwg, int Npad) {
    // bijective XCD swizzle: contiguous triangle range per XCD (A-panel L2 reuse)
    int b = blockIdx.x;
    int q = nwg >> 3, r8 = nwg & 7, xc = b & 7, oo = b >> 3;
    int sid = (xc < r8 ? xc * (q + 1) : r8 * (q + 1) + (xc - r8) * q) + oo;
    int bi = 0, rem = sid;
    while (rem >= T - bi) { rem -= T - bi; ++bi; }
    int bj = bi + rem;

    int t    = threadIdx.x;
    int lane = t & 63;
    int wid  = t >> 6;
    int wrow = wid >> 1, wcol = wid & 1;
    int l15  = lane & 15, lg = lane >> 4;
    int i0w  = bi * 128 + wrow * 64;
    int j0w  = bj * 128 + wcol * 64;

    const short* Apt = znb + (size_t)(i0w + l15) * NN_HID + lg * 8;
    const short* Bpt = znb + (size_t)(j0w + l15) * NN_HID + lg * 8;

    f32x4 acc[4][4];
#pragma unroll
    for (int m = 0; m < 4; ++m)
#pragma unroll
        for (int nn = 0; nn < 4; ++nn)
#pragma unroll
            for (int r = 0; r < 4; ++r) acc[m][nn][r] = 0.f;

    bf16x8 aP[4], bP[4], aQ[4], bQ[4];
#pragma unroll
    for (int m = 0; m < 4; ++m) {
        aP[m] = *(const bf16x8*)(Apt + (size_t)m * 16 * NN_HID);
        bP[m] = *(const bf16x8*)(Bpt + (size_t)m * 16 * NN_HID);
    }
    int kk = 32;
#pragma unroll
    for (int it = 0; it < 4; ++it) {   // K=256: 4 double-steps of 64
#pragma unroll
        for (int m = 0; m < 4; ++m) {
            aQ[m] = *(const bf16x8*)(Apt + (size_t)m * 16 * NN_HID + kk);
            bQ[m] = *(const bf16x8*)(Bpt + (size_t)m * 16 * NN_HID + kk);
        }
#pragma unroll
        for (int m = 0; m < 4; ++m)
#pragma unroll
            for (int nn = 0; nn < 4; ++nn)
                acc[m][nn] = __builtin_amdgcn_mfma_f32_16x16x32_bf16(aP[m], bP[nn], acc[m][nn], 0, 0, 0);
        if (it < 3) {
#pragma unroll
            for (int m = 0; m < 4; ++m) {
                aP[m] = *(const bf16x8*)(Apt + (size_t)m * 16 * NN_HID + kk + 32);
                bP[m] = *(const bf16x8*)(Bpt + (size_t)m * 16 * NN_HID + kk + 32);
            }
        }
#pragma unroll
        for (int m = 0; m < 4; ++m)
#pragma unroll
            for (int nn = 0; nn < 4; ++nn)
                acc[m][nn] = __builtin_amdgcn_mfma_f32_16x16x32_bf16(aQ[m], bQ[nn], acc[m][nn], 0, 0, 0);
        kk += 64;
    }

    // epilogue: acc -> exp(acc/tau), masked; rowsums always, colsums if off-diag
    bool diag = (bj == bi);
#pragma unroll
    for (int m = 0; m < 4; ++m)
#pragma unroll
        for (int nn = 0; nn < 4; ++nn) {
            int gj = j0w + nn * 16 + l15;
            bool jok = gj < n;
#pragma unroll
            for (int r = 0; r < 4; ++r) {
                int gi = i0w + m * 16 + lg * 4 + r;
                acc[m][nn][r] = (jok && gi < n) ? expf(acc[m][nn][r] * (1.f / TAU_F)) : 0.f;
            }
        }
    float* rowslot = P2d + (size_t)(2 * bj + wcol) * Npad;
#pragma unroll
    for (int m = 0; m < 4; ++m) {
#pragma unroll
        for (int r = 0; r < 4; ++r) {
            float v = acc[m][0][r] + acc[m][1][r] + acc[m][2][r] + acc[m][3][r];
            v += __shfl_xor(v, 1, 64);
            v += __shfl_xor(v, 2, 64);
            v += __shfl_xor(v, 4, 64);
            v += __shfl_xor(v, 8, 64);
            if (l15 == 0) {
                int gi = i0w + m * 16 + lg * 4 + r;
                if (gi < n) rowslot[gi] = v;
            }
        }
    }
    if (!diag) {
        float* colslot = P2d + (size_t)(2 * bi + wrow) * Npad;
#pragma unroll
        for (int nn = 0; nn < 4; ++nn) {
            float v = 0.f;
#pragma unroll
            for (int m = 0; m < 4; ++m)
#pragma unroll
                for (int r = 0; r < 4; ++r) v += acc[m][nn][r];
            v += __shfl_xor(v, 16, 64);
            v += __shfl_xor(v, 32, 64);
            if (lg == 0) {
                int gj = j0w + nn * 16 + l15;
                if (gj < n) colslot[gj] = v;
            }
        }
    }
}

// ---------------------------------------------------------------------------
// Parallel fold of partial slots: R[i] = sum_sl P2d[sl][i]
// ---------------------------------------------------------------------------
__global__ void fold_kernel(const float* __restrict__ P2d, float* __restrict__ R,
                            int n, int slots, int Npad) {
    int i = blockIdx.x * 256 + threadIdx.x;
    if (i >= n) return;
    const float* p = P2d + i;
    float s0 = 0.f, s1 = 0.f, s2 = 0.f, s3 = 0.f;
    int sl = 0;
    for (; sl + 4 <= slots; sl += 4) {
        s0 += p[(size_t)(sl + 0) * Npad];
        s1 += p[(size_t)(sl + 1) * Npad];
        s2 += p[(size_t)(sl + 2) * Npad];
        s3 += p[(size_t)(sl + 3) * Npad];
    }
    for (; sl < slots; ++sl) s0 += p[(size_t)sl * Npad];
    R[i] = (s0 + s1) + (s2 + s3);
}

__global__ void loss_kernel(const float* __restrict__ R, const float* __restrict__ dvec,
                            float* __restrict__ out_loss, int n) {
    __shared__ float s[1024];
    int t = threadIdx.x;
    float sum = 0.f;
    for (int i = t; i < n; i += 1024) {
        float d   = dvec[i];
        float off = R[i] - d;
        sum += -logf(d / (off + off));
    }
    s[t] = sum;
    __syncthreads();
    for (int o = 512; o > 0; o >>= 1) {
        if (t < o) s[t] += s[t + o];
        __syncthreads();
    }
    if (t == 0) *out_loss = s[0] / n;
}

// ---------------------------------------------------------------------------
extern "C" void kernel_launch(void* const* d_in, const int* in_sizes, int n_in,
                              void* d_out, int out_size, void* d_ws, size_t ws_size,
                              hipStream_t stream) {
    const float* x   = (const float*)d_in[0];
    const int*   src = (const int*)d_in[1];
    const int*   dst = (const int*)d_in[2];
    const float* W0  = (const float*)d_in[3];
    const float* a0s = (const float*)d_in[4];
    const float* a0d = (const float*)d_in[5];
    const float* W1  = (const float*)d_in[6];
    const float* a1s = (const float*)d_in[7];
    const float* a1d = (const float*)d_in[8];
    const float* W2  = (const float*)d_in[9];
    const float* a2s = (const float*)d_in[10];
    const float* a2d = (const float*)d_in[11];
    const float* Wout= (const float*)d_in[12];
    const float* aos = (const float*)d_in[13];
    const float* aod = (const float*)d_in[14];

    int N = in_sizes[0] / NN_F_IN;
    int E = in_sizes[1];
    int Npad = ((N + 127) / 128) * 128;
    int T = Npad / 128;
    int nwg = T * (T + 1) / 2;   // one block per triangle tile
    float* out = (float*)d_out;

    char*  ws  = (char*)d_ws;
    size_t off = 0;
    auto alloc = [&](size_t bytes) -> void* {
        void* p = ws + off;
        off += bytes;
        off = (off + 255) & ~(size_t)255;
        return p;
    };
    size_t hbBytes = (size_t)N * 320 * 2;
    size_t znBytes = (size_t)Npad * NN_HID * 2;
    unsigned short* Hb = (unsigned short*)alloc(hbBytes > znBytes ? hbBytes : znBytes);
    short* znb = (short*)Hb;  // alias: znb live only between rownorm and gram
    unsigned short* Bl = (unsigned short*)alloc((size_t)N * NN_HID * 2);
    unsigned short* Bc = (unsigned short*)alloc((size_t)N * NN_HID * 2);
    size_t xbBytes = (size_t)N * NN_F_IN * 2;
    size_t p2Bytes = (size_t)2 * T * Npad * 4;
    void* XbP2d = alloc(xbBytes > p2Bytes ? xbBytes : p2Bytes);
    unsigned short* Xb  = (unsigned short*)XbP2d;  // live: castX..fc L0
    float*          P2d = (float*)XbP2d;           // live: memset..fold
    unsigned short* Wt0 = (unsigned short*)alloc((size_t)256 * 512 * 2);
    unsigned short* Wt1 = (unsigned short*)alloc((size_t)256 * 256 * 2);
    unsigned short* Wt2 = (unsigned short*)alloc((size_t)256 * 256 * 2);
    unsigned short* Wto = (unsigned short*)alloc((size_t)384 * 256 * 2);
    float* es     = (float*)alloc((size_t)N * NN_HEADS * 4);
    float* ed     = (float*)alloc((size_t)N * NN_HEADS * 4);
    float* Rrow   = (float*)alloc((size_t)N * 4);
    float* dvec   = (float*)alloc((size_t)N * 4);
    int*   counts = (int*)alloc((size_t)N * 4);
    int*   rs     = (int*)alloc((size_t)(N + 1) * 4);
    int*   cursor = (int*)alloc((size_t)N * 4);
    int*   csr    = (int*)alloc((size_t)E * 4);

    // ---- CSR build
    hipMemsetAsync(counts, 0, (size_t)N * 4, stream);
    count_kernel<<<(E + 255) / 256, 256, 0, stream>>>(dst, counts, E);
    scan_kernel<<<1, 1024, 0, stream>>>(counts, rs, cursor, N);
    scatter_kernel<<<(E + 255) / 256, 256, 0, stream>>>(src, dst, cursor, csr, E);

    // ---- casts
    cast_f2b_kernel<<<(N * NN_F_IN / 4 + 255) / 256, 256, 0, stream>>>(x, Xb, N * NN_F_IN / 4);
    castW_kernel<<<(256 * 512 + 255) / 256, 256, 0, stream>>>(W0, Wt0, 512, 256, 256);
    castW_kernel<<<(256 * 256 + 255) / 256, 256, 0, stream>>>(W1, Wt1, 256, 256, 256);
    castW_kernel<<<(256 * 256 + 255) / 256, 256, 0, stream>>>(W2, Wt2, 256, 256, 256);
    castW_kernel<<<(384 * 256 + 255) / 256, 256, 0, stream>>>(Wout, Wto, 256, 320, 384);

    int atGrid = (N * NN_HEADS + 255) / 256;
    int ghGrid = (N + 3) / 4;
    int mT64 = (N + 63) / 64;

    // ---- layer 0: Xb -> Hb -> Bl
    fc_mfma<<<dim3(4, mT64), 256, 0, stream>>>(Xb, Wt0, Hb, N, 512, 256, 256);
    attn_kernel<<<atGrid, 256, 0, stream>>>(Hb, a0s, a0d, es, ed, N, NN_FH);
    gather_hidden<<<ghGrid, 256, 0, stream>>>(Hb, es, ed, csr, rs, nullptr, Bl, N, -1.f);

    // ---- layer 1: Bl -> Hb -> Bc (beta = 0.5/3)
    fc_mfma<<<dim3(4, mT64), 256, 0, stream>>>(Bl, Wt1, Hb, N, 256, 256, 256);
    attn_kernel<<<atGrid, 256, 0, stream>>>(Hb, a1s, a1d, es, ed, N, NN_FH);
    gather_hidden<<<ghGrid, 256, 0, stream>>>(Hb, es, ed, csr, rs, Bl, Bc, N, LAMDA_F / 3.f);

    // ---- layer 2: Bc -> Hb -> Bl (beta = 0.5/4)
    fc_mfma<<<dim3(4, mT64), 256, 0, stream>>>(Bc, Wt2, Hb, N, 256, 256, 256);
    attn_kernel<<<atGrid, 256, 0, stream>>>(Hb, a2s, a2d, es, ed, N, NN_FH);
    gather_hidden<<<ghGrid, 256, 0, stream>>>(Hb, es, ed, csr, rs, Bc, Bl, N, LAMDA_F / 4.f);

    // ---- bind_loss(Bl): znb (aliases Hb), partial slots in P2d
    rownorm_kernel<<<N, 256, 0, stream>>>(Bl, znb, dvec, N);
    hipMemsetAsync(znb + (size_t)N * NN_HID, 0, (size_t)(Npad - N) * NN_HID * 2, stream);
    hipMemsetAsync(P2d, 0, (size_t)2 * T * Npad * 4, stream);
    gram_mfma<<<nwg, 256, 0, stream>>>(znb, P2d, N, T, nwg, Npad);
    fold_kernel<<<(N + 255) / 256, 256, 0, stream>>>(P2d, Rrow, N, 2 * T, Npad);
    loss_kernel<<<1, 1024, 0, stream>>>(Rrow, dvec, out + (size_t)N * NN_NCLASS, N);

    // ---- output layer: Bl -> Hb(320) -> d_out
    fc_mfma<<<dim3(5, mT64), 256, 0, stream>>>(Bl, Wto, Hb, N, 256, 320, 320);
    attn_kernel<<<atGrid, 256, 0, stream>>>(Hb, aos, aod, es, ed, N, NN_NCLASS);
    gather_final<<<N, NN_HEADS * NN_NCLASS, 0, stream>>>(Hb, es, ed, csr, rs, out, N);
}

// Round 7
// 452.136 us; speedup vs baseline: 2.0450x; 1.1680x over previous
//
#include <hip/hip_runtime.h>
#include <hip/hip_bf16.h>
#include <math.h>

#define NN_F_IN   512
#define NN_HID    256
#define NN_HEADS  8
#define NN_FH     32
#define NN_NCLASS 40
#define TAU_F     0.5f
#define LAMDA_F   0.5f

typedef __attribute__((ext_vector_type(8))) short bf16x8;
typedef __attribute__((ext_vector_type(4))) float f32x4;

static __device__ __forceinline__ float lrelu02(float x) { return x >= 0.f ? x : 0.2f * x; }
static __device__ __forceinline__ float elu1(float x)    { return x > 0.f ? x : expm1f(x); }
static __device__ __forceinline__ float b2f(unsigned short u) {
    unsigned int x = ((unsigned int)u) << 16;
    return __uint_as_float(x);
}
static __device__ __forceinline__ unsigned short f2b(float f) {
    __hip_bfloat16 hb = __float2bfloat16(f);
    return *reinterpret_cast<unsigned short*>(&hb);
}

// ---------------------------------------------------------------------------
// fp32 -> bf16 bulk cast (x input), 4 elems/thread
// ---------------------------------------------------------------------------
__global__ void cast_f2b_kernel(const float* __restrict__ src,
                                unsigned short* __restrict__ dst, int n4) {
    int i = blockIdx.x * 256 + threadIdx.x;
    if (i >= n4) return;
    float4 v = *(const float4*)(src + (size_t)i * 4);
    ushort4 o;
    o.x = f2b(v.x); o.y = f2b(v.y); o.z = f2b(v.z); o.w = f2b(v.w);
    *(ushort4*)(dst + (size_t)i * 4) = o;
}

// ---------------------------------------------------------------------------
// W [K][Nc] fp32  ->  Wt [Np][K] bf16 (transposed, zero-padded rows >= Nc)
// ---------------------------------------------------------------------------
__global__ void castW_kernel(const float* __restrict__ W, unsigned short* __restrict__ Wt,
                             int K, int Nc, int Np) {
    int idx = blockIdx.x * 256 + threadIdx.x;
    if (idx >= Np * K) return;
    int np = idx / K, k = idx - np * K;
    float v = (np < Nc) ? W[(size_t)k * Nc + np] : 0.f;
    Wt[idx] = f2b(v);
}

// ---------------------------------------------------------------------------
// MFMA GEMM: H[m][col] = sum_k A[m][k] * B[col][k], A/B bf16, H bf16.
// Block = 4 waves 2x2 -> 64x64 tile; wave = 32x32 = 2x2 frags of 16x16x32.
// ---------------------------------------------------------------------------
__global__ __launch_bounds__(256) void fc_mfma(const unsigned short* __restrict__ A,
                                               const unsigned short* __restrict__ B,
                                               unsigned short* __restrict__ H,
                                               int M, int K, int ncols, int ldH) {
    int t = threadIdx.x, lane = t & 63, wid = t >> 6;
    int wrow = wid >> 1, wcol = wid & 1;
    int l15 = lane & 15, lg = lane >> 4;
    int mbase = blockIdx.y * 64 + wrow * 32;
    int nbase = blockIdx.x * 64 + wcol * 32;

    const unsigned short* Ap[2];
    const unsigned short* Bp[2];
#pragma unroll
    for (int m = 0; m < 2; ++m) {
        int rr = mbase + m * 16 + l15;
        if (rr > M - 1) rr = M - 1;
        Ap[m] = A + (size_t)rr * K + lg * 8;
        Bp[m] = B + (size_t)(nbase + m * 16 + l15) * K + lg * 8;
    }
    f32x4 acc[2][2];
#pragma unroll
    for (int m = 0; m < 2; ++m)
#pragma unroll
        for (int nn = 0; nn < 2; ++nn)
#pragma unroll
            for (int r = 0; r < 4; ++r) acc[m][nn][r] = 0.f;

    bf16x8 aP[2], bP[2], aQ[2], bQ[2];
#pragma unroll
    for (int m = 0; m < 2; ++m) {
        aP[m] = *(const bf16x8*)(Ap[m]);
        bP[m] = *(const bf16x8*)(Bp[m]);
    }
    int nhalf = K >> 6;
    int kk = 32;
    for (int it = 0; it < nhalf; ++it) {
#pragma unroll
        for (int m = 0; m < 2; ++m) {
            aQ[m] = *(const bf16x8*)(Ap[m] + kk);
            bQ[m] = *(const bf16x8*)(Bp[m] + kk);
        }
#pragma unroll
        for (int m = 0; m < 2; ++m)
#pragma unroll
            for (int nn = 0; nn < 2; ++nn)
                acc[m][nn] = __builtin_amdgcn_mfma_f32_16x16x32_bf16(aP[m], bP[nn], acc[m][nn], 0, 0, 0);
        if (it + 1 < nhalf) {
#pragma unroll
            for (int m = 0; m < 2; ++m) {
                aP[m] = *(const bf16x8*)(Ap[m] + kk + 32);
                bP[m] = *(const bf16x8*)(Bp[m] + kk + 32);
            }
        }
#pragma unroll
        for (int m = 0; m < 2; ++m)
#pragma unroll
            for (int nn = 0; nn < 2; ++nn)
                acc[m][nn] = __builtin_amdgcn_mfma_f32_16x16x32_bf16(aQ[m], bQ[nn], acc[m][nn], 0, 0, 0);
        kk += 64;
    }
#pragma unroll
    for (int m = 0; m < 2; ++m) {
#pragma unroll
        for (int nn = 0; nn < 2; ++nn) {
            int col = nbase + nn * 16 + l15;
            if (col >= ncols) continue;
#pragma unroll
            for (int r = 0; r < 4; ++r) {
                int row = mbase + m * 16 + lg * 4 + r;
                if (row < M) H[(size_t)row * ldH + col] = f2b(acc[m][nn][r]);
            }
        }
    }
}

// ---------------------------------------------------------------------------
// es/ed dot products (Hm bf16)
// ---------------------------------------------------------------------------
__global__ void attn_kernel(const unsigned short* __restrict__ Hm, const float* __restrict__ As,
                            const float* __restrict__ Ad, float* __restrict__ es,
                            float* __restrict__ ed, int n, int df) {
    int idx = blockIdx.x * blockDim.x + threadIdx.x;
    if (idx >= n * NN_HEADS) return;
    int nn = idx / NN_HEADS, hh = idx - nn * NN_HEADS;
    const unsigned short* hp = Hm + (size_t)nn * NN_HEADS * df + hh * df;
    const float* ap = As + hh * df;
    const float* bp = Ad + hh * df;
    float s1 = 0.f, s2 = 0.f;
    for (int d = 0; d < df; d += 4) {
        ushort4 hv = *(const ushort4*)(hp + d);
        float4 av = *(const float4*)(ap + d);
        float4 bv = *(const float4*)(bp + d);
        float h0 = b2f(hv.x), h1 = b2f(hv.y), h2 = b2f(hv.z), h3 = b2f(hv.w);
        s1 += h0 * av.x + h1 * av.y + h2 * av.z + h3 * av.w;
        s2 += h0 * bv.x + h1 * bv.y + h2 * bv.z + h3 * bv.w;
    }
    es[idx] = s1;
    ed[idx] = s2;
}

// ---------------------------------------------------------------------------
// CSR build
// ---------------------------------------------------------------------------
__global__ void count_kernel(const int* __restrict__ dst, int* __restrict__ counts, int E) {
    int e = blockIdx.x * blockDim.x + threadIdx.x;
    if (e < E) atomicAdd(&counts[dst[e]], 1);
}

__global__ void scan_kernel(const int* __restrict__ counts, int* __restrict__ row_start,
                            int* __restrict__ cursor, int n) {
    __shared__ int s[1024];
    int t  = threadIdx.x;
    int ch = (n + 1023) / 1024;
    int lo = t * ch;
    int sum = 0;
    for (int j = 0; j < ch; ++j) {
        int i = lo + j;
        if (i < n) sum += counts[i];
    }
    s[t] = sum;
    __syncthreads();
    for (int off = 1; off < 1024; off <<= 1) {
        int v = 0;
        if (t >= off) v = s[t - off];
        __syncthreads();
        s[t] += v;
        __syncthreads();
    }
    int run = (t == 0) ? 0 : s[t - 1];
    for (int j = 0; j < ch; ++j) {
        int i = lo + j;
        if (i < n) {
            row_start[i] = run;
            cursor[i] = run;
            run += counts[i];
        }
    }
    if (t == 1023) row_start[n] = s[1023];
}

__global__ void scatter_kernel(const int* __restrict__ src, const int* __restrict__ dst,
                               int* __restrict__ cursor, int* __restrict__ csr_src, int E) {
    int e = blockIdx.x * blockDim.x + threadIdx.x;
    if (e < E) {
        int d   = dst[e];
        int pos = atomicAdd(&cursor[d], 1);
        csr_src[pos] = src[e];
    }
}

// ---------------------------------------------------------------------------
// Hidden-layer gather, SINGLE PASS, 8-deep load batching (MLP).
// ---------------------------------------------------------------------------
__global__ __launch_bounds__(256) void gather_hidden(
    const unsigned short* __restrict__ Hm, const float* __restrict__ es,
    const float* __restrict__ ed, const int* __restrict__ csr_src,
    const int* __restrict__ row_start, const unsigned short* __restrict__ last,
    unsigned short* __restrict__ out, int n, float beta) {
    int lane = threadIdx.x & 63;
    int nn   = blockIdx.x * 4 + (threadIdx.x >> 6);
    if (nn >= n) return;
    int s0 = row_start[nn], s1 = row_start[nn + 1];
    int h2 = lane >> 3;
    float edh = ed[nn * NN_HEADS + h2];

    float zacc = 0.f;
    float a0 = 0.f, a1 = 0.f, a2 = 0.f, a3 = 0.f;
    for (int e = s0; e < s1; e += 8) {
        int c = s1 - e;
        int idx[8];
#pragma unroll
        for (int j = 0; j < 8; ++j) idx[j] = csr_src[(j < c) ? e + j : e];
        float q[8];
#pragma unroll
        for (int j = 0; j < 8; ++j) q[j] = es[idx[j] * NN_HEADS + h2];
        ushort4 r[8];
#pragma unroll
        for (int j = 0; j < 8; ++j) r[j] = *(const ushort4*)&Hm[(size_t)idx[j] * NN_HID + lane * 4];
#pragma unroll
        for (int j = 0; j < 8; ++j) {
            if (j < c) {
                float w = expf(lrelu02(q[j] + edh));
                zacc += w;
                a0 += w * b2f(r[j].x); a1 += w * b2f(r[j].y);
                a2 += w * b2f(r[j].z); a3 += w * b2f(r[j].w);
            }
        }
    }
    float zinv = 1.f / zacc;
    float v0 = elu1(a0 * zinv), v1 = elu1(a1 * zinv), v2 = elu1(a2 * zinv), v3 = elu1(a3 * zinv);
    if (beta >= 0.f) {
        ushort4 lv = *(const ushort4*)&last[(size_t)nn * NN_HID + lane * 4];
        v0 = beta * b2f(lv.x) + (1.f - beta) * v0;
        v1 = beta * b2f(lv.y) + (1.f - beta) * v1;
        v2 = beta * b2f(lv.z) + (1.f - beta) * v2;
        v3 = beta * b2f(lv.w) + (1.f - beta) * v3;
    }
    ushort4 o;
    o.x = f2b(v0); o.y = f2b(v1); o.z = f2b(v2); o.w = f2b(v3);
    *(ushort4*)&out[(size_t)nn * NN_HID + lane * 4] = o;
}

// ---------------------------------------------------------------------------
// Final layer gather, SINGLE PASS, 8-deep batching + head-mean + log_softmax
// ---------------------------------------------------------------------------
__global__ void gather_final(const unsigned short* __restrict__ Hm, const float* __restrict__ es,
                             const float* __restrict__ ed, const int* __restrict__ csr_src,
                             const int* __restrict__ row_start, float* __restrict__ dout, int n) {
    int nn = blockIdx.x;
    __shared__ float accs[NN_HEADS * NN_NCLASS];
    int t = threadIdx.x;  // 0..319
    int s0 = row_start[nn], s1 = row_start[nn + 1];
    int hh = t / NN_NCLASS;
    float edh = ed[nn * NN_HEADS + hh];
    float acc = 0.f, zacc = 0.f;
    const int LD = NN_HEADS * NN_NCLASS;
    for (int e = s0; e < s1; e += 8) {
        int c = s1 - e;
        int idx[8];
#pragma unroll
        for (int j = 0; j < 8; ++j) idx[j] = csr_src[(j < c) ? e + j : e];
        float q[8];
#pragma unroll
        for (int j = 0; j < 8; ++j) q[j] = es[idx[j] * NN_HEADS + hh];
        float v[8];
#pragma unroll
        for (int j = 0; j < 8; ++j) v[j] = b2f(Hm[(size_t)idx[j] * LD + t]);
#pragma unroll
        for (int j = 0; j < 8; ++j) {
            if (j < c) {
                float w = expf(lrelu02(q[j] + edh));
                zacc += w;
                acc += w * v[j];
            }
        }
    }
    accs[t] = acc / zacc;
    __syncthreads();
    if (t < 64) {
        float v = -INFINITY;
        if (t < NN_NCLASS) {
            float sacc = 0.f;
#pragma unroll
            for (int h2 = 0; h2 < NN_HEADS; ++h2) sacc += accs[h2 * NN_NCLASS + t];
            v = sacc * (1.f / NN_HEADS);
        }
        float mx = v;
#pragma unroll
        for (int o = 1; o < 64; o <<= 1) mx = fmaxf(mx, __shfl_xor(mx, o, 64));
        float ex = (t < NN_NCLASS) ? expf(v - mx) : 0.f;
        float se = ex;
#pragma unroll
        for (int o = 1; o < 64; o <<= 1) se += __shfl_xor(se, o, 64);
        if (t < NN_NCLASS) dout[(size_t)nn * NN_NCLASS + t] = (v - mx) - logf(se);
    }
}

// ---------------------------------------------------------------------------
// Row-normalize (bf16 in) + bf16 zn + analytic diagonal
// ---------------------------------------------------------------------------
__global__ void rownorm_kernel(const unsigned short* __restrict__ z, short* __restrict__ znb,
                               float* __restrict__ dvec, int n) {
    int nn = blockIdx.x;
    int t  = threadIdx.x;  // 256
    float v  = b2f(z[(size_t)nn * NN_HID + t]);
    float sq = v * v;
#pragma unroll
    for (int o = 1; o < 64; o <<= 1) sq += __shfl_xor(sq, o, 64);
    __shared__ float ws[4];
    if ((t & 63) == 0) ws[t >> 6] = sq;
    __syncthreads();
    float s = ws[0] + ws[1] + ws[2] + ws[3];
    float m = fmaxf(sqrtf(s), 1e-12f);
    znb[(size_t)nn * NN_HID + t] = (short)f2b(v / m);
    if (t == 0) dvec[nn] = expf((s / (m * m)) * (1.f / TAU_F));
}

// ---------------------------------------------------------------------------
// Symmetric gram rowsums, LDS-staged pipelined GEMM, NO atomics.
// Block = 128x128 triangle tile, 4 waves 2x2, BK=64, single-buffer 2-barrier.
// Staging: 4 waves cooperatively load A+B K-slab (each row ONCE), reg->LDS
// with XOR chunk swizzle (slot = chunk ^ (row&7)); write side linear via
// pre-swizzled global source; reads use same XOR -> balanced banks.
// kt+1 global loads issue before kt's MFMAs (async split).
// Partial sums to disjoint P2d slots (validated R5/R6 scheme).
// ---------------------------------------------------------------------------
__global__ __launch_bounds__(256) void gram_mfma(const short* __restrict__ znb,
                                                 float* __restrict__ P2d, int n,
                                                 int T, int nwg, int Npad) {
    __shared__ short As[128 * 64];
    __shared__ short Bs[128 * 64];

    // bijective XCD swizzle + triangle decode
    int b = blockIdx.x;
    int q = nwg >> 3, r8 = nwg & 7, xc = b & 7, oo = b >> 3;
    int sid = (xc < r8 ? xc * (q + 1) : r8 * (q + 1) + (xc - r8) * q) + oo;
    int bi = 0, rem = sid;
    while (rem >= T - bi) { rem -= T - bi; ++bi; }
    int bj = bi + rem;
    int i0 = bi * 128, j0 = bj * 128;

    int t    = threadIdx.x;
    int lane = t & 63;
    int wid  = t >> 6;
    int wrow = wid >> 1, wcol = wid & 1;
    int l15  = lane & 15, lg = lane >> 4;
    int srow = lane >> 3;   // 0..7 within 8-row staging group
    int sch  = lane & 7;    // 0..7 chunk slot

    f32x4 acc[4][4];
#pragma unroll
    for (int m = 0; m < 4; ++m)
#pragma unroll
        for (int nn = 0; nn < 4; ++nn)
#pragma unroll
            for (int r = 0; r < 4; ++r) acc[m][nn][r] = 0.f;

    bf16x8 sa[4], sb[4];
    // prologue: load kt=0 slab into regs (pre-swizzled source chunk)
#pragma unroll
    for (int s = 0; s < 4; ++s) {
        int row = wid * 32 + s * 8 + srow;
        int gch = sch ^ (row & 7);
        sa[s] = *(const bf16x8*)(znb + (size_t)(i0 + row) * NN_HID + gch * 8);
        sb[s] = *(const bf16x8*)(znb + (size_t)(j0 + row) * NN_HID + gch * 8);
    }

#pragma unroll
    for (int kt = 0; kt < 4; ++kt) {
        // write staged regs to LDS (linear slot = sch)
#pragma unroll
        for (int s = 0; s < 4; ++s) {
            int row = wid * 32 + s * 8 + srow;
            *(bf16x8*)(&As[row * 64 + sch * 8]) = sa[s];
            *(bf16x8*)(&Bs[row * 64 + sch * 8]) = sb[s];
        }
        __syncthreads();
        // issue next slab's global loads (overlap with compute)
        if (kt < 3) {
            int kb = (kt + 1) * 64;
#pragma unroll
            for (int s = 0; s < 4; ++s) {
                int row = wid * 32 + s * 8 + srow;
                int gch = sch ^ (row & 7);
                sa[s] = *(const bf16x8*)(znb + (size_t)(i0 + row) * NN_HID + kb + gch * 8);
                sb[s] = *(const bf16x8*)(znb + (size_t)(j0 + row) * NN_HID + kb + gch * 8);
            }
        }
        // compute on LDS slab: 2 k-substeps of 32
#pragma unroll
        for (int ks = 0; ks < 2; ++ks) {
            bf16x8 av[4], bv[4];
#pragma unroll
            for (int m = 0; m < 4; ++m) {
                int Ra = wrow * 64 + m * 16 + l15;
                int Rb = wcol * 64 + m * 16 + l15;
                int ca = (ks * 4 + lg) ^ (Ra & 7);
                int cb = (ks * 4 + lg) ^ (Rb & 7);
                av[m] = *(const bf16x8*)(&As[Ra * 64 + ca * 8]);
                bv[m] = *(const bf16x8*)(&Bs[Rb * 64 + cb * 8]);
            }
#pragma unroll
            for (int m = 0; m < 4; ++m)
#pragma unroll
                for (int nn = 0; nn < 4; ++nn)
                    acc[m][nn] = __builtin_amdgcn_mfma_f32_16x16x32_bf16(av[m], bv[nn], acc[m][nn], 0, 0, 0);
        }
        __syncthreads();  // protect LDS before next write
    }

    // epilogue: acc -> exp(acc/tau), masked; rowsums + colsums (symmetry)
    int i0w = i0 + wrow * 64;
    int j0w = j0 + wcol * 64;
    bool diag = (bj == bi);
#pragma unroll
    for (int m = 0; m < 4; ++m)
#pragma unroll
        for (int nn = 0; nn < 4; ++nn) {
            int gj = j0w + nn * 16 + l15;
            bool jok = gj < n;
#pragma unroll
            for (int r = 0; r < 4; ++r) {
                int gi = i0w + m * 16 + lg * 4 + r;
                acc[m][nn][r] = (jok && gi < n) ? expf(acc[m][nn][r] * (1.f / TAU_F)) : 0.f;
            }
        }
    float* rowslot = P2d + (size_t)(2 * bj + wcol) * Npad;
#pragma unroll
    for (int m = 0; m < 4; ++m) {
#pragma unroll
        for (int r = 0; r < 4; ++r) {
            float v = acc[m][0][r] + acc[m][1][r] + acc[m][2][r] + acc[m][3][r];
            v += __shfl_xor(v, 1, 64);
            v += __shfl_xor(v, 2, 64);
            v += __shfl_xor(v, 4, 64);
            v += __shfl_xor(v, 8, 64);
            if (l15 == 0) {
                int gi = i0w + m * 16 + lg * 4 + r;
                if (gi < n) rowslot[gi] = v;
            }
        }
    }
    if (!diag) {
        float* colslot = P2d + (size_t)(2 * bi + wrow) * Npad;
#pragma unroll
        for (int nn = 0; nn < 4; ++nn) {
            float v = 0.f;
#pragma unroll
            for (int m = 0; m < 4; ++m)
#pragma unroll
                for (int r = 0; r < 4; ++r) v += acc[m][nn][r];
            v += __shfl_xor(v, 16, 64);
            v += __shfl_xor(v, 32, 64);
            if (lg == 0) {
                int gj = j0w + nn * 16 + l15;
                if (gj < n) colslot[gj] = v;
            }
        }
    }
}

// ---------------------------------------------------------------------------
// Parallel fold of partial slots: R[i] = sum_sl P2d[sl][i]
// ---------------------------------------------------------------------------
__global__ void fold_kernel(const float* __restrict__ P2d, float* __restrict__ R,
                            int n, int slots, int Npad) {
    int i = blockIdx.x * 256 + threadIdx.x;
    if (i >= n) return;
    const float* p = P2d + i;
    float s0 = 0.f, s1 = 0.f, s2 = 0.f, s3 = 0.f;
    int sl = 0;
    for (; sl + 4 <= slots; sl += 4) {
        s0 += p[(size_t)(sl + 0) * Npad];
        s1 += p[(size_t)(sl + 1) * Npad];
        s2 += p[(size_t)(sl + 2) * Npad];
        s3 += p[(size_t)(sl + 3) * Npad];
    }
    for (; sl < slots; ++sl) s0 += p[(size_t)sl * Npad];
    R[i] = (s0 + s1) + (s2 + s3);
}

__global__ void loss_kernel(const float* __restrict__ R, const float* __restrict__ dvec,
                            float* __restrict__ out_loss, int n) {
    __shared__ float s[1024];
    int t = threadIdx.x;
    float sum = 0.f;
    for (int i = t; i < n; i += 1024) {
        float d   = dvec[i];
        float off = R[i] - d;
        sum += -logf(d / (off + off));
    }
    s[t] = sum;
    __syncthreads();
    for (int o = 512; o > 0; o >>= 1) {
        if (t < o) s[t] += s[t + o];
        __syncthreads();
    }
    if (t == 0) *out_loss = s[0] / n;
}

// ---------------------------------------------------------------------------
extern "C" void kernel_launch(void* const* d_in, const int* in_sizes, int n_in,
                              void* d_out, int out_size, void* d_ws, size_t ws_size,
                              hipStream_t stream) {
    const float* x   = (const float*)d_in[0];
    const int*   src = (const int*)d_in[1];
    const int*   dst = (const int*)d_in[2];
    const float* W0  = (const float*)d_in[3];
    const float* a0s = (const float*)d_in[4];
    const float* a0d = (const float*)d_in[5];
    const float* W1  = (const float*)d_in[6];
    const float* a1s = (const float*)d_in[7];
    const float* a1d = (const float*)d_in[8];
    const float* W2  = (const float*)d_in[9];
    const float* a2s = (const float*)d_in[10];
    const float* a2d = (const float*)d_in[11];
    const float* Wout= (const float*)d_in[12];
    const float* aos = (const float*)d_in[13];
    const float* aod = (const float*)d_in[14];

    int N = in_sizes[0] / NN_F_IN;
    int E = in_sizes[1];
    int Npad = ((N + 127) / 128) * 128;
    int T = Npad / 128;
    int nwg = T * (T + 1) / 2;   // one block per triangle tile
    float* out = (float*)d_out;

    char*  ws  = (char*)d_ws;
    size_t off = 0;
    auto alloc = [&](size_t bytes) -> void* {
        void* p = ws + off;
        off += bytes;
        off = (off + 255) & ~(size_t)255;
        return p;
    };
    size_t hbBytes = (size_t)N * 320 * 2;
    size_t znBytes = (size_t)Npad * NN_HID * 2;
    unsigned short* Hb = (unsigned short*)alloc(hbBytes > znBytes ? hbBytes : znBytes);
    short* znb = (short*)Hb;  // alias: znb live only between rownorm and gram
    unsigned short* Bl = (unsigned short*)alloc((size_t)N * NN_HID * 2);
    unsigned short* Bc = (unsigned short*)alloc((size_t)N * NN_HID * 2);
    size_t xbBytes = (size_t)N * NN_F_IN * 2;
    size_t p2Bytes = (size_t)2 * T * Npad * 4;
    void* XbP2d = alloc(xbBytes > p2Bytes ? xbBytes : p2Bytes);
    unsigned short* Xb  = (unsigned short*)XbP2d;  // live: castX..fc L0
    float*          P2d = (float*)XbP2d;           // live: memset..fold
    unsigned short* Wt0 = (unsigned short*)alloc((size_t)256 * 512 * 2);
    unsigned short* Wt1 = (unsigned short*)alloc((size_t)256 * 256 * 2);
    unsigned short* Wt2 = (unsigned short*)alloc((size_t)256 * 256 * 2);
    unsigned short* Wto = (unsigned short*)alloc((size_t)384 * 256 * 2);
    float* es     = (float*)alloc((size_t)N * NN_HEADS * 4);
    float* ed     = (float*)alloc((size_t)N * NN_HEADS * 4);
    float* Rrow   = (float*)alloc((size_t)N * 4);
    float* dvec   = (float*)alloc((size_t)N * 4);
    int*   counts = (int*)alloc((size_t)N * 4);
    int*   rs     = (int*)alloc((size_t)(N + 1) * 4);
    int*   cursor = (int*)alloc((size_t)N * 4);
    int*   csr    = (int*)alloc((size_t)E * 4);

    // ---- CSR build
    hipMemsetAsync(counts, 0, (size_t)N * 4, stream);
    count_kernel<<<(E + 255) / 256, 256, 0, stream>>>(dst, counts, E);
    scan_kernel<<<1, 1024, 0, stream>>>(counts, rs, cursor, N);
    scatter_kernel<<<(E + 255) / 256, 256, 0, stream>>>(src, dst, cursor, csr, E);

    // ---- casts
    cast_f2b_kernel<<<(N * NN_F_IN / 4 + 255) / 256, 256, 0, stream>>>(x, Xb, N * NN_F_IN / 4);
    castW_kernel<<<(256 * 512 + 255) / 256, 256, 0, stream>>>(W0, Wt0, 512, 256, 256);
    castW_kernel<<<(256 * 256 + 255) / 256, 256, 0, stream>>>(W1, Wt1, 256, 256, 256);
    castW_kernel<<<(256 * 256 + 255) / 256, 256, 0, stream>>>(W2, Wt2, 256, 256, 256);
    castW_kernel<<<(384 * 256 + 255) / 256, 256, 0, stream>>>(Wout, Wto, 256, 320, 384);

    int atGrid = (N * NN_HEADS + 255) / 256;
    int ghGrid = (N + 3) / 4;
    int mT64 = (N + 63) / 64;

    // ---- layer 0: Xb -> Hb -> Bl
    fc_mfma<<<dim3(4, mT64), 256, 0, stream>>>(Xb, Wt0, Hb, N, 512, 256, 256);
    attn_kernel<<<atGrid, 256, 0, stream>>>(Hb, a0s, a0d, es, ed, N, NN_FH);
    gather_hidden<<<ghGrid, 256, 0, stream>>>(Hb, es, ed, csr, rs, nullptr, Bl, N, -1.f);

    // ---- layer 1: Bl -> Hb -> Bc (beta = 0.5/3)
    fc_mfma<<<dim3(4, mT64), 256, 0, stream>>>(Bl, Wt1, Hb, N, 256, 256, 256);
    attn_kernel<<<atGrid, 256, 0, stream>>>(Hb, a1s, a1d, es, ed, N, NN_FH);
    gather_hidden<<<ghGrid, 256, 0, stream>>>(Hb, es, ed, csr, rs, Bl, Bc, N, LAMDA_F / 3.f);

    // ---- layer 2: Bc -> Hb -> Bl (beta = 0.5/4)
    fc_mfma<<<dim3(4, mT64), 256, 0, stream>>>(Bc, Wt2, Hb, N, 256, 256, 256);
    attn_kernel<<<atGrid, 256, 0, stream>>>(Hb, a2s, a2d, es, ed, N, NN_FH);
    gather_hidden<<<ghGrid, 256, 0, stream>>>(Hb, es, ed, csr, rs, Bc, Bl, N, LAMDA_F / 4.f);

    // ---- bind_loss(Bl): znb (aliases Hb), partial slots in P2d
    rownorm_kernel<<<N, 256, 0, stream>>>(Bl, znb, dvec, N);
    hipMemsetAsync(znb + (size_t)N * NN_HID, 0, (size_t)(Npad - N) * NN_HID * 2, stream);
    hipMemsetAsync(P2d, 0, (size_t)2 * T * Npad * 4, stream);
    gram_mfma<<<nwg, 256, 0, stream>>>(znb, P2d, N, T, nwg, Npad);
    fold_kernel<<<(N + 255) / 256, 256, 0, stream>>>(P2d, Rrow, N, 2 * T, Npad);
    loss_kernel<<<1, 1024, 0, stream>>>(Rrow, dvec, out + (size_t)N * NN_NCLASS, N);

    // ---- output layer: Bl -> Hb(320) -> d_out
    fc_mfma<<<dim3(5, mT64), 256, 0, stream>>>(Bl, Wto, Hb, N, 256, 320, 320);
    attn_kernel<<<atGrid, 256, 0, stream>>>(Hb, aos, aod, es, ed, N, NN_NCLASS);
    gather_final<<<N, NN_HEADS * NN_NCLASS, 0, stream>>>(Hb, es, ed, csr, rs, out, N);
}

// Round 8
// 432.871 us; speedup vs baseline: 2.1360x; 1.0445x over previous
//
#include <hip/hip_runtime.h>
#include <hip/hip_bf16.h>
#include <math.h>

#define NN_F_IN   512
#define NN_HID    256
#define NN_HEADS  8
#define NN_FH     32
#define NN_NCLASS 40
#define TAU_F     0.5f
#define LAMDA_F   0.5f

typedef __attribute__((ext_vector_type(8))) short bf16x8;
typedef __attribute__((ext_vector_type(4))) float f32x4;

static __device__ __forceinline__ float lrelu02(float x) { return x >= 0.f ? x : 0.2f * x; }
static __device__ __forceinline__ float elu1(float x)    { return x > 0.f ? x : expm1f(x); }
static __device__ __forceinline__ float b2f(unsigned short u) {
    unsigned int x = ((unsigned int)u) << 16;
    return __uint_as_float(x);
}
static __device__ __forceinline__ unsigned short f2b(float f) {
    __hip_bfloat16 hb = __float2bfloat16(f);
    return *reinterpret_cast<unsigned short*>(&hb);
}

// ---------------------------------------------------------------------------
// fp32 -> bf16 bulk cast (x input), 4 elems/thread
// ---------------------------------------------------------------------------
__global__ void cast_f2b_kernel(const float* __restrict__ src,
                                unsigned short* __restrict__ dst, int n4) {
    int i = blockIdx.x * 256 + threadIdx.x;
    if (i >= n4) return;
    float4 v = *(const float4*)(src + (size_t)i * 4);
    ushort4 o;
    o.x = f2b(v.x); o.y = f2b(v.y); o.z = f2b(v.z); o.w = f2b(v.w);
    *(ushort4*)(dst + (size_t)i * 4) = o;
}

// ---------------------------------------------------------------------------
// W [K][Nc] fp32  ->  Wt [Np][K] bf16 (transposed, zero-padded rows >= Nc)
// ---------------------------------------------------------------------------
__global__ void castW_kernel(const float* __restrict__ W, unsigned short* __restrict__ Wt,
                             int K, int Nc, int Np) {
    int idx = blockIdx.x * 256 + threadIdx.x;
    if (idx >= Np * K) return;
    int np = idx / K, k = idx - np * K;
    float v = (np < Nc) ? W[(size_t)k * Nc + np] : 0.f;
    Wt[idx] = f2b(v);
}

// ---------------------------------------------------------------------------
// MFMA GEMM: H[m][col] = sum_k A[m][k] * B[col][k], A/B bf16, H bf16.
// Block = 4 waves 2x2 -> 64x64 tile; wave = 32x32 = 2x2 frags of 16x16x32.
// ---------------------------------------------------------------------------
__global__ __launch_bounds__(256) void fc_mfma(const unsigned short* __restrict__ A,
                                               const unsigned short* __restrict__ B,
                                               unsigned short* __restrict__ H,
                                               int M, int K, int ncols, int ldH) {
    int t = threadIdx.x, lane = t & 63, wid = t >> 6;
    int wrow = wid >> 1, wcol = wid & 1;
    int l15 = lane & 15, lg = lane >> 4;
    int mbase = blockIdx.y * 64 + wrow * 32;
    int nbase = blockIdx.x * 64 + wcol * 32;

    const unsigned short* Ap[2];
    const unsigned short* Bp[2];
#pragma unroll
    for (int m = 0; m < 2; ++m) {
        int rr = mbase + m * 16 + l15;
        if (rr > M - 1) rr = M - 1;
        Ap[m] = A + (size_t)rr * K + lg * 8;
        Bp[m] = B + (size_t)(nbase + m * 16 + l15) * K + lg * 8;
    }
    f32x4 acc[2][2];
#pragma unroll
    for (int m = 0; m < 2; ++m)
#pragma unroll
        for (int nn = 0; nn < 2; ++nn)
#pragma unroll
            for (int r = 0; r < 4; ++r) acc[m][nn][r] = 0.f;

    bf16x8 aP[2], bP[2], aQ[2], bQ[2];
#pragma unroll
    for (int m = 0; m < 2; ++m) {
        aP[m] = *(const bf16x8*)(Ap[m]);
        bP[m] = *(const bf16x8*)(Bp[m]);
    }
    int nhalf = K >> 6;
    int kk = 32;
    for (int it = 0; it < nhalf; ++it) {
#pragma unroll
        for (int m = 0; m < 2; ++m) {
            aQ[m] = *(const bf16x8*)(Ap[m] + kk);
            bQ[m] = *(const bf16x8*)(Bp[m] + kk);
        }
#pragma unroll
        for (int m = 0; m < 2; ++m)
#pragma unroll
            for (int nn = 0; nn < 2; ++nn)
                acc[m][nn] = __builtin_amdgcn_mfma_f32_16x16x32_bf16(aP[m], bP[nn], acc[m][nn], 0, 0, 0);
        if (it + 1 < nhalf) {
#pragma unroll
            for (int m = 0; m < 2; ++m) {
                aP[m] = *(const bf16x8*)(Ap[m] + kk + 32);
                bP[m] = *(const bf16x8*)(Bp[m] + kk + 32);
            }
        }
#pragma unroll
        for (int m = 0; m < 2; ++m)
#pragma unroll
            for (int nn = 0; nn < 2; ++nn)
                acc[m][nn] = __builtin_amdgcn_mfma_f32_16x16x32_bf16(aQ[m], bQ[nn], acc[m][nn], 0, 0, 0);
        kk += 64;
    }
#pragma unroll
    for (int m = 0; m < 2; ++m) {
#pragma unroll
        for (int nn = 0; nn < 2; ++nn) {
            int col = nbase + nn * 16 + l15;
            if (col >= ncols) continue;
#pragma unroll
            for (int r = 0; r < 4; ++r) {
                int row = mbase + m * 16 + lg * 4 + r;
                if (row < M) H[(size_t)row * ldH + col] = f2b(acc[m][nn][r]);
            }
        }
    }
}

// ---------------------------------------------------------------------------
// es/ed dot products (Hm bf16)
// ---------------------------------------------------------------------------
__global__ void attn_kernel(const unsigned short* __restrict__ Hm, const float* __restrict__ As,
                            const float* __restrict__ Ad, float* __restrict__ es,
                            float* __restrict__ ed, int n, int df) {
    int idx = blockIdx.x * blockDim.x + threadIdx.x;
    if (idx >= n * NN_HEADS) return;
    int nn = idx / NN_HEADS, hh = idx - nn * NN_HEADS;
    const unsigned short* hp = Hm + (size_t)nn * NN_HEADS * df + hh * df;
    const float* ap = As + hh * df;
    const float* bp = Ad + hh * df;
    float s1 = 0.f, s2 = 0.f;
    for (int d = 0; d < df; d += 4) {
        ushort4 hv = *(const ushort4*)(hp + d);
        float4 av = *(const float4*)(ap + d);
        float4 bv = *(const float4*)(bp + d);
        float h0 = b2f(hv.x), h1 = b2f(hv.y), h2 = b2f(hv.z), h3 = b2f(hv.w);
        s1 += h0 * av.x + h1 * av.y + h2 * av.z + h3 * av.w;
        s2 += h0 * bv.x + h1 * bv.y + h2 * bv.z + h3 * bv.w;
    }
    es[idx] = s1;
    ed[idx] = s2;
}

// ---------------------------------------------------------------------------
// Edge weights: one exp per (edge,head). wC[p][h] in CSR order, zinv[n][h].
// 1 wave per node, lane = slot*8 + head.
// ---------------------------------------------------------------------------
__global__ __launch_bounds__(256) void edge_wz(
    const float* __restrict__ es, const float* __restrict__ ed,
    const int* __restrict__ csr_src, const int* __restrict__ row_start,
    float* __restrict__ wC, float* __restrict__ zinv, int n) {
    int lane = threadIdx.x & 63;
    int nn   = blockIdx.x * 4 + (threadIdx.x >> 6);
    if (nn >= n) return;
    int s0 = row_start[nn], s1 = row_start[nn + 1];
    int h    = lane & 7;
    int slot = lane >> 3;
    float edh = ed[nn * NN_HEADS + h];
    float z = 0.f;
    for (int e = s0 + slot; e < s1; e += 8) {
        int sv = csr_src[e];
        float w = expf(lrelu02(es[sv * NN_HEADS + h] + edh));
        wC[(size_t)e * NN_HEADS + h] = w;
        z += w;
    }
    z += __shfl_xor(z, 8, 64);
    z += __shfl_xor(z, 16, 64);
    z += __shfl_xor(z, 32, 64);
    if (slot == 0) zinv[nn * NN_HEADS + h] = 1.f / z;
}

// ---------------------------------------------------------------------------
// CSR build
// ---------------------------------------------------------------------------
__global__ void count_kernel(const int* __restrict__ dst, int* __restrict__ counts, int E) {
    int e = blockIdx.x * blockDim.x + threadIdx.x;
    if (e < E) atomicAdd(&counts[dst[e]], 1);
}

__global__ void scan_kernel(const int* __restrict__ counts, int* __restrict__ row_start,
                            int* __restrict__ cursor, int n) {
    __shared__ int s[1024];
    int t  = threadIdx.x;
    int ch = (n + 1023) / 1024;
    int lo = t * ch;
    int sum = 0;
    for (int j = 0; j < ch; ++j) {
        int i = lo + j;
        if (i < n) sum += counts[i];
    }
    s[t] = sum;
    __syncthreads();
    for (int off = 1; off < 1024; off <<= 1) {
        int v = 0;
        if (t >= off) v = s[t - off];
        __syncthreads();
        s[t] += v;
        __syncthreads();
    }
    int run = (t == 0) ? 0 : s[t - 1];
    for (int j = 0; j < ch; ++j) {
        int i = lo + j;
        if (i < n) {
            row_start[i] = run;
            cursor[i] = run;
            run += counts[i];
        }
    }
    if (t == 1023) row_start[n] = s[1023];
}

__global__ void scatter_kernel(const int* __restrict__ src, const int* __restrict__ dst,
                               int* __restrict__ cursor, int* __restrict__ csr_src, int E) {
    int e = blockIdx.x * blockDim.x + threadIdx.x;
    if (e < E) {
        int d   = dst[e];
        int pos = atomicAdd(&cursor[d], 1);
        csr_src[pos] = src[e];
    }
}

// ---------------------------------------------------------------------------
// Hidden-layer gather: pure weighted sum (weights precomputed), 8-deep MLP.
// ---------------------------------------------------------------------------
__global__ __launch_bounds__(256) void gather_hidden(
    const unsigned short* __restrict__ Hm, const float* __restrict__ wC,
    const float* __restrict__ zinv, const int* __restrict__ csr_src,
    const int* __restrict__ row_start, const unsigned short* __restrict__ last,
    unsigned short* __restrict__ out, int n, float beta) {
    int lane = threadIdx.x & 63;
    int nn   = blockIdx.x * 4 + (threadIdx.x >> 6);
    if (nn >= n) return;
    int s0 = row_start[nn], s1 = row_start[nn + 1];
    int h2 = lane >> 3;

    float a0 = 0.f, a1 = 0.f, a2 = 0.f, a3 = 0.f;
    for (int e = s0; e < s1; e += 8) {
        int c = s1 - e;
        int idx[8];
        float wv[8];
#pragma unroll
        for (int j = 0; j < 8; ++j) {
            int p = (j < c) ? e + j : e;
            idx[j] = csr_src[p];
            wv[j]  = wC[(size_t)p * NN_HEADS + h2];
        }
        ushort4 r[8];
#pragma unroll
        for (int j = 0; j < 8; ++j) r[j] = *(const ushort4*)&Hm[(size_t)idx[j] * NN_HID + lane * 4];
#pragma unroll
        for (int j = 0; j < 8; ++j) {
            if (j < c) {
                float w = wv[j];
                a0 += w * b2f(r[j].x); a1 += w * b2f(r[j].y);
                a2 += w * b2f(r[j].z); a3 += w * b2f(r[j].w);
            }
        }
    }
    float zi = zinv[nn * NN_HEADS + h2];
    float v0 = elu1(a0 * zi), v1 = elu1(a1 * zi), v2 = elu1(a2 * zi), v3 = elu1(a3 * zi);
    if (beta >= 0.f) {
        ushort4 lv = *(const ushort4*)&last[(size_t)nn * NN_HID + lane * 4];
        v0 = beta * b2f(lv.x) + (1.f - beta) * v0;
        v1 = beta * b2f(lv.y) + (1.f - beta) * v1;
        v2 = beta * b2f(lv.z) + (1.f - beta) * v2;
        v3 = beta * b2f(lv.w) + (1.f - beta) * v3;
    }
    ushort4 o;
    o.x = f2b(v0); o.y = f2b(v1); o.z = f2b(v2); o.w = f2b(v3);
    *(ushort4*)&out[(size_t)nn * NN_HID + lane * 4] = o;
}

// ---------------------------------------------------------------------------
// Final layer gather: weighted sum + head-mean + log_softmax -> d_out
// ---------------------------------------------------------------------------
__global__ void gather_final(const unsigned short* __restrict__ Hm, const float* __restrict__ wC,
                             const float* __restrict__ zinv, const int* __restrict__ csr_src,
                             const int* __restrict__ row_start, float* __restrict__ dout, int n) {
    int nn = blockIdx.x;
    __shared__ float accs[NN_HEADS * NN_NCLASS];
    int t = threadIdx.x;  // 0..319
    int s0 = row_start[nn], s1 = row_start[nn + 1];
    int hh = t / NN_NCLASS;
    float acc = 0.f;
    const int LD = NN_HEADS * NN_NCLASS;
    for (int e = s0; e < s1; e += 8) {
        int c = s1 - e;
        int idx[8];
        float wv[8];
#pragma unroll
        for (int j = 0; j < 8; ++j) {
            int p = (j < c) ? e + j : e;
            idx[j] = csr_src[p];
            wv[j]  = wC[(size_t)p * NN_HEADS + hh];
        }
        float v[8];
#pragma unroll
        for (int j = 0; j < 8; ++j) v[j] = b2f(Hm[(size_t)idx[j] * LD + t]);
#pragma unroll
        for (int j = 0; j < 8; ++j) {
            if (j < c) acc += wv[j] * v[j];
        }
    }
    accs[t] = acc * zinv[nn * NN_HEADS + hh];
    __syncthreads();
    if (t < 64) {
        float v = -INFINITY;
        if (t < NN_NCLASS) {
            float sacc = 0.f;
#pragma unroll
            for (int h2 = 0; h2 < NN_HEADS; ++h2) sacc += accs[h2 * NN_NCLASS + t];
            v = sacc * (1.f / NN_HEADS);
        }
        float mx = v;
#pragma unroll
        for (int o = 1; o < 64; o <<= 1) mx = fmaxf(mx, __shfl_xor(mx, o, 64));
        float ex = (t < NN_NCLASS) ? expf(v - mx) : 0.f;
        float se = ex;
#pragma unroll
        for (int o = 1; o < 64; o <<= 1) se += __shfl_xor(se, o, 64);
        if (t < NN_NCLASS) dout[(size_t)nn * NN_NCLASS + t] = (v - mx) - logf(se);
    }
}

// ---------------------------------------------------------------------------
// Row-normalize (bf16 in) + bf16 zn + analytic diagonal
// ---------------------------------------------------------------------------
__global__ void rownorm_kernel(const unsigned short* __restrict__ z, short* __restrict__ znb,
                               float* __restrict__ dvec, int n) {
    int nn = blockIdx.x;
    int t  = threadIdx.x;  // 256
    float v  = b2f(z[(size_t)nn * NN_HID + t]);
    float sq = v * v;
#pragma unroll
    for (int o = 1; o < 64; o <<= 1) sq += __shfl_xor(sq, o, 64);
    __shared__ float ws[4];
    if ((t & 63) == 0) ws[t >> 6] = sq;
    __syncthreads();
    float s = ws[0] + ws[1] + ws[2] + ws[3];
    float m = fmaxf(sqrtf(s), 1e-12f);
    znb[(size_t)nn * NN_HID + t] = (short)f2b(v / m);
    if (t == 0) dvec[nn] = expf((s / (m * m)) * (1.f / TAU_F));
}

// ---------------------------------------------------------------------------
// Symmetric gram rowsums, LDS-staged pipelined GEMM, NO atomics (R7-validated).
// ---------------------------------------------------------------------------
__global__ __launch_bounds__(256) void gram_mfma(const short* __restrict__ znb,
                                                 float* __restrict__ P2d, int n,
                                                 int T, int nwg, int Npad) {
    __shared__ short As[128 * 64];
    __shared__ short Bs[128 * 64];

    int b = blockIdx.x;
    int q = nwg >> 3, r8 = nwg & 7, xc = b & 7, oo = b >> 3;
    int sid = (xc < r8 ? xc * (q + 1) : r8 * (q + 1) + (xc - r8) * q) + oo;
    int bi = 0, rem = sid;
    while (rem >= T - bi) { rem -= T - bi; ++bi; }
    int bj = bi + rem;
    int i0 = bi * 128, j0 = bj * 128;

    int t    = threadIdx.x;
    int lane = t & 63;
    int wid  = t >> 6;
    int wrow = wid >> 1, wcol = wid & 1;
    int l15  = lane & 15, lg = lane >> 4;
    int srow = lane >> 3;
    int sch  = lane & 7;

    f32x4 acc[4][4];
#pragma unroll
    for (int m = 0; m < 4; ++m)
#pragma unroll
        for (int nn = 0; nn < 4; ++nn)
#pragma unroll
            for (int r = 0; r < 4; ++r) acc[m][nn][r] = 0.f;

    bf16x8 sa[4], sb[4];
#pragma unroll
    for (int s = 0; s < 4; ++s) {
        int row = wid * 32 + s * 8 + srow;
        int gch = sch ^ (row & 7);
        sa[s] = *(const bf16x8*)(znb + (size_t)(i0 + row) * NN_HID + gch * 8);
        sb[s] = *(const bf16x8*)(znb + (size_t)(j0 + row) * NN_HID + gch * 8);
    }

#pragma unroll
    for (int kt = 0; kt < 4; ++kt) {
#pragma unroll
        for (int s = 0; s < 4; ++s) {
            int row = wid * 32 + s * 8 + srow;
            *(bf16x8*)(&As[row * 64 + sch * 8]) = sa[s];
            *(bf16x8*)(&Bs[row * 64 + sch * 8]) = sb[s];
        }
        __syncthreads();
        if (kt < 3) {
            int kb = (kt + 1) * 64;
#pragma unroll
            for (int s = 0; s < 4; ++s) {
                int row = wid * 32 + s * 8 + srow;
                int gch = sch ^ (row & 7);
                sa[s] = *(const bf16x8*)(znb + (size_t)(i0 + row) * NN_HID + kb + gch * 8);
                sb[s] = *(const bf16x8*)(znb + (size_t)(j0 + row) * NN_HID + kb + gch * 8);
            }
        }
#pragma unroll
        for (int ks = 0; ks < 2; ++ks) {
            bf16x8 av[4], bv[4];
#pragma unroll
            for (int m = 0; m < 4; ++m) {
                int Ra = wrow * 64 + m * 16 + l15;
                int Rb = wcol * 64 + m * 16 + l15;
                int ca = (ks * 4 + lg) ^ (Ra & 7);
                int cb = (ks * 4 + lg) ^ (Rb & 7);
                av[m] = *(const bf16x8*)(&As[Ra * 64 + ca * 8]);
                bv[m] = *(const bf16x8*)(&Bs[Rb * 64 + cb * 8]);
            }
#pragma unroll
            for (int m = 0; m < 4; ++m)
#pragma unroll
                for (int nn = 0; nn < 4; ++nn)
                    acc[m][nn] = __builtin_amdgcn_mfma_f32_16x16x32_bf16(av[m], bv[nn], acc[m][nn], 0, 0, 0);
        }
        __syncthreads();
    }

    int i0w = i0 + wrow * 64;
    int j0w = j0 + wcol * 64;
    bool diag = (bj == bi);
#pragma unroll
    for (int m = 0; m < 4; ++m)
#pragma unroll
        for (int nn = 0; nn < 4; ++nn) {
            int gj = j0w + nn * 16 + l15;
            bool jok = gj < n;
#pragma unroll
            for (int r = 0; r < 4; ++r) {
                int gi = i0w + m * 16 + lg * 4 + r;
                acc[m][nn][r] = (jok && gi < n) ? expf(acc[m][nn][r] * (1.f / TAU_F)) : 0.f;
            }
        }
    float* rowslot = P2d + (size_t)(2 * bj + wcol) * Npad;
#pragma unroll
    for (int m = 0; m < 4; ++m) {
#pragma unroll
        for (int r = 0; r < 4; ++r) {
            float v = acc[m][0][r] + acc[m][1][r] + acc[m][2][r] + acc[m][3][r];
            v += __shfl_xor(v, 1, 64);
            v += __shfl_xor(v, 2, 64);
            v += __shfl_xor(v, 4, 64);
            v += __shfl_xor(v, 8, 64);
            if (l15 == 0) {
                int gi = i0w + m * 16 + lg * 4 + r;
                if (gi < n) rowslot[gi] = v;
            }
        }
    }
    if (!diag) {
        float* colslot = P2d + (size_t)(2 * bi + wrow) * Npad;
#pragma unroll
        for (int nn = 0; nn < 4; ++nn) {
            float v = 0.f;
#pragma unroll
            for (int m = 0; m < 4; ++m)
#pragma unroll
                for (int r = 0; r < 4; ++r) v += acc[m][nn][r];
            v += __shfl_xor(v, 16, 64);
            v += __shfl_xor(v, 32, 64);
            if (lg == 0) {
                int gj = j0w + nn * 16 + l15;
                if (gj < n) colslot[gj] = v;
            }
        }
    }
}

// ---------------------------------------------------------------------------
// Parallel fold of partial slots: R[i] = sum_sl P2d[sl][i]
// ---------------------------------------------------------------------------
__global__ void fold_kernel(const float* __restrict__ P2d, float* __restrict__ R,
                            int n, int slots, int Npad) {
    int i = blockIdx.x * 256 + threadIdx.x;
    if (i >= n) return;
    const float* p = P2d + i;
    float s0 = 0.f, s1 = 0.f, s2 = 0.f, s3 = 0.f;
    int sl = 0;
    for (; sl + 4 <= slots; sl += 4) {
        s0 += p[(size_t)(sl + 0) * Npad];
        s1 += p[(size_t)(sl + 1) * Npad];
        s2 += p[(size_t)(sl + 2) * Npad];
        s3 += p[(size_t)(sl + 3) * Npad];
    }
    for (; sl < slots; ++sl) s0 += p[(size_t)sl * Npad];
    R[i] = (s0 + s1) + (s2 + s3);
}

__global__ void loss_kernel(const float* __restrict__ R, const float* __restrict__ dvec,
                            float* __restrict__ out_loss, int n) {
    __shared__ float s[1024];
    int t = threadIdx.x;
    float sum = 0.f;
    for (int i = t; i < n; i += 1024) {
        float d   = dvec[i];
        float off = R[i] - d;
        sum += -logf(d / (off + off));
    }
    s[t] = sum;
    __syncthreads();
    for (int o = 512; o > 0; o >>= 1) {
        if (t < o) s[t] += s[t + o];
        __syncthreads();
    }
    if (t == 0) *out_loss = s[0] / n;
}

// ---------------------------------------------------------------------------
extern "C" void kernel_launch(void* const* d_in, const int* in_sizes, int n_in,
                              void* d_out, int out_size, void* d_ws, size_t ws_size,
                              hipStream_t stream) {
    const float* x   = (const float*)d_in[0];
    const int*   src = (const int*)d_in[1];
    const int*   dst = (const int*)d_in[2];
    const float* W0  = (const float*)d_in[3];
    const float* a0s = (const float*)d_in[4];
    const float* a0d = (const float*)d_in[5];
    const float* W1  = (const float*)d_in[6];
    const float* a1s = (const float*)d_in[7];
    const float* a1d = (const float*)d_in[8];
    const float* W2  = (const float*)d_in[9];
    const float* a2s = (const float*)d_in[10];
    const float* a2d = (const float*)d_in[11];
    const float* Wout= (const float*)d_in[12];
    const float* aos = (const float*)d_in[13];
    const float* aod = (const float*)d_in[14];

    int N = in_sizes[0] / NN_F_IN;
    int E = in_sizes[1];
    int Npad = ((N + 127) / 128) * 128;
    int T = Npad / 128;
    int nwg = T * (T + 1) / 2;
    float* out = (float*)d_out;

    char*  ws  = (char*)d_ws;
    size_t off = 0;
    auto alloc = [&](size_t bytes) -> void* {
        void* p = ws + off;
        off += bytes;
        off = (off + 255) & ~(size_t)255;
        return p;
    };
    size_t hbBytes = (size_t)N * 320 * 2;
    size_t znBytes = (size_t)Npad * NN_HID * 2;
    unsigned short* Hb = (unsigned short*)alloc(hbBytes > znBytes ? hbBytes : znBytes);
    short* znb = (short*)Hb;  // alias: znb live only between rownorm and gram
    unsigned short* Bl = (unsigned short*)alloc((size_t)N * NN_HID * 2);
    unsigned short* Bc = (unsigned short*)alloc((size_t)N * NN_HID * 2);
    size_t xbBytes = (size_t)N * NN_F_IN * 2;
    size_t p2Bytes = (size_t)2 * T * Npad * 4;
    void* XbP2d = alloc(xbBytes > p2Bytes ? xbBytes : p2Bytes);
    unsigned short* Xb  = (unsigned short*)XbP2d;  // live: castX..fc L0
    float*          P2d = (float*)XbP2d;           // live: memset..fold
    unsigned short* Wt0 = (unsigned short*)alloc((size_t)256 * 512 * 2);
    unsigned short* Wt1 = (unsigned short*)alloc((size_t)256 * 256 * 2);
    unsigned short* Wt2 = (unsigned short*)alloc((size_t)256 * 256 * 2);
    unsigned short* Wto = (unsigned short*)alloc((size_t)384 * 256 * 2);
    float* es     = (float*)alloc((size_t)N * NN_HEADS * 4);
    float* ed     = (float*)alloc((size_t)N * NN_HEADS * 4);
    float* wC     = (float*)alloc((size_t)E * NN_HEADS * 4);
    float* zinvA  = (float*)alloc((size_t)N * NN_HEADS * 4);
    float* Rrow   = (float*)alloc((size_t)N * 4);
    float* dvec   = (float*)alloc((size_t)N * 4);
    int*   counts = (int*)alloc((size_t)N * 4);
    int*   rs     = (int*)alloc((size_t)(N + 1) * 4);
    int*   cursor = (int*)alloc((size_t)N * 4);
    int*   csr    = (int*)alloc((size_t)E * 4);

    // ---- CSR build
    hipMemsetAsync(counts, 0, (size_t)N * 4, stream);
    count_kernel<<<(E + 255) / 256, 256, 0, stream>>>(dst, counts, E);
    scan_kernel<<<1, 1024, 0, stream>>>(counts, rs, cursor, N);
    scatter_kernel<<<(E + 255) / 256, 256, 0, stream>>>(src, dst, cursor, csr, E);

    // ---- casts
    cast_f2b_kernel<<<(N * NN_F_IN / 4 + 255) / 256, 256, 0, stream>>>(x, Xb, N * NN_F_IN / 4);
    castW_kernel<<<(256 * 512 + 255) / 256, 256, 0, stream>>>(W0, Wt0, 512, 256, 256);
    castW_kernel<<<(256 * 256 + 255) / 256, 256, 0, stream>>>(W1, Wt1, 256, 256, 256);
    castW_kernel<<<(256 * 256 + 255) / 256, 256, 0, stream>>>(W2, Wt2, 256, 256, 256);
    castW_kernel<<<(384 * 256 + 255) / 256, 256, 0, stream>>>(Wout, Wto, 256, 320, 384);

    int atGrid = (N * NN_HEADS + 255) / 256;
    int ghGrid = (N + 3) / 4;
    int mT64 = (N + 63) / 64;

    // ---- layer 0: Xb -> Hb -> Bl
    fc_mfma<<<dim3(4, mT64), 256, 0, stream>>>(Xb, Wt0, Hb, N, 512, 256, 256);
    attn_kernel<<<atGrid, 256, 0, stream>>>(Hb, a0s, a0d, es, ed, N, NN_FH);
    edge_wz<<<ghGrid, 256, 0, stream>>>(es, ed, csr, rs, wC, zinvA, N);
    gather_hidden<<<ghGrid, 256, 0, stream>>>(Hb, wC, zinvA, csr, rs, nullptr, Bl, N, -1.f);

    // ---- layer 1: Bl -> Hb -> Bc (beta = 0.5/3)
    fc_mfma<<<dim3(4, mT64), 256, 0, stream>>>(Bl, Wt1, Hb, N, 256, 256, 256);
    attn_kernel<<<atGrid, 256, 0, stream>>>(Hb, a1s, a1d, es, ed, N, NN_FH);
    edge_wz<<<ghGrid, 256, 0, stream>>>(es, ed, csr, rs, wC, zinvA, N);
    gather_hidden<<<ghGrid, 256, 0, stream>>>(Hb, wC, zinvA, csr, rs, Bl, Bc, N, LAMDA_F / 3.f);

    // ---- layer 2: Bc -> Hb -> Bl (beta = 0.5/4)
    fc_mfma<<<dim3(4, mT64), 256, 0, stream>>>(Bc, Wt2, Hb, N, 256, 256, 256);
    attn_kernel<<<atGrid, 256, 0, stream>>>(Hb, a2s, a2d, es, ed, N, NN_FH);
    edge_wz<<<ghGrid, 256, 0, stream>>>(es, ed, csr, rs, wC, zinvA, N);
    gather_hidden<<<ghGrid, 256, 0, stream>>>(Hb, wC, zinvA, csr, rs, Bc, Bl, N, LAMDA_F / 4.f);

    // ---- bind_loss(Bl): znb (aliases Hb), partial slots in P2d
    rownorm_kernel<<<N, 256, 0, stream>>>(Bl, znb, dvec, N);
    hipMemsetAsync(znb + (size_t)N * NN_HID, 0, (size_t)(Npad - N) * NN_HID * 2, stream);
    hipMemsetAsync(P2d, 0, (size_t)2 * T * Npad * 4, stream);
    gram_mfma<<<nwg, 256, 0, stream>>>(znb, P2d, N, T, nwg, Npad);
    fold_kernel<<<(N + 255) / 256, 256, 0, stream>>>(P2d, Rrow, N, 2 * T, Npad);
    loss_kernel<<<1, 1024, 0, stream>>>(Rrow, dvec, out + (size_t)N * NN_NCLASS, N);

    // ---- output layer: Bl -> Hb(320) -> d_out
    fc_mfma<<<dim3(5, mT64), 256, 0, stream>>>(Bl, Wto, Hb, N, 256, 320, 320);
    attn_kernel<<<atGrid, 256, 0, stream>>>(Hb, aos, aod, es, ed, N, NN_NCLASS);
    edge_wz<<<ghGrid, 256, 0, stream>>>(es, ed, csr, rs, wC, zinvA, N);
    gather_final<<<N, NN_HEADS * NN_NCLASS, 0, stream>>>(Hb, wC, zinvA, csr, rs, out, N);
}

// Round 9
// 415.094 us; speedup vs baseline: 2.2275x; 1.0428x over previous
//
#include <hip/hip_runtime.h>
#include <hip/hip_bf16.h>
#include <math.h>

#define NN_F_IN   512
#define NN_HID    256
#define NN_HEADS  8
#define NN_FH     32
#define NN_NCLASS 40
#define TAU_F     0.5f
#define LAMDA_F   0.5f

typedef __attribute__((ext_vector_type(8))) short bf16x8;
typedef __attribute__((ext_vector_type(4))) float f32x4;

static __device__ __forceinline__ float lrelu02(float x) { return x >= 0.f ? x : 0.2f * x; }
static __device__ __forceinline__ float elu1(float x)    { return x > 0.f ? x : expm1f(x); }
static __device__ __forceinline__ float b2f(unsigned short u) {
    unsigned int x = ((unsigned int)u) << 16;
    return __uint_as_float(x);
}
static __device__ __forceinline__ unsigned short f2b(float f) {
    __hip_bfloat16 hb = __float2bfloat16(f);
    return *reinterpret_cast<unsigned short*>(&hb);
}

// ---------------------------------------------------------------------------
// Fused prep: X cast (float4-wide) + 4 transposed W casts, one launch.
// ---------------------------------------------------------------------------
__global__ void prep_kernel(const float* __restrict__ x,
                            const float* __restrict__ W0, const float* __restrict__ W1,
                            const float* __restrict__ W2, const float* __restrict__ Wo,
                            unsigned short* __restrict__ Xb,
                            unsigned short* __restrict__ Wt0, unsigned short* __restrict__ Wt1,
                            unsigned short* __restrict__ Wt2, unsigned short* __restrict__ Wto,
                            int n4X) {
    int i = blockIdx.x * 256 + threadIdx.x;
    if (i < n4X) {
        float4 v = *(const float4*)(x + (size_t)i * 4);
        ushort4 o;
        o.x = f2b(v.x); o.y = f2b(v.y); o.z = f2b(v.z); o.w = f2b(v.w);
        *(ushort4*)(Xb + (size_t)i * 4) = o;
        return;
    }
    i -= n4X;
    if (i < 256 * 512) {            // Wt0: Np=256, K=512, Nc=256
        int np = i >> 9, k = i & 511;
        Wt0[i] = f2b(W0[(size_t)k * 256 + np]);
        return;
    }
    i -= 256 * 512;
    if (i < 256 * 256) {            // Wt1
        int np = i >> 8, k = i & 255;
        Wt1[i] = f2b(W1[(size_t)k * 256 + np]);
        return;
    }
    i -= 256 * 256;
    if (i < 256 * 256) {            // Wt2
        int np = i >> 8, k = i & 255;
        Wt2[i] = f2b(W2[(size_t)k * 256 + np]);
        return;
    }
    i -= 256 * 256;
    if (i < 384 * 256) {            // Wto: Np=384, K=256, Nc=320
        int np = i >> 8, k = i & 255;
        Wto[i] = f2b(np < 320 ? Wo[(size_t)k * 320 + np] : 0.f);
    }
}

// ---------------------------------------------------------------------------
// MFMA GEMM: H[m][col] = sum_k A[m][k] * B[col][k], A/B bf16, H bf16.
// Block = 4 waves 2x2 -> 64x64 tile; wave = 32x32 = 2x2 frags of 16x16x32.
// ---------------------------------------------------------------------------
__global__ __launch_bounds__(256) void fc_mfma(const unsigned short* __restrict__ A,
                                               const unsigned short* __restrict__ B,
                                               unsigned short* __restrict__ H,
                                               int M, int K, int ncols, int ldH) {
    int t = threadIdx.x, lane = t & 63, wid = t >> 6;
    int wrow = wid >> 1, wcol = wid & 1;
    int l15 = lane & 15, lg = lane >> 4;
    int mbase = blockIdx.y * 64 + wrow * 32;
    int nbase = blockIdx.x * 64 + wcol * 32;

    const unsigned short* Ap[2];
    const unsigned short* Bp[2];
#pragma unroll
    for (int m = 0; m < 2; ++m) {
        int rr = mbase + m * 16 + l15;
        if (rr > M - 1) rr = M - 1;
        Ap[m] = A + (size_t)rr * K + lg * 8;
        Bp[m] = B + (size_t)(nbase + m * 16 + l15) * K + lg * 8;
    }
    f32x4 acc[2][2];
#pragma unroll
    for (int m = 0; m < 2; ++m)
#pragma unroll
        for (int nn = 0; nn < 2; ++nn)
#pragma unroll
            for (int r = 0; r < 4; ++r) acc[m][nn][r] = 0.f;

    bf16x8 aP[2], bP[2], aQ[2], bQ[2];
#pragma unroll
    for (int m = 0; m < 2; ++m) {
        aP[m] = *(const bf16x8*)(Ap[m]);
        bP[m] = *(const bf16x8*)(Bp[m]);
    }
    int nhalf = K >> 6;
    int kk = 32;
    for (int it = 0; it < nhalf; ++it) {
#pragma unroll
        for (int m = 0; m < 2; ++m) {
            aQ[m] = *(const bf16x8*)(Ap[m] + kk);
            bQ[m] = *(const bf16x8*)(Bp[m] + kk);
        }
#pragma unroll
        for (int m = 0; m < 2; ++m)
#pragma unroll
            for (int nn = 0; nn < 2; ++nn)
                acc[m][nn] = __builtin_amdgcn_mfma_f32_16x16x32_bf16(aP[m], bP[nn], acc[m][nn], 0, 0, 0);
        if (it + 1 < nhalf) {
#pragma unroll
            for (int m = 0; m < 2; ++m) {
                aP[m] = *(const bf16x8*)(Ap[m] + kk + 32);
                bP[m] = *(const bf16x8*)(Bp[m] + kk + 32);
            }
        }
#pragma unroll
        for (int m = 0; m < 2; ++m)
#pragma unroll
            for (int nn = 0; nn < 2; ++nn)
                acc[m][nn] = __builtin_amdgcn_mfma_f32_16x16x32_bf16(aQ[m], bQ[nn], acc[m][nn], 0, 0, 0);
        kk += 64;
    }
#pragma unroll
    for (int m = 0; m < 2; ++m) {
#pragma unroll
        for (int nn = 0; nn < 2; ++nn) {
            int col = nbase + nn * 16 + l15;
            if (col >= ncols) continue;
#pragma unroll
            for (int r = 0; r < 4; ++r) {
                int row = mbase + m * 16 + lg * 4 + r;
                if (row < M) H[(size_t)row * ldH + col] = f2b(acc[m][nn][r]);
            }
        }
    }
}

// ---------------------------------------------------------------------------
// es/ed dot products (Hm bf16)
// ---------------------------------------------------------------------------
__global__ void attn_kernel(const unsigned short* __restrict__ Hm, const float* __restrict__ As,
                            const float* __restrict__ Ad, float* __restrict__ es,
                            float* __restrict__ ed, int n, int df) {
    int idx = blockIdx.x * blockDim.x + threadIdx.x;
    if (idx >= n * NN_HEADS) return;
    int nn = idx / NN_HEADS, hh = idx - nn * NN_HEADS;
    const unsigned short* hp = Hm + (size_t)nn * NN_HEADS * df + hh * df;
    const float* ap = As + hh * df;
    const float* bp = Ad + hh * df;
    float s1 = 0.f, s2 = 0.f;
    for (int d = 0; d < df; d += 4) {
        ushort4 hv = *(const ushort4*)(hp + d);
        float4 av = *(const float4*)(ap + d);
        float4 bv = *(const float4*)(bp + d);
        float h0 = b2f(hv.x), h1 = b2f(hv.y), h2 = b2f(hv.z), h3 = b2f(hv.w);
        s1 += h0 * av.x + h1 * av.y + h2 * av.z + h3 * av.w;
        s2 += h0 * bv.x + h1 * bv.y + h2 * bv.z + h3 * bv.w;
    }
    es[idx] = s1;
    ed[idx] = s2;
}

// ---------------------------------------------------------------------------
// Edge weights: one fast-exp per (edge,head). wC[p][h] CSR order, zinv[n][h].
// ---------------------------------------------------------------------------
__global__ __launch_bounds__(256) void edge_wz(
    const float* __restrict__ es, const float* __restrict__ ed,
    const int* __restrict__ csr_src, const int* __restrict__ row_start,
    float* __restrict__ wC, float* __restrict__ zinv, int n) {
    int lane = threadIdx.x & 63;
    int nn   = blockIdx.x * 4 + (threadIdx.x >> 6);
    if (nn >= n) return;
    int s0 = row_start[nn], s1 = row_start[nn + 1];
    int h    = lane & 7;
    int slot = lane >> 3;
    float edh = ed[nn * NN_HEADS + h];
    float z = 0.f;
    for (int e = s0 + slot; e < s1; e += 8) {
        int sv = csr_src[e];
        float w = __expf(lrelu02(es[sv * NN_HEADS + h] + edh));
        wC[(size_t)e * NN_HEADS + h] = w;
        z += w;
    }
    z += __shfl_xor(z, 8, 64);
    z += __shfl_xor(z, 16, 64);
    z += __shfl_xor(z, 32, 64);
    if (slot == 0) zinv[nn * NN_HEADS + h] = 1.f / z;
}

// ---------------------------------------------------------------------------
// CSR build
// ---------------------------------------------------------------------------
__global__ void count_kernel(const int* __restrict__ dst, int* __restrict__ counts, int E) {
    int e = blockIdx.x * blockDim.x + threadIdx.x;
    if (e < E) atomicAdd(&counts[dst[e]], 1);
}

__global__ void scan_kernel(const int* __restrict__ counts, int* __restrict__ row_start,
                            int* __restrict__ cursor, int n) {
    __shared__ int s[1024];
    int t  = threadIdx.x;
    int ch = (n + 1023) / 1024;
    int lo = t * ch;
    int sum = 0;
    for (int j = 0; j < ch; ++j) {
        int i = lo + j;
        if (i < n) sum += counts[i];
    }
    s[t] = sum;
    __syncthreads();
    for (int off = 1; off < 1024; off <<= 1) {
        int v = 0;
        if (t >= off) v = s[t - off];
        __syncthreads();
        s[t] += v;
        __syncthreads();
    }
    int run = (t == 0) ? 0 : s[t - 1];
    for (int j = 0; j < ch; ++j) {
        int i = lo + j;
        if (i < n) {
            row_start[i] = run;
            cursor[i] = run;
            run += counts[i];
        }
    }
    if (t == 1023) row_start[n] = s[1023];
}

__global__ void scatter_kernel(const int* __restrict__ src, const int* __restrict__ dst,
                               int* __restrict__ cursor, int* __restrict__ csr_src, int E) {
    int e = blockIdx.x * blockDim.x + threadIdx.x;
    if (e < E) {
        int d   = dst[e];
        int pos = atomicAdd(&cursor[d], 1);
        csr_src[pos] = src[e];
    }
}

// ---------------------------------------------------------------------------
// Hidden-layer gather: pure weighted sum, 8-deep MLP.
// ---------------------------------------------------------------------------
__global__ __launch_bounds__(256) void gather_hidden(
    const unsigned short* __restrict__ Hm, const float* __restrict__ wC,
    const float* __restrict__ zinv, const int* __restrict__ csr_src,
    const int* __restrict__ row_start, const unsigned short* __restrict__ last,
    unsigned short* __restrict__ out, int n, float beta) {
    int lane = threadIdx.x & 63;
    int nn   = blockIdx.x * 4 + (threadIdx.x >> 6);
    if (nn >= n) return;
    int s0 = row_start[nn], s1 = row_start[nn + 1];
    int h2 = lane >> 3;

    float a0 = 0.f, a1 = 0.f, a2 = 0.f, a3 = 0.f;
    for (int e = s0; e < s1; e += 8) {
        int c = s1 - e;
        int idx[8];
        float wv[8];
#pragma unroll
        for (int j = 0; j < 8; ++j) {
            int p = (j < c) ? e + j : e;
            idx[j] = csr_src[p];
            wv[j]  = wC[(size_t)p * NN_HEADS + h2];
        }
        ushort4 r[8];
#pragma unroll
        for (int j = 0; j < 8; ++j) r[j] = *(const ushort4*)&Hm[(size_t)idx[j] * NN_HID + lane * 4];
#pragma unroll
        for (int j = 0; j < 8; ++j) {
            if (j < c) {
                float w = wv[j];
                a0 += w * b2f(r[j].x); a1 += w * b2f(r[j].y);
                a2 += w * b2f(r[j].z); a3 += w * b2f(r[j].w);
            }
        }
    }
    float zi = zinv[nn * NN_HEADS + h2];
    float v0 = elu1(a0 * zi), v1 = elu1(a1 * zi), v2 = elu1(a2 * zi), v3 = elu1(a3 * zi);
    if (beta >= 0.f) {
        ushort4 lv = *(const ushort4*)&last[(size_t)nn * NN_HID + lane * 4];
        v0 = beta * b2f(lv.x) + (1.f - beta) * v0;
        v1 = beta * b2f(lv.y) + (1.f - beta) * v1;
        v2 = beta * b2f(lv.z) + (1.f - beta) * v2;
        v3 = beta * b2f(lv.w) + (1.f - beta) * v3;
    }
    ushort4 o;
    o.x = f2b(v0); o.y = f2b(v1); o.z = f2b(v2); o.w = f2b(v3);
    *(ushort4*)&out[(size_t)nn * NN_HID + lane * 4] = o;
}

// ---------------------------------------------------------------------------
// Final layer gather: weighted sum + head-mean + log_softmax -> d_out
// ---------------------------------------------------------------------------
__global__ void gather_final(const unsigned short* __restrict__ Hm, const float* __restrict__ wC,
                             const float* __restrict__ zinv, const int* __restrict__ csr_src,
                             const int* __restrict__ row_start, float* __restrict__ dout, int n) {
    int nn = blockIdx.x;
    __shared__ float accs[NN_HEADS * NN_NCLASS];
    int t = threadIdx.x;  // 0..319
    int s0 = row_start[nn], s1 = row_start[nn + 1];
    int hh = t / NN_NCLASS;
    float acc = 0.f;
    const int LD = NN_HEADS * NN_NCLASS;
    for (int e = s0; e < s1; e += 8) {
        int c = s1 - e;
        int idx[8];
        float wv[8];
#pragma unroll
        for (int j = 0; j < 8; ++j) {
            int p = (j < c) ? e + j : e;
            idx[j] = csr_src[p];
            wv[j]  = wC[(size_t)p * NN_HEADS + hh];
        }
        float v[8];
#pragma unroll
        for (int j = 0; j < 8; ++j) v[j] = b2f(Hm[(size_t)idx[j] * LD + t]);
#pragma unroll
        for (int j = 0; j < 8; ++j) {
            if (j < c) acc += wv[j] * v[j];
        }
    }
    accs[t] = acc * zinv[nn * NN_HEADS + hh];
    __syncthreads();
    if (t < 64) {
        float v = -INFINITY;
        if (t < NN_NCLASS) {
            float sacc = 0.f;
#pragma unroll
            for (int h2 = 0; h2 < NN_HEADS; ++h2) sacc += accs[h2 * NN_NCLASS + t];
            v = sacc * (1.f / NN_HEADS);
        }
        float mx = v;
#pragma unroll
        for (int o = 1; o < 64; o <<= 1) mx = fmaxf(mx, __shfl_xor(mx, o, 64));
        float ex = (t < NN_NCLASS) ? expf(v - mx) : 0.f;
        float se = ex;
#pragma unroll
        for (int o = 1; o < 64; o <<= 1) se += __shfl_xor(se, o, 64);
        if (t < NN_NCLASS) dout[(size_t)nn * NN_NCLASS + t] = (v - mx) - logf(se);
    }
}

// ---------------------------------------------------------------------------
// Row-normalize (bf16 in) + bf16 zn + analytic diagonal
// ---------------------------------------------------------------------------
__global__ void rownorm_kernel(const unsigned short* __restrict__ z, short* __restrict__ znb,
                               float* __restrict__ dvec, int n) {
    int nn = blockIdx.x;
    int t  = threadIdx.x;  // 256
    float v  = b2f(z[(size_t)nn * NN_HID + t]);
    float sq = v * v;
#pragma unroll
    for (int o = 1; o < 64; o <<= 1) sq += __shfl_xor(sq, o, 64);
    __shared__ float ws[4];
    if ((t & 63) == 0) ws[t >> 6] = sq;
    __syncthreads();
    float s = ws[0] + ws[1] + ws[2] + ws[3];
    float m = fmaxf(sqrtf(s), 1e-12f);
    znb[(size_t)nn * NN_HID + t] = (short)f2b(v / m);
    if (t == 0) dvec[nn] = __expf((s / (m * m)) * (1.f / TAU_F));
}

// ---------------------------------------------------------------------------
// Symmetric gram rowsums, BK=128 LDS-staged GEMM, 3 barriers, NO atomics.
// LDS 64KB: As/Bs 128 rows x 128 k. Swizzle: slot c holds global chunk
// c ^ (row&7) (pre-swizzled source, XOR read) -> conflict-free b128 reads.
// Slab-1 global loads issued right after first barrier (overlap 64 MFMAs).
// Fast __expf epilogue. Partials to disjoint P2d slots (R5-validated).
// ---------------------------------------------------------------------------
__global__ __launch_bounds__(256) void gram_mfma(const short* __restrict__ znb,
                                                 float* __restrict__ P2d, int n,
                                                 int T, int nwg, int Npad) {
    __shared__ short As[128 * 128];
    __shared__ short Bs[128 * 128];

    int b = blockIdx.x;
    int q = nwg >> 3, r8 = nwg & 7, xc = b & 7, oo = b >> 3;
    int sid = (xc < r8 ? xc * (q + 1) : r8 * (q + 1) + (xc - r8) * q) + oo;
    int bi = 0, rem = sid;
    while (rem >= T - bi) { rem -= T - bi; ++bi; }
    int bj = bi + rem;
    int i0 = bi * 128, j0 = bj * 128;

    int t    = threadIdx.x;
    int lane = t & 63;
    int wid  = t >> 6;
    int wrow = wid >> 1, wcol = wid & 1;
    int l15  = lane & 15, lg = lane >> 4;
    int sc16 = lane & 15;   // chunk slot 0..15
    int sr4  = lane >> 4;   // row subgroup 0..3

    f32x4 acc[4][4];
#pragma unroll
    for (int m = 0; m < 4; ++m)
#pragma unroll
        for (int nn = 0; nn < 4; ++nn)
#pragma unroll
            for (int r = 0; r < 4; ++r) acc[m][nn][r] = 0.f;

    bf16x8 sa[8], sb[8];
#pragma unroll
    for (int s = 0; s < 8; ++s) {
        int row = wid * 32 + sr4 * 8 + s;
        int gch = sc16 ^ (row & 7);
        sa[s] = *(const bf16x8*)(znb + (size_t)(i0 + row) * NN_HID + gch * 8);
        sb[s] = *(const bf16x8*)(znb + (size_t)(j0 + row) * NN_HID + gch * 8);
    }

#pragma unroll
    for (int kt = 0; kt < 2; ++kt) {
#pragma unroll
        for (int s = 0; s < 8; ++s) {
            int row = wid * 32 + sr4 * 8 + s;
            *(bf16x8*)(&As[row * 128 + sc16 * 8]) = sa[s];
            *(bf16x8*)(&Bs[row * 128 + sc16 * 8]) = sb[s];
        }
        __syncthreads();
        if (kt == 0) {
#pragma unroll
            for (int s = 0; s < 8; ++s) {
                int row = wid * 32 + sr4 * 8 + s;
                int gch = sc16 ^ (row & 7);
                sa[s] = *(const bf16x8*)(znb + (size_t)(i0 + row) * NN_HID + 128 + gch * 8);
                sb[s] = *(const bf16x8*)(znb + (size_t)(j0 + row) * NN_HID + 128 + gch * 8);
            }
        }
#pragma unroll
        for (int ks = 0; ks < 4; ++ks) {
            bf16x8 av[4], bv[4];
#pragma unroll
            for (int m = 0; m < 4; ++m) {
                int Ra = wrow * 64 + m * 16 + l15;
                int Rb = wcol * 64 + m * 16 + l15;
                int ca = (ks * 4 + lg) ^ (Ra & 7);
                int cb = (ks * 4 + lg) ^ (Rb & 7);
                av[m] = *(const bf16x8*)(&As[Ra * 128 + ca * 8]);
                bv[m] = *(const bf16x8*)(&Bs[Rb * 128 + cb * 8]);
            }
#pragma unroll
            for (int m = 0; m < 4; ++m)
#pragma unroll
                for (int nn = 0; nn < 4; ++nn)
                    acc[m][nn] = __builtin_amdgcn_mfma_f32_16x16x32_bf16(av[m], bv[nn], acc[m][nn], 0, 0, 0);
        }
        if (kt == 0) __syncthreads();
    }

    // epilogue: fast exp, masked; rowsums + colsums (symmetry)
    int i0w = i0 + wrow * 64;
    int j0w = j0 + wcol * 64;
    bool diag = (bj == bi);
#pragma unroll
    for (int m = 0; m < 4; ++m)
#pragma unroll
        for (int nn = 0; nn < 4; ++nn) {
            int gj = j0w + nn * 16 + l15;
            bool jok = gj < n;
#pragma unroll
            for (int r = 0; r < 4; ++r) {
                int gi = i0w + m * 16 + lg * 4 + r;
                acc[m][nn][r] = (jok && gi < n) ? __expf(acc[m][nn][r] * (1.f / TAU_F)) : 0.f;
            }
        }
    float* rowslot = P2d + (size_t)(2 * bj + wcol) * Npad;
#pragma unroll
    for (int m = 0; m < 4; ++m) {
#pragma unroll
        for (int r = 0; r < 4; ++r) {
            float v = acc[m][0][r] + acc[m][1][r] + acc[m][2][r] + acc[m][3][r];
            v += __shfl_xor(v, 1, 64);
            v += __shfl_xor(v, 2, 64);
            v += __shfl_xor(v, 4, 64);
            v += __shfl_xor(v, 8, 64);
            if (l15 == 0) {
                int gi = i0w + m * 16 + lg * 4 + r;
                if (gi < n) rowslot[gi] = v;
            }
        }
    }
    if (!diag) {
        float* colslot = P2d + (size_t)(2 * bi + wrow) * Npad;
#pragma unroll
        for (int nn = 0; nn < 4; ++nn) {
            float v = 0.f;
#pragma unroll
            for (int m = 0; m < 4; ++m)
#pragma unroll
                for (int r = 0; r < 4; ++r) v += acc[m][nn][r];
            v += __shfl_xor(v, 16, 64);
            v += __shfl_xor(v, 32, 64);
            if (lg == 0) {
                int gj = j0w + nn * 16 + l15;
                if (gj < n) colslot[gj] = v;
            }
        }
    }
}

// ---------------------------------------------------------------------------
// Parallel fold of partial slots: R[i] = sum_sl P2d[sl][i]
// ---------------------------------------------------------------------------
__global__ void fold_kernel(const float* __restrict__ P2d, float* __restrict__ R,
                            int n, int slots, int Npad) {
    int i = blockIdx.x * 256 + threadIdx.x;
    if (i >= n) return;
    const float* p = P2d + i;
    float s0 = 0.f, s1 = 0.f, s2 = 0.f, s3 = 0.f;
    int sl = 0;
    for (; sl + 4 <= slots; sl += 4) {
        s0 += p[(size_t)(sl + 0) * Npad];
        s1 += p[(size_t)(sl + 1) * Npad];
        s2 += p[(size_t)(sl + 2) * Npad];
        s3 += p[(size_t)(sl + 3) * Npad];
    }
    for (; sl < slots; ++sl) s0 += p[(size_t)sl * Npad];
    R[i] = (s0 + s1) + (s2 + s3);
}

__global__ void loss_kernel(const float* __restrict__ R, const float* __restrict__ dvec,
                            float* __restrict__ out_loss, int n) {
    __shared__ float s[1024];
    int t = threadIdx.x;
    float sum = 0.f;
    for (int i = t; i < n; i += 1024) {
        float d   = dvec[i];
        float off = R[i] - d;
        sum += -logf(d / (off + off));
    }
    s[t] = sum;
    __syncthreads();
    for (int o = 512; o > 0; o >>= 1) {
        if (t < o) s[t] += s[t + o];
        __syncthreads();
    }
    if (t == 0) *out_loss = s[0] / n;
}

// ---------------------------------------------------------------------------
extern "C" void kernel_launch(void* const* d_in, const int* in_sizes, int n_in,
                              void* d_out, int out_size, void* d_ws, size_t ws_size,
                              hipStream_t stream) {
    const float* x   = (const float*)d_in[0];
    const int*   src = (const int*)d_in[1];
    const int*   dst = (const int*)d_in[2];
    const float* W0  = (const float*)d_in[3];
    const float* a0s = (const float*)d_in[4];
    const float* a0d = (const float*)d_in[5];
    const float* W1  = (const float*)d_in[6];
    const float* a1s = (const float*)d_in[7];
    const float* a1d = (const float*)d_in[8];
    const float* W2  = (const float*)d_in[9];
    const float* a2s = (const float*)d_in[10];
    const float* a2d = (const float*)d_in[11];
    const float* Wout= (const float*)d_in[12];
    const float* aos = (const float*)d_in[13];
    const float* aod = (const float*)d_in[14];

    int N = in_sizes[0] / NN_F_IN;
    int E = in_sizes[1];
    int Npad = ((N + 127) / 128) * 128;
    int T = Npad / 128;
    int nwg = T * (T + 1) / 2;
    float* out = (float*)d_out;

    char*  ws  = (char*)d_ws;
    size_t off = 0;
    auto alloc = [&](size_t bytes) -> void* {
        void* p = ws + off;
        off += bytes;
        off = (off + 255) & ~(size_t)255;
        return p;
    };
    size_t hbBytes = (size_t)N * 320 * 2;
    size_t znBytes = (size_t)Npad * NN_HID * 2;
    unsigned short* Hb = (unsigned short*)alloc(hbBytes > znBytes ? hbBytes : znBytes);
    short* znb = (short*)Hb;  // alias: znb live only between rownorm and gram
    unsigned short* Bl = (unsigned short*)alloc((size_t)N * NN_HID * 2);
    unsigned short* Bc = (unsigned short*)alloc((size_t)N * NN_HID * 2);
    size_t xbBytes = (size_t)N * NN_F_IN * 2;
    size_t p2Bytes = (size_t)2 * T * Npad * 4;
    void* XbP2d = alloc(xbBytes > p2Bytes ? xbBytes : p2Bytes);
    unsigned short* Xb  = (unsigned short*)XbP2d;  // live: prep..fc L0
    float*          P2d = (float*)XbP2d;           // live: memset..fold
    unsigned short* Wt0 = (unsigned short*)alloc((size_t)256 * 512 * 2);
    unsigned short* Wt1 = (unsigned short*)alloc((size_t)256 * 256 * 2);
    unsigned short* Wt2 = (unsigned short*)alloc((size_t)256 * 256 * 2);
    unsigned short* Wto = (unsigned short*)alloc((size_t)384 * 256 * 2);
    float* es     = (float*)alloc((size_t)N * NN_HEADS * 4);
    float* ed     = (float*)alloc((size_t)N * NN_HEADS * 4);
    float* wC     = (float*)alloc((size_t)E * NN_HEADS * 4);
    float* zinvA  = (float*)alloc((size_t)N * NN_HEADS * 4);
    float* Rrow   = (float*)alloc((size_t)N * 4);
    float* dvec   = (float*)alloc((size_t)N * 4);
    int*   counts = (int*)alloc((size_t)N * 4);
    int*   rs     = (int*)alloc((size_t)(N + 1) * 4);
    int*   cursor = (int*)alloc((size_t)N * 4);
    int*   csr    = (int*)alloc((size_t)E * 4);

    // ---- CSR build
    hipMemsetAsync(counts, 0, (size_t)N * 4, stream);
    count_kernel<<<(E + 255) / 256, 256, 0, stream>>>(dst, counts, E);
    scan_kernel<<<1, 1024, 0, stream>>>(counts, rs, cursor, N);
    scatter_kernel<<<(E + 255) / 256, 256, 0, stream>>>(src, dst, cursor, csr, E);

    // ---- fused prep (X + 4 W casts)
    int n4X = N * NN_F_IN / 4;
    int prepTotal = n4X + 256 * 512 + 256 * 256 + 256 * 256 + 384 * 256;
    prep_kernel<<<(prepTotal + 255) / 256, 256, 0, stream>>>(
        x, W0, W1, W2, Wout, Xb, Wt0, Wt1, Wt2, Wto, n4X);

    int atGrid = (N * NN_HEADS + 255) / 256;
    int ghGrid = (N + 3) / 4;
    int mT64 = (N + 63) / 64;

    // ---- layer 0: Xb -> Hb -> Bl
    fc_mfma<<<dim3(4, mT64), 256, 0, stream>>>(Xb, Wt0, Hb, N, 512, 256, 256);
    attn_kernel<<<atGrid, 256, 0, stream>>>(Hb, a0s, a0d, es, ed, N, NN_FH);
    edge_wz<<<ghGrid, 256, 0, stream>>>(es, ed, csr, rs, wC, zinvA, N);
    gather_hidden<<<ghGrid, 256, 0, stream>>>(Hb, wC, zinvA, csr, rs, nullptr, Bl, N, -1.f);

    // ---- layer 1: Bl -> Hb -> Bc (beta = 0.5/3)
    fc_mfma<<<dim3(4, mT64), 256, 0, stream>>>(Bl, Wt1, Hb, N, 256, 256, 256);
    attn_kernel<<<atGrid, 256, 0, stream>>>(Hb, a1s, a1d, es, ed, N, NN_FH);
    edge_wz<<<ghGrid, 256, 0, stream>>>(es, ed, csr, rs, wC, zinvA, N);
    gather_hidden<<<ghGrid, 256, 0, stream>>>(Hb, wC, zinvA, csr, rs, Bl, Bc, N, LAMDA_F / 3.f);

    // ---- layer 2: Bc -> Hb -> Bl (beta = 0.5/4)
    fc_mfma<<<dim3(4, mT64), 256, 0, stream>>>(Bc, Wt2, Hb, N, 256, 256, 256);
    attn_kernel<<<atGrid, 256, 0, stream>>>(Hb, a2s, a2d, es, ed, N, NN_FH);
    edge_wz<<<ghGrid, 256, 0, stream>>>(es, ed, csr, rs, wC, zinvA, N);
    gather_hidden<<<ghGrid, 256, 0, stream>>>(Hb, wC, zinvA, csr, rs, Bc, Bl, N, LAMDA_F / 4.f);

    // ---- bind_loss(Bl): znb (aliases Hb), partial slots in P2d
    rownorm_kernel<<<N, 256, 0, stream>>>(Bl, znb, dvec, N);
    hipMemsetAsync(znb + (size_t)N * NN_HID, 0, (size_t)(Npad - N) * NN_HID * 2, stream);
    hipMemsetAsync(P2d, 0, (size_t)2 * T * Npad * 4, stream);
    gram_mfma<<<nwg, 256, 0, stream>>>(znb, P2d, N, T, nwg, Npad);
    fold_kernel<<<(N + 255) / 256, 256, 0, stream>>>(P2d, Rrow, N, 2 * T, Npad);
    loss_kernel<<<1, 1024, 0, stream>>>(Rrow, dvec, out + (size_t)N * NN_NCLASS, N);

    // ---- output layer: Bl -> Hb(320) -> d_out
    fc_mfma<<<dim3(5, mT64), 256, 0, stream>>>(Bl, Wto, Hb, N, 256, 320, 320);
    attn_kernel<<<atGrid, 256, 0, stream>>>(Hb, aos, aod, es, ed, N, NN_NCLASS);
    edge_wz<<<ghGrid, 256, 0, stream>>>(es, ed, csr, rs, wC, zinvA, N);
    gather_final<<<N, NN_HEADS * NN_NCLASS, 0, stream>>>(Hb, wC, zinvA, csr, rs, out, N);
}

// Round 10
// 408.789 us; speedup vs baseline: 2.2618x; 1.0154x over previous
//
#include <hip/hip_runtime.h>
#include <hip/hip_bf16.h>
#include <math.h>

#define NN_F_IN   512
#define NN_HID    256
#define NN_HEADS  8
#define NN_FH     32
#define NN_NCLASS 40
#define TAU_F     0.5f
#define LAMDA_F   0.5f

typedef __attribute__((ext_vector_type(8))) short bf16x8;
typedef __attribute__((ext_vector_type(4))) float f32x4;

static __device__ __forceinline__ float lrelu02(float x) { return x >= 0.f ? x : 0.2f * x; }
static __device__ __forceinline__ float elu1(float x)    { return x > 0.f ? x : expm1f(x); }
static __device__ __forceinline__ float b2f(unsigned short u) {
    unsigned int x = ((unsigned int)u) << 16;
    return __uint_as_float(x);
}
static __device__ __forceinline__ unsigned short f2b(float f) {
    __hip_bfloat16 hb = __float2bfloat16(f);
    return *reinterpret_cast<unsigned short*>(&hb);
}

// ---------------------------------------------------------------------------
// Fused prep: X cast (float4-wide) + 4 transposed W casts, one launch.
// ---------------------------------------------------------------------------
__global__ void prep_kernel(const float* __restrict__ x,
                            const float* __restrict__ W0, const float* __restrict__ W1,
                            const float* __restrict__ W2, const float* __restrict__ Wo,
                            unsigned short* __restrict__ Xb,
                            unsigned short* __restrict__ Wt0, unsigned short* __restrict__ Wt1,
                            unsigned short* __restrict__ Wt2, unsigned short* __restrict__ Wto,
                            int n4X) {
    int i = blockIdx.x * 256 + threadIdx.x;
    if (i < n4X) {
        float4 v = *(const float4*)(x + (size_t)i * 4);
        ushort4 o;
        o.x = f2b(v.x); o.y = f2b(v.y); o.z = f2b(v.z); o.w = f2b(v.w);
        *(ushort4*)(Xb + (size_t)i * 4) = o;
        return;
    }
    i -= n4X;
    if (i < 256 * 512) {            // Wt0: Np=256, K=512, Nc=256
        int np = i >> 9, k = i & 511;
        Wt0[i] = f2b(W0[(size_t)k * 256 + np]);
        return;
    }
    i -= 256 * 512;
    if (i < 256 * 256) {            // Wt1
        int np = i >> 8, k = i & 255;
        Wt1[i] = f2b(W1[(size_t)k * 256 + np]);
        return;
    }
    i -= 256 * 256;
    if (i < 256 * 256) {            // Wt2
        int np = i >> 8, k = i & 255;
        Wt2[i] = f2b(W2[(size_t)k * 256 + np]);
        return;
    }
    i -= 256 * 256;
    if (i < 384 * 256) {            // Wto: Np=384, K=256, Nc=320
        int np = i >> 8, k = i & 255;
        Wto[i] = f2b(np < 320 ? Wo[(size_t)k * 320 + np] : 0.f);
    }
}

// ---------------------------------------------------------------------------
// MFMA GEMM: H[m][col] = sum_k A[m][k] * B[col][k], A/B bf16, H bf16.
// Block = 4 waves 2x2 -> 64x64 tile; wave = 32x32 = 2x2 frags of 16x16x32.
// ---------------------------------------------------------------------------
__global__ __launch_bounds__(256) void fc_mfma(const unsigned short* __restrict__ A,
                                               const unsigned short* __restrict__ B,
                                               unsigned short* __restrict__ H,
                                               int M, int K, int ncols, int ldH) {
    int t = threadIdx.x, lane = t & 63, wid = t >> 6;
    int wrow = wid >> 1, wcol = wid & 1;
    int l15 = lane & 15, lg = lane >> 4;
    int mbase = blockIdx.y * 64 + wrow * 32;
    int nbase = blockIdx.x * 64 + wcol * 32;

    const unsigned short* Ap[2];
    const unsigned short* Bp[2];
#pragma unroll
    for (int m = 0; m < 2; ++m) {
        int rr = mbase + m * 16 + l15;
        if (rr > M - 1) rr = M - 1;
        Ap[m] = A + (size_t)rr * K + lg * 8;
        Bp[m] = B + (size_t)(nbase + m * 16 + l15) * K + lg * 8;
    }
    f32x4 acc[2][2];
#pragma unroll
    for (int m = 0; m < 2; ++m)
#pragma unroll
        for (int nn = 0; nn < 2; ++nn)
#pragma unroll
            for (int r = 0; r < 4; ++r) acc[m][nn][r] = 0.f;

    bf16x8 aP[2], bP[2], aQ[2], bQ[2];
#pragma unroll
    for (int m = 0; m < 2; ++m) {
        aP[m] = *(const bf16x8*)(Ap[m]);
        bP[m] = *(const bf16x8*)(Bp[m]);
    }
    int nhalf = K >> 6;
    int kk = 32;
    for (int it = 0; it < nhalf; ++it) {
#pragma unroll
        for (int m = 0; m < 2; ++m) {
            aQ[m] = *(const bf16x8*)(Ap[m] + kk);
            bQ[m] = *(const bf16x8*)(Bp[m] + kk);
        }
#pragma unroll
        for (int m = 0; m < 2; ++m)
#pragma unroll
            for (int nn = 0; nn < 2; ++nn)
                acc[m][nn] = __builtin_amdgcn_mfma_f32_16x16x32_bf16(aP[m], bP[nn], acc[m][nn], 0, 0, 0);
        if (it + 1 < nhalf) {
#pragma unroll
            for (int m = 0; m < 2; ++m) {
                aP[m] = *(const bf16x8*)(Ap[m] + kk + 32);
                bP[m] = *(const bf16x8*)(Bp[m] + kk + 32);
            }
        }
#pragma unroll
        for (int m = 0; m < 2; ++m)
#pragma unroll
            for (int nn = 0; nn < 2; ++nn)
                acc[m][nn] = __builtin_amdgcn_mfma_f32_16x16x32_bf16(aQ[m], bQ[nn], acc[m][nn], 0, 0, 0);
        kk += 64;
    }
#pragma unroll
    for (int m = 0; m < 2; ++m) {
#pragma unroll
        for (int nn = 0; nn < 2; ++nn) {
            int col = nbase + nn * 16 + l15;
            if (col >= ncols) continue;
#pragma unroll
            for (int r = 0; r < 4; ++r) {
                int row = mbase + m * 16 + lg * 4 + r;
                if (row < M) H[(size_t)row * ldH + col] = f2b(acc[m][nn][r]);
            }
        }
    }
}

// ---------------------------------------------------------------------------
// es/ed dot products (Hm bf16)
// ---------------------------------------------------------------------------
__global__ void attn_kernel(const unsigned short* __restrict__ Hm, const float* __restrict__ As,
                            const float* __restrict__ Ad, float* __restrict__ es,
                            float* __restrict__ ed, int n, int df) {
    int idx = blockIdx.x * blockDim.x + threadIdx.x;
    if (idx >= n * NN_HEADS) return;
    int nn = idx / NN_HEADS, hh = idx - nn * NN_HEADS;
    const unsigned short* hp = Hm + (size_t)nn * NN_HEADS * df + hh * df;
    const float* ap = As + hh * df;
    const float* bp = Ad + hh * df;
    float s1 = 0.f, s2 = 0.f;
    for (int d = 0; d < df; d += 4) {
        ushort4 hv = *(const ushort4*)(hp + d);
        float4 av = *(const float4*)(ap + d);
        float4 bv = *(const float4*)(bp + d);
        float h0 = b2f(hv.x), h1 = b2f(hv.y), h2 = b2f(hv.z), h3 = b2f(hv.w);
        s1 += h0 * av.x + h1 * av.y + h2 * av.z + h3 * av.w;
        s2 += h0 * bv.x + h1 * bv.y + h2 * bv.z + h3 * bv.w;
    }
    es[idx] = s1;
    ed[idx] = s2;
}

// ---------------------------------------------------------------------------
// Edge weights: one fast-exp per (edge,head). wC[p][h] CSR order, zinv[n][h].
// ---------------------------------------------------------------------------
__global__ __launch_bounds__(256) void edge_wz(
    const float* __restrict__ es, const float* __restrict__ ed,
    const int* __restrict__ csr_src, const int* __restrict__ row_start,
    float* __restrict__ wC, float* __restrict__ zinv, int n) {
    int lane = threadIdx.x & 63;
    int nn   = blockIdx.x * 4 + (threadIdx.x >> 6);
    if (nn >= n) return;
    int s0 = row_start[nn], s1 = row_start[nn + 1];
    int h    = lane & 7;
    int slot = lane >> 3;
    float edh = ed[nn * NN_HEADS + h];
    float z = 0.f;
    for (int e = s0 + slot; e < s1; e += 8) {
        int sv = csr_src[e];
        float w = __expf(lrelu02(es[sv * NN_HEADS + h] + edh));
        wC[(size_t)e * NN_HEADS + h] = w;
        z += w;
    }
    z += __shfl_xor(z, 8, 64);
    z += __shfl_xor(z, 16, 64);
    z += __shfl_xor(z, 32, 64);
    if (slot == 0) zinv[nn * NN_HEADS + h] = 1.f / z;
}

// ---------------------------------------------------------------------------
// CSR build
// ---------------------------------------------------------------------------
__global__ void count_kernel(const int* __restrict__ dst, int* __restrict__ counts, int E) {
    int e = blockIdx.x * blockDim.x + threadIdx.x;
    if (e < E) atomicAdd(&counts[dst[e]], 1);
}

__global__ void scan_kernel(const int* __restrict__ counts, int* __restrict__ row_start,
                            int* __restrict__ cursor, int n) {
    __shared__ int s[1024];
    int t  = threadIdx.x;
    int ch = (n + 1023) / 1024;
    int lo = t * ch;
    int sum = 0;
    for (int j = 0; j < ch; ++j) {
        int i = lo + j;
        if (i < n) sum += counts[i];
    }
    s[t] = sum;
    __syncthreads();
    for (int off = 1; off < 1024; off <<= 1) {
        int v = 0;
        if (t >= off) v = s[t - off];
        __syncthreads();
        s[t] += v;
        __syncthreads();
    }
    int run = (t == 0) ? 0 : s[t - 1];
    for (int j = 0; j < ch; ++j) {
        int i = lo + j;
        if (i < n) {
            row_start[i] = run;
            cursor[i] = run;
            run += counts[i];
        }
    }
    if (t == 1023) row_start[n] = s[1023];
}

__global__ void scatter_kernel(const int* __restrict__ src, const int* __restrict__ dst,
                               int* __restrict__ cursor, int* __restrict__ csr_src, int E) {
    int e = blockIdx.x * blockDim.x + threadIdx.x;
    if (e < E) {
        int d   = dst[e];
        int pos = atomicAdd(&cursor[d], 1);
        csr_src[pos] = src[e];
    }
}

// ---------------------------------------------------------------------------
// Hidden-layer gather: weighted sum; guard-free full batches + guarded tail.
// ---------------------------------------------------------------------------
__global__ __launch_bounds__(256) void gather_hidden(
    const unsigned short* __restrict__ Hm, const float* __restrict__ wC,
    const float* __restrict__ zinv, const int* __restrict__ csr_src,
    const int* __restrict__ row_start, const unsigned short* __restrict__ last,
    unsigned short* __restrict__ out, int n, float beta) {
    int lane = threadIdx.x & 63;
    int nn   = blockIdx.x * 4 + (threadIdx.x >> 6);
    if (nn >= n) return;
    int s0 = row_start[nn], s1 = row_start[nn + 1];
    int h2 = lane >> 3;

    float a0 = 0.f, a1 = 0.f, a2 = 0.f, a3 = 0.f;
    int fullEnd = s0 + ((s1 - s0) & ~7);
    int e = s0;
    for (; e < fullEnd; e += 8) {
        int idx[8];
        float wv[8];
#pragma unroll
        for (int j = 0; j < 8; ++j) {
            idx[j] = csr_src[e + j];
            wv[j]  = wC[(size_t)(e + j) * NN_HEADS + h2];
        }
        ushort4 r[8];
#pragma unroll
        for (int j = 0; j < 8; ++j) r[j] = *(const ushort4*)&Hm[(size_t)idx[j] * NN_HID + lane * 4];
#pragma unroll
        for (int j = 0; j < 8; ++j) {
            float w = wv[j];
            a0 += w * b2f(r[j].x); a1 += w * b2f(r[j].y);
            a2 += w * b2f(r[j].z); a3 += w * b2f(r[j].w);
        }
    }
    if (e < s1) {
        int c = s1 - e;
        int idx[8];
        float wv[8];
#pragma unroll
        for (int j = 0; j < 8; ++j) {
            int p = (j < c) ? e + j : e;
            idx[j] = csr_src[p];
            wv[j]  = wC[(size_t)p * NN_HEADS + h2];
        }
        ushort4 r[8];
#pragma unroll
        for (int j = 0; j < 8; ++j) r[j] = *(const ushort4*)&Hm[(size_t)idx[j] * NN_HID + lane * 4];
#pragma unroll
        for (int j = 0; j < 8; ++j) {
            if (j < c) {
                float w = wv[j];
                a0 += w * b2f(r[j].x); a1 += w * b2f(r[j].y);
                a2 += w * b2f(r[j].z); a3 += w * b2f(r[j].w);
            }
        }
    }
    float zi = zinv[nn * NN_HEADS + h2];
    float v0 = elu1(a0 * zi), v1 = elu1(a1 * zi), v2 = elu1(a2 * zi), v3 = elu1(a3 * zi);
    if (beta >= 0.f) {
        ushort4 lv = *(const ushort4*)&last[(size_t)nn * NN_HID + lane * 4];
        v0 = beta * b2f(lv.x) + (1.f - beta) * v0;
        v1 = beta * b2f(lv.y) + (1.f - beta) * v1;
        v2 = beta * b2f(lv.z) + (1.f - beta) * v2;
        v3 = beta * b2f(lv.w) + (1.f - beta) * v3;
    }
    ushort4 o;
    o.x = f2b(v0); o.y = f2b(v1); o.z = f2b(v2); o.w = f2b(v3);
    *(ushort4*)&out[(size_t)nn * NN_HID + lane * 4] = o;
}

// ---------------------------------------------------------------------------
// Final layer gather: weighted sum + head-mean + log_softmax -> d_out
// ---------------------------------------------------------------------------
__global__ void gather_final(const unsigned short* __restrict__ Hm, const float* __restrict__ wC,
                             const float* __restrict__ zinv, const int* __restrict__ csr_src,
                             const int* __restrict__ row_start, float* __restrict__ dout, int n) {
    int nn = blockIdx.x;
    __shared__ float accs[NN_HEADS * NN_NCLASS];
    int t = threadIdx.x;  // 0..319
    int s0 = row_start[nn], s1 = row_start[nn + 1];
    int hh = t / NN_NCLASS;
    float acc = 0.f;
    const int LD = NN_HEADS * NN_NCLASS;
    int fullEnd = s0 + ((s1 - s0) & ~7);
    int e = s0;
    for (; e < fullEnd; e += 8) {
        int idx[8];
        float wv[8];
#pragma unroll
        for (int j = 0; j < 8; ++j) {
            idx[j] = csr_src[e + j];
            wv[j]  = wC[(size_t)(e + j) * NN_HEADS + hh];
        }
        float v[8];
#pragma unroll
        for (int j = 0; j < 8; ++j) v[j] = b2f(Hm[(size_t)idx[j] * LD + t]);
#pragma unroll
        for (int j = 0; j < 8; ++j) acc += wv[j] * v[j];
    }
    if (e < s1) {
        int c = s1 - e;
        int idx[8];
        float wv[8];
#pragma unroll
        for (int j = 0; j < 8; ++j) {
            int p = (j < c) ? e + j : e;
            idx[j] = csr_src[p];
            wv[j]  = wC[(size_t)p * NN_HEADS + hh];
        }
        float v[8];
#pragma unroll
        for (int j = 0; j < 8; ++j) v[j] = b2f(Hm[(size_t)idx[j] * LD + t]);
#pragma unroll
        for (int j = 0; j < 8; ++j) {
            if (j < c) acc += wv[j] * v[j];
        }
    }
    accs[t] = acc * zinv[nn * NN_HEADS + hh];
    __syncthreads();
    if (t < 64) {
        float v = -INFINITY;
        if (t < NN_NCLASS) {
            float sacc = 0.f;
#pragma unroll
            for (int h2 = 0; h2 < NN_HEADS; ++h2) sacc += accs[h2 * NN_NCLASS + t];
            v = sacc * (1.f / NN_HEADS);
        }
        float mx = v;
#pragma unroll
        for (int o = 1; o < 64; o <<= 1) mx = fmaxf(mx, __shfl_xor(mx, o, 64));
        float ex = (t < NN_NCLASS) ? expf(v - mx) : 0.f;
        float se = ex;
#pragma unroll
        for (int o = 1; o < 64; o <<= 1) se += __shfl_xor(se, o, 64);
        if (t < NN_NCLASS) dout[(size_t)nn * NN_NCLASS + t] = (v - mx) - logf(se);
    }
}

// ---------------------------------------------------------------------------
// Row-normalize (bf16 in) + bf16 zn + analytic diagonal
// ---------------------------------------------------------------------------
__global__ void rownorm_kernel(const unsigned short* __restrict__ z, short* __restrict__ znb,
                               float* __restrict__ dvec, int n) {
    int nn = blockIdx.x;
    int t  = threadIdx.x;  // 256
    float v  = b2f(z[(size_t)nn * NN_HID + t]);
    float sq = v * v;
#pragma unroll
    for (int o = 1; o < 64; o <<= 1) sq += __shfl_xor(sq, o, 64);
    __shared__ float ws[4];
    if ((t & 63) == 0) ws[t >> 6] = sq;
    __syncthreads();
    float s = ws[0] + ws[1] + ws[2] + ws[3];
    float m = fmaxf(sqrtf(s), 1e-12f);
    znb[(size_t)nn * NN_HID + t] = (short)f2b(v / m);
    if (t == 0) dvec[nn] = __expf((s / (m * m)) * (1.f / TAU_F));
}

// ---------------------------------------------------------------------------
// Symmetric gram rowsums, BK=128 / 3-barrier schedule, NO atomics.
// LDS = 4 slabs of [128 rows][64 k] (16KB each) — EXACTLY R8's proven
// zero-conflict geometry per slab (stride 128B, 8 chunks, slot=chunk^(row&7)).
// R9's flat [128][128] (256B stride) produced 3.2M bank conflicts; this keeps
// the BK=128 barrier savings while restoring the conflict-free slab layout.
// K visit order identical to R9 -> bit-identical results.
// ---------------------------------------------------------------------------
__global__ __launch_bounds__(256) void gram_mfma(const short* __restrict__ znb,
                                                 float* __restrict__ P2d, int n,
                                                 int T, int nwg, int Npad) {
    __shared__ short As[2][128 * 64];
    __shared__ short Bs[2][128 * 64];

    int b = blockIdx.x;
    int q = nwg >> 3, r8 = nwg & 7, xc = b & 7, oo = b >> 3;
    int sid = (xc < r8 ? xc * (q + 1) : r8 * (q + 1) + (xc - r8) * q) + oo;
    int bi = 0, rem = sid;
    while (rem >= T - bi) { rem -= T - bi; ++bi; }
    int bj = bi + rem;
    int i0 = bi * 128, j0 = bj * 128;

    int t    = threadIdx.x;
    int lane = t & 63;
    int wid  = t >> 6;
    int wrow = wid >> 1, wcol = wid & 1;
    int l15  = lane & 15, lg = lane >> 4;
    int srow = lane >> 3;   // 0..7
    int sch  = lane & 7;    // 0..7

    f32x4 acc[4][4];
#pragma unroll
    for (int m = 0; m < 4; ++m)
#pragma unroll
        for (int nn = 0; nn < 4; ++nn)
#pragma unroll
            for (int r = 0; r < 4; ++r) acc[m][nn][r] = 0.f;

    bf16x8 sa[2][4], sb[2][4];
    // prologue: stage kt=0 (k 0..127 = 2 slabs of 64)
#pragma unroll
    for (int sl = 0; sl < 2; ++sl)
#pragma unroll
        for (int s = 0; s < 4; ++s) {
            int row = wid * 32 + s * 8 + srow;
            int gch = sch ^ (row & 7);
            sa[sl][s] = *(const bf16x8*)(znb + (size_t)(i0 + row) * NN_HID + sl * 64 + gch * 8);
            sb[sl][s] = *(const bf16x8*)(znb + (size_t)(j0 + row) * NN_HID + sl * 64 + gch * 8);
        }

#pragma unroll
    for (int kt = 0; kt < 2; ++kt) {
#pragma unroll
        for (int sl = 0; sl < 2; ++sl)
#pragma unroll
            for (int s = 0; s < 4; ++s) {
                int row = wid * 32 + s * 8 + srow;
                *(bf16x8*)(&As[sl][row * 64 + sch * 8]) = sa[sl][s];
                *(bf16x8*)(&Bs[sl][row * 64 + sch * 8]) = sb[sl][s];
            }
        __syncthreads();
        if (kt == 0) {
            // issue kt=1 global loads (k 128..255), overlap with compute below
#pragma unroll
            for (int sl = 0; sl < 2; ++sl)
#pragma unroll
                for (int s = 0; s < 4; ++s) {
                    int row = wid * 32 + s * 8 + srow;
                    int gch = sch ^ (row & 7);
                    sa[sl][s] = *(const bf16x8*)(znb + (size_t)(i0 + row) * NN_HID + 128 + sl * 64 + gch * 8);
                    sb[sl][s] = *(const bf16x8*)(znb + (size_t)(j0 + row) * NN_HID + 128 + sl * 64 + gch * 8);
                }
        }
#pragma unroll
        for (int sl = 0; sl < 2; ++sl) {
#pragma unroll
            for (int ks = 0; ks < 2; ++ks) {
                bf16x8 av[4], bv[4];
#pragma unroll
                for (int m = 0; m < 4; ++m) {
                    int Ra = wrow * 64 + m * 16 + l15;
                    int Rb = wcol * 64 + m * 16 + l15;
                    int ca = (ks * 4 + lg) ^ (Ra & 7);
                    int cb = (ks * 4 + lg) ^ (Rb & 7);
                    av[m] = *(const bf16x8*)(&As[sl][Ra * 64 + ca * 8]);
                    bv[m] = *(const bf16x8*)(&Bs[sl][Rb * 64 + cb * 8]);
                }
#pragma unroll
                for (int m = 0; m < 4; ++m)
#pragma unroll
                    for (int nn = 0; nn < 4; ++nn)
                        acc[m][nn] = __builtin_amdgcn_mfma_f32_16x16x32_bf16(av[m], bv[nn], acc[m][nn], 0, 0, 0);
            }
        }
        if (kt == 0) __syncthreads();
    }

    // epilogue: fast exp, masked; rowsums + colsums (symmetry)
    int i0w = i0 + wrow * 64;
    int j0w = j0 + wcol * 64;
    bool diag = (bj == bi);
#pragma unroll
    for (int m = 0; m < 4; ++m)
#pragma unroll
        for (int nn = 0; nn < 4; ++nn) {
            int gj = j0w + nn * 16 + l15;
            bool jok = gj < n;
#pragma unroll
            for (int r = 0; r < 4; ++r) {
                int gi = i0w + m * 16 + lg * 4 + r;
                acc[m][nn][r] = (jok && gi < n) ? __expf(acc[m][nn][r] * (1.f / TAU_F)) : 0.f;
            }
        }
    float* rowslot = P2d + (size_t)(2 * bj + wcol) * Npad;
#pragma unroll
    for (int m = 0; m < 4; ++m) {
#pragma unroll
        for (int r = 0; r < 4; ++r) {
            float v = acc[m][0][r] + acc[m][1][r] + acc[m][2][r] + acc[m][3][r];
            v += __shfl_xor(v, 1, 64);
            v += __shfl_xor(v, 2, 64);
            v += __shfl_xor(v, 4, 64);
            v += __shfl_xor(v, 8, 64);
            if (l15 == 0) {
                int gi = i0w + m * 16 + lg * 4 + r;
                if (gi < n) rowslot[gi] = v;
            }
        }
    }
    if (!diag) {
        float* colslot = P2d + (size_t)(2 * bi + wrow) * Npad;
#pragma unroll
        for (int nn = 0; nn < 4; ++nn) {
            float v = 0.f;
#pragma unroll
            for (int m = 0; m < 4; ++m)
#pragma unroll
                for (int r = 0; r < 4; ++r) v += acc[m][nn][r];
            v += __shfl_xor(v, 16, 64);
            v += __shfl_xor(v, 32, 64);
            if (lg == 0) {
                int gj = j0w + nn * 16 + l15;
                if (gj < n) colslot[gj] = v;
            }
        }
    }
}

// ---------------------------------------------------------------------------
// Parallel fold of partial slots: R[i] = sum_sl P2d[sl][i]
// ---------------------------------------------------------------------------
__global__ void fold_kernel(const float* __restrict__ P2d, float* __restrict__ R,
                            int n, int slots, int Npad) {
    int i = blockIdx.x * 256 + threadIdx.x;
    if (i >= n) return;
    const float* p = P2d + i;
    float s0 = 0.f, s1 = 0.f, s2 = 0.f, s3 = 0.f;
    int sl = 0;
    for (; sl + 4 <= slots; sl += 4) {
        s0 += p[(size_t)(sl + 0) * Npad];
        s1 += p[(size_t)(sl + 1) * Npad];
        s2 += p[(size_t)(sl + 2) * Npad];
        s3 += p[(size_t)(sl + 3) * Npad];
    }
    for (; sl < slots; ++sl) s0 += p[(size_t)sl * Npad];
    R[i] = (s0 + s1) + (s2 + s3);
}

__global__ void loss_kernel(const float* __restrict__ R, const float* __restrict__ dvec,
                            float* __restrict__ out_loss, int n) {
    __shared__ float s[1024];
    int t = threadIdx.x;
    float sum = 0.f;
    for (int i = t; i < n; i += 1024) {
        float d   = dvec[i];
        float off = R[i] - d;
        sum += -logf(d / (off + off));
    }
    s[t] = sum;
    __syncthreads();
    for (int o = 512; o > 0; o >>= 1) {
        if (t < o) s[t] += s[t + o];
        __syncthreads();
    }
    if (t == 0) *out_loss = s[0] / n;
}

// ---------------------------------------------------------------------------
extern "C" void kernel_launch(void* const* d_in, const int* in_sizes, int n_in,
                              void* d_out, int out_size, void* d_ws, size_t ws_size,
                              hipStream_t stream) {
    const float* x   = (const float*)d_in[0];
    const int*   src = (const int*)d_in[1];
    const int*   dst = (const int*)d_in[2];
    const float* W0  = (const float*)d_in[3];
    const float* a0s = (const float*)d_in[4];
    const float* a0d = (const float*)d_in[5];
    const float* W1  = (const float*)d_in[6];
    const float* a1s = (const float*)d_in[7];
    const float* a1d = (const float*)d_in[8];
    const float* W2  = (const float*)d_in[9];
    const float* a2s = (const float*)d_in[10];
    const float* a2d = (const float*)d_in[11];
    const float* Wout= (const float*)d_in[12];
    const float* aos = (const float*)d_in[13];
    const float* aod = (const float*)d_in[14];

    int N = in_sizes[0] / NN_F_IN;
    int E = in_sizes[1];
    int Npad = ((N + 127) / 128) * 128;
    int T = Npad / 128;
    int nwg = T * (T + 1) / 2;
    float* out = (float*)d_out;

    char*  ws  = (char*)d_ws;
    size_t off = 0;
    auto alloc = [&](size_t bytes) -> void* {
        void* p = ws + off;
        off += bytes;
        off = (off + 255) & ~(size_t)255;
        return p;
    };
    size_t hbBytes = (size_t)N * 320 * 2;
    size_t znBytes = (size_t)Npad * NN_HID * 2;
    unsigned short* Hb = (unsigned short*)alloc(hbBytes > znBytes ? hbBytes : znBytes);
    short* znb = (short*)Hb;  // alias: znb live only between rownorm and gram
    unsigned short* Bl = (unsigned short*)alloc((size_t)N * NN_HID * 2);
    unsigned short* Bc = (unsigned short*)alloc((size_t)N * NN_HID * 2);
    size_t xbBytes = (size_t)N * NN_F_IN * 2;
    size_t p2Bytes = (size_t)2 * T * Npad * 4;
    void* XbP2d = alloc(xbBytes > p2Bytes ? xbBytes : p2Bytes);
    unsigned short* Xb  = (unsigned short*)XbP2d;  // live: prep..fc L0
    float*          P2d = (float*)XbP2d;           // live: memset..fold
    unsigned short* Wt0 = (unsigned short*)alloc((size_t)256 * 512 * 2);
    unsigned short* Wt1 = (unsigned short*)alloc((size_t)256 * 256 * 2);
    unsigned short* Wt2 = (unsigned short*)alloc((size_t)256 * 256 * 2);
    unsigned short* Wto = (unsigned short*)alloc((size_t)384 * 256 * 2);
    float* es     = (float*)alloc((size_t)N * NN_HEADS * 4);
    float* ed     = (float*)alloc((size_t)N * NN_HEADS * 4);
    float* wC     = (float*)alloc((size_t)E * NN_HEADS * 4);
    float* zinvA  = (float*)alloc((size_t)N * NN_HEADS * 4);
    float* Rrow   = (float*)alloc((size_t)N * 4);
    float* dvec   = (float*)alloc((size_t)N * 4);
    int*   counts = (int*)alloc((size_t)N * 4);
    int*   rs     = (int*)alloc((size_t)(N + 1) * 4);
    int*   cursor = (int*)alloc((size_t)N * 4);
    int*   csr    = (int*)alloc((size_t)E * 4);

    // ---- CSR build
    hipMemsetAsync(counts, 0, (size_t)N * 4, stream);
    count_kernel<<<(E + 255) / 256, 256, 0, stream>>>(dst, counts, E);
    scan_kernel<<<1, 1024, 0, stream>>>(counts, rs, cursor, N);
    scatter_kernel<<<(E + 255) / 256, 256, 0, stream>>>(src, dst, cursor, csr, E);

    // ---- fused prep (X + 4 W casts)
    int n4X = N * NN_F_IN / 4;
    int prepTotal = n4X + 256 * 512 + 256 * 256 + 256 * 256 + 384 * 256;
    prep_kernel<<<(prepTotal + 255) / 256, 256, 0, stream>>>(
        x, W0, W1, W2, Wout, Xb, Wt0, Wt1, Wt2, Wto, n4X);

    int atGrid = (N * NN_HEADS + 255) / 256;
    int ghGrid = (N + 3) / 4;
    int mT64 = (N + 63) / 64;

    // ---- layer 0: Xb -> Hb -> Bl
    fc_mfma<<<dim3(4, mT64), 256, 0, stream>>>(Xb, Wt0, Hb, N, 512, 256, 256);
    attn_kernel<<<atGrid, 256, 0, stream>>>(Hb, a0s, a0d, es, ed, N, NN_FH);
    edge_wz<<<ghGrid, 256, 0, stream>>>(es, ed, csr, rs, wC, zinvA, N);
    gather_hidden<<<ghGrid, 256, 0, stream>>>(Hb, wC, zinvA, csr, rs, nullptr, Bl, N, -1.f);

    // ---- layer 1: Bl -> Hb -> Bc (beta = 0.5/3)
    fc_mfma<<<dim3(4, mT64), 256, 0, stream>>>(Bl, Wt1, Hb, N, 256, 256, 256);
    attn_kernel<<<atGrid, 256, 0, stream>>>(Hb, a1s, a1d, es, ed, N, NN_FH);
    edge_wz<<<ghGrid, 256, 0, stream>>>(es, ed, csr, rs, wC, zinvA, N);
    gather_hidden<<<ghGrid, 256, 0, stream>>>(Hb, wC, zinvA, csr, rs, Bl, Bc, N, LAMDA_F / 3.f);

    // ---- layer 2: Bc -> Hb -> Bl (beta = 0.5/4)
    fc_mfma<<<dim3(4, mT64), 256, 0, stream>>>(Bc, Wt2, Hb, N, 256, 256, 256);
    attn_kernel<<<atGrid, 256, 0, stream>>>(Hb, a2s, a2d, es, ed, N, NN_FH);
    edge_wz<<<ghGrid, 256, 0, stream>>>(es, ed, csr, rs, wC, zinvA, N);
    gather_hidden<<<ghGrid, 256, 0, stream>>>(Hb, wC, zinvA, csr, rs, Bc, Bl, N, LAMDA_F / 4.f);

    // ---- bind_loss(Bl): znb (aliases Hb), partial slots in P2d
    rownorm_kernel<<<N, 256, 0, stream>>>(Bl, znb, dvec, N);
    hipMemsetAsync(znb + (size_t)N * NN_HID, 0, (size_t)(Npad - N) * NN_HID * 2, stream);
    hipMemsetAsync(P2d, 0, (size_t)2 * T * Npad * 4, stream);
    gram_mfma<<<nwg, 256, 0, stream>>>(znb, P2d, N, T, nwg, Npad);
    fold_kernel<<<(N + 255) / 256, 256, 0, stream>>>(P2d, Rrow, N, 2 * T, Npad);
    loss_kernel<<<1, 1024, 0, stream>>>(Rrow, dvec, out + (size_t)N * NN_NCLASS, N);

    // ---- output layer: Bl -> Hb(320) -> d_out
    fc_mfma<<<dim3(5, mT64), 256, 0, stream>>>(Bl, Wto, Hb, N, 256, 320, 320);
    attn_kernel<<<atGrid, 256, 0, stream>>>(Hb, aos, aod, es, ed, N, NN_NCLASS);
    edge_wz<<<ghGrid, 256, 0, stream>>>(es, ed, csr, rs, wC, zinvA, N);
    gather_final<<<N, NN_HEADS * NN_NCLASS, 0, stream>>>(Hb, wC, zinvA, csr, rs, out, N);
}